// Round 14
// baseline (447.082 us; speedup 1.0000x reference)
//
#include <hip/hip_runtime.h>

typedef unsigned short u16;
typedef short bf16x8 __attribute__((ext_vector_type(8)));
typedef float f32x4 __attribute__((ext_vector_type(4)));
typedef unsigned short u16x4 __attribute__((ext_vector_type(4)));

__device__ __forceinline__ u16 f2bf(float f) {
  union { float f; unsigned u; } v; v.f = f;
  unsigned u = v.u;
  unsigned r = (u + 0x7FFFu + ((u >> 16) & 1u)) >> 16;
  return (u16)r;
}
__device__ __forceinline__ float bf2f(u16 h) {
  union { unsigned u; float f; } v; v.u = ((unsigned)h) << 16;
  return v.f;
}
// packed f32x2 -> bf16x2 (RTNE, matches f2bf); 1 inst per 2 values
__device__ __forceinline__ unsigned cvt_pk_bf16(float lo, float hi) {
  unsigned d;
  asm("v_cvt_pk_bf16_f32 %0, %1, %2" : "=v"(d) : "v"(lo), "v"(hi));
  return d;
}
// gelu(x) = x * sigmoid(1.5957691(x+0.044715x^3)); exp2-domain (log2e folded), rcp approx.
__device__ __forceinline__ float gelu_f(float x) {
  const float c1 = -2.302585093f;          // -1.5957691216 * log2(e)
  const float c2 = -0.1029620967f;         // c1 * 0.044715
  float t = __builtin_fmaf(x * x, c2, c1) * x;
  float e = exp2f(t);
  return x * __builtin_amdgcn_rcpf(e + 1.0f);
}

#define GLD_LDS16(gp, lp)                                             \
  __builtin_amdgcn_global_load_lds(                                   \
      (const __attribute__((address_space(1))) void*)(gp),            \
      (__attribute__((address_space(3))) void*)(lp), 16, 0, 0)

// ds_read_b64_tr_b16 semantics (m156/m162): per 16-lane group, lane l elem e receives
// u16 #(l&3) of the 8-byte block addressed by lane (4e + ((l&15)>>2)) of the group.
// With per-lane addr = base + 8*lane over a blocked layout (4 q/d per 8B block), this
// delivers transposed MFMA fragments conflict-free. OFF is an additive byte immediate.
template<int OFF>
__device__ __forceinline__ u16x4 tr16(unsigned a) {
  u16x4 d;
  asm volatile("ds_read_b64_tr_b16 %0, %1 offset:%2" : "=&v"(d) : "v"(a), "n"(OFF));
  return d;
}
// bit-preserving pack of two u16x4 into one bf16x8 (avoids narrowing diagnostics)
__device__ __forceinline__ bf16x8 pack8(u16x4 a, u16x4 b) {
  union { u16x4 p[2]; bf16x8 v; } u;
  u.p[0] = a; u.p[1] = b;
  return u.v;
}
// two packed-bf16 words -> u16x4 (for b64 LDS store)
__device__ __forceinline__ u16x4 pack4(unsigned w0, unsigned w1) {
  union { unsigned w[2]; u16x4 v; } u;
  u.w[0] = w0; u.w[1] = w1;
  return u.v;
}

// ---------------- batched weight transpose+convert: W[K][N] f32 -> Bt[Npad][Kpad] bf16 ------
struct TrBatch {
  const float* W[9];
  u16* Bt[9];
  int K[9], N[9], Kpad[9], Npad[9];
  int tstart[10];   // prefix sum of (Npad/64)*(Kpad/64)
};
__global__ __launch_bounds__(256)
void transpose_all(TrBatch tb) {
  __shared__ float tile[64][65];
  const int tid = blockIdx.x;
  int mi = 0;
  while (mi < 8 && tid >= tb.tstart[mi + 1]) ++mi;
  const int lt = tid - tb.tstart[mi];
  const int tx = tb.Npad[mi] >> 6;
  const int n0 = (lt % tx) * 64;
  const int k0 = (lt / tx) * 64;
  const float* W = tb.W[mi];
  u16* Bt = tb.Bt[mi];
  const int K = tb.K[mi], N = tb.N[mi], Kpad = tb.Kpad[mi];
  const int t = threadIdx.x;
  const int c = t & 63;
  const int rb = t >> 6;
#pragma unroll
  for (int i = 0; i < 16; ++i) {
    int r = i * 4 + rb;
    float v = 0.f;
    if (k0 + r < K && n0 + c < N) v = W[(size_t)(k0 + r) * N + n0 + c];
    tile[r][c] = v;
  }
  __syncthreads();
#pragma unroll
  for (int i = 0; i < 16; ++i) {
    int r = i * 4 + rb;  // row in N-dim
    Bt[(size_t)(n0 + r) * Kpad + k0 + c] = f2bf(tile[c][r]);
  }
}

// ---------------- layernorm: fp32 [M][768] -> bf16 [Mpad][768], pad rows zeroed -------------
__global__ __launch_bounds__(64)
void ln_kernel(const float* __restrict__ X, const float* __restrict__ G,
               const float* __restrict__ Bv, u16* __restrict__ O, int Mreal) {
  const int row = blockIdx.x;
  const int l = threadIdx.x;
  u16* op = O + (size_t)row * 768;
  if (row >= Mreal) {
    u16x4 z = {0, 0, 0, 0};
#pragma unroll
    for (int i = 0; i < 3; ++i) *(u16x4*)(op + (i * 64 + l) * 4) = z;
    return;
  }
  const float* xp = X + (size_t)row * 768;
  float v[12];
  float s = 0.f, s2 = 0.f;
#pragma unroll
  for (int i = 0; i < 3; ++i) {
    float4 t4 = *(const float4*)(xp + (i * 64 + l) * 4);
    v[i * 4 + 0] = t4.x; v[i * 4 + 1] = t4.y; v[i * 4 + 2] = t4.z; v[i * 4 + 3] = t4.w;
    s += t4.x + t4.y + t4.z + t4.w;
    s2 += t4.x * t4.x + t4.y * t4.y + t4.z * t4.z + t4.w * t4.w;
  }
#pragma unroll
  for (int off = 32; off > 0; off >>= 1) {
    s += __shfl_xor(s, off);
    s2 += __shfl_xor(s2, off);
  }
  const float mean = s * (1.0f / 768.0f);
  const float var = s2 * (1.0f / 768.0f) - mean * mean;
  const float rstd = rsqrtf(var + 1e-5f);
#pragma unroll
  for (int i = 0; i < 3; ++i) {
    int base = (i * 64 + l) * 4;
    float4 g4 = *(const float4*)(G + base);
    float4 b4 = *(const float4*)(Bv + base);
    u16x4 o4;
    o4[0] = f2bf((v[i * 4 + 0] - mean) * rstd * g4.x + b4.x);
    o4[1] = f2bf((v[i * 4 + 1] - mean) * rstd * g4.y + b4.y);
    o4[2] = f2bf((v[i * 4 + 2] - mean) * rstd * g4.z + b4.z);
    o4[3] = f2bf((v[i * 4 + 3] - mean) * rstd * g4.w + b4.w);
    *(u16x4*)(op + base) = o4;
  }
}

// ---------------- fused residual-add (+optional LN): D = S (+P);  O = LN(D)*G+B -------------
template<bool DOLN, bool RESID>
__global__ __launch_bounds__(64)
void resid_ln(const float* __restrict__ S, float* __restrict__ D,
              const u16* __restrict__ P,
              const float* __restrict__ G, const float* __restrict__ Bv,
              u16* __restrict__ O) {
  const int row = blockIdx.x;
  const int l = threadIdx.x;
  const float* sp = S + (size_t)row * 768;
  float* dp = D + (size_t)row * 768;
  float v[12];
  float s = 0.f, s2 = 0.f;
#pragma unroll
  for (int i = 0; i < 3; ++i) {
    const int base = (i * 64 + l) * 4;
    float4 t4 = *(const float4*)(sp + base);
    if (RESID) {
      u16x4 p4 = *(const u16x4*)(P + (size_t)row * 768 + base);
      t4.x += bf2f(p4[0]); t4.y += bf2f(p4[1]);
      t4.z += bf2f(p4[2]); t4.w += bf2f(p4[3]);
    }
    v[i * 4 + 0] = t4.x; v[i * 4 + 1] = t4.y; v[i * 4 + 2] = t4.z; v[i * 4 + 3] = t4.w;
    s += t4.x + t4.y + t4.z + t4.w;
    s2 += t4.x * t4.x + t4.y * t4.y + t4.z * t4.z + t4.w * t4.w;
    *(float4*)(dp + base) = t4;
  }
  if (DOLN) {
#pragma unroll
    for (int off = 32; off > 0; off >>= 1) {
      s += __shfl_xor(s, off);
      s2 += __shfl_xor(s2, off);
    }
    const float mean = s * (1.0f / 768.0f);
    const float var = s2 * (1.0f / 768.0f) - mean * mean;
    const float rstd = rsqrtf(var + 1e-5f);
    u16* op = O + (size_t)row * 768;
#pragma unroll
    for (int i = 0; i < 3; ++i) {
      int base = (i * 64 + l) * 4;
      float4 g4 = *(const float4*)(G + base);
      float4 b4 = *(const float4*)(Bv + base);
      u16x4 o4;
      o4[0] = f2bf((v[i * 4 + 0] - mean) * rstd * g4.x + b4.x);
      o4[1] = f2bf((v[i * 4 + 1] - mean) * rstd * g4.y + b4.y);
      o4[2] = f2bf((v[i * 4 + 2] - mean) * rstd * g4.z + b4.z);
      o4[3] = f2bf((v[i * 4 + 3] - mean) * rstd * g4.w + b4.w);
      *(u16x4*)(op + base) = o4;
    }
  }
}

// ---------------- GEMM 128x128, BK=64, split-half LDS (rule #21 staging) --------------------
// MODE 0: store bf16   1: relu->bf16   2: gelu->bf16
// 4-wave 1-phase structure. Chunk-XOR bank swizzle (R6: SQ_LDS_BANK_CONFLICT 4.7M -> 0).
// cvt_pk epilogue. For high-occupancy grids (dual) where inter-block TLP hides the stage
// drain. No XCD swizzle (measured -35us here: L3-resident working set).
template<int MODE>
__global__ void gemm_bt(const u16* __restrict__ A, const u16* __restrict__ Bt,
                        void* __restrict__ C, const float* __restrict__ bias,
                        int K, int ldc, int nbias) {
  __shared__ u16 As[2 * 128 * 32];   // [ks][row][chunk-swizzled][8]
  __shared__ u16 Bs[2 * 128 * 32];
  const int t = threadIdx.x;
  const int lane = t & 63;
  const int wid = t >> 6;
  const int wm = (wid >> 1) * 64;
  const int wn = (wid & 1) * 64;
  const int tm = blockIdx.x * 128;
  const int tn = blockIdx.y * 128;

  f32x4 zero = {0.f, 0.f, 0.f, 0.f};
  f32x4 acc[4][4];
#pragma unroll
  for (int i = 0; i < 4; ++i)
#pragma unroll
    for (int j = 0; j < 4; ++j) acc[i][j] = zero;

  const int rowA = lane & 15;
  const int kb = (((lane >> 4) ^ ((rowA >> 1) & 3)) << 3);   // swizzled chunk slot
  const int kTiles = K >> 6;
  for (int kt = 0; kt < kTiles; ++kt) {
    const int kk = kt << 6;
#pragma unroll
    for (int i = 0; i < 4; ++i) {
      const int c = i * 256 + t;                       // linear LDS slot index
      const int r = (c >> 2) & 127;                    // permuted global row
      const int cc = ((c >> 9) << 5) + ((((c & 3) ^ ((r >> 1) & 3))) << 3); // swizzled k-chunk
      GLD_LDS16(A + (size_t)(tm + r) * K + kk + cc, As + c * 8);
      GLD_LDS16(Bt + (size_t)(tn + r) * K + kk + cc, Bs + c * 8);
    }
    __syncthreads();
#pragma unroll
    for (int ks = 0; ks < 2; ++ks) {
      bf16x8 af[4], bfr[4];
      const int base = ks * 4096;
#pragma unroll
      for (int i = 0; i < 4; ++i) {
        af[i] = *(const bf16x8*)(As + base + (wm + i * 16 + rowA) * 32 + kb);
        bfr[i] = *(const bf16x8*)(Bs + base + (wn + i * 16 + rowA) * 32 + kb);
      }
#pragma unroll
      for (int mi = 0; mi < 4; ++mi)
#pragma unroll
        for (int ni = 0; ni < 4; ++ni)
          acc[mi][ni] = __builtin_amdgcn_mfma_f32_16x16x32_bf16(af[mi], bfr[ni], acc[mi][ni], 0, 0, 0);
    }
    __syncthreads();
  }
  const int col0 = lane & 15;
  const int row0 = (lane >> 4) << 2;
#pragma unroll
  for (int mi = 0; mi < 4; ++mi) {
#pragma unroll
    for (int ni = 0; ni < 4; ++ni) {
      int col = tn + wn + ni * 16 + col0;
      float bb = (col < nbias) ? bias[col] : 0.f;
      float vv[4];
#pragma unroll
      for (int r = 0; r < 4; ++r) {
        float v = acc[mi][ni][r] + bb;
        if (MODE == 1) v = fmaxf(v, 0.f);
        else if (MODE == 2) v = gelu_f(v);
        vv[r] = v;
      }
      unsigned w0 = cvt_pk_bf16(vv[0], vv[1]);
      unsigned w1 = cvt_pk_bf16(vv[2], vv[3]);
      size_t row = (size_t)(tm + wm + mi * 16 + row0);
      u16* cp = (u16*)C + row * ldc + col;
      cp[0] = (u16)w0;
      cp[(size_t)ldc] = (u16)(w0 >> 16);
      cp[(size_t)ldc * 2] = (u16)w1;
      cp[(size_t)ldc * 3] = (u16)(w1 >> 16);
    }
  }
}

// ---------------- depth-2 pipelined GEMM 128x256, 8 waves, 3 LDS buffers (R14) --------------
// The 2-barrier structure ceiling is ~660 TF (R4/R7/R8/R9/R10 all failed to break it with
// shallow fixes; R10 showed 1-deep prefetch covers ~1/3 of load latency). This applies the
// measured lever (m218: counted vmcnt with loads spanning >=2 iterations): 3 buffers, loads
// for tile t+2 issued at iter t, waited at iter t+2 -> ~2 iterations (~700 cyc) of cover.
// ONE barrier per K-tile. vmcnt(6): 12 outstanding (L(t),L(t+1)) -> in-order retire (m135)
// waits exactly L(t)'s 6. Race audit: b[(t+2)%3]=b[(t-1)%3] overwritten only after iter t's
// barrier, which orders all waves' iter t-1 ds_reads (each feeds an MFMA via lgkmcnt before
// the barrier). 8 waves (2M x 4N), each the verified 64x64/acc[4][4] job; A/B staging and
// chunk-XOR swizzle formulas are gemm_bt's (B generalized to 256 rows). LDS 144 KB ->
// 1 block/CU, M-fastest grid (B-panel L2 sharing). Routed to fc (64x12=768 blocks = 3.0
// rounds) and qkv (64x9=576). MODE 0/2.
template<int MODE>
__global__ __launch_bounds__(512)
void gemm_bt_dp(const u16* __restrict__ A, const u16* __restrict__ Bt,
                void* __restrict__ C, const float* __restrict__ bias,
                int K, int ldc, int nbias) {
  __shared__ u16 As[3][2 * 128 * 32];   // 48 KB
  __shared__ u16 Bs[3][2 * 256 * 32];   // 96 KB
  const int t = threadIdx.x;
  const int lane = t & 63;
  const int wid = t >> 6;               // 0..7
  const int wm = (wid >> 2) * 64;
  const int wn = (wid & 3) * 64;
  const int tm = blockIdx.x * 128;      // M fastest: consecutive blocks share B-panel
  const int tn = blockIdx.y * 256;

  f32x4 zero = {0.f, 0.f, 0.f, 0.f};
  f32x4 acc[4][4];
#pragma unroll
  for (int i = 0; i < 4; ++i)
#pragma unroll
    for (int j = 0; j < 4; ++j) acc[i][j] = zero;

  const int rowA = lane & 15;
  const int kb = (((lane >> 4) ^ ((rowA >> 1) & 3)) << 3);
  const int kTiles = K >> 6;

  auto ISSUE = [&](int kt) {
    const int buf = kt % 3;
    const int kk = kt << 6;
#pragma unroll
    for (int i = 0; i < 2; ++i) {       // A: 1024 slots, 2/thread
      const int c = i * 512 + t;
      const int r = (c >> 2) & 127;
      const int cc = ((c >> 9) << 5) + ((((c & 3) ^ ((r >> 1) & 3))) << 3);
      GLD_LDS16(A + (size_t)(tm + r) * K + kk + cc, &As[buf][c * 8]);
    }
#pragma unroll
    for (int i = 0; i < 4; ++i) {       // B: 2048 slots, 4/thread
      const int c = i * 512 + t;
      const int r = (c >> 2) & 255;
      const int cc = ((c >> 10) << 5) + ((((c & 3) ^ ((r >> 1) & 3))) << 3);
      GLD_LDS16(Bt + (size_t)(tn + r) * K + kk + cc, &Bs[buf][c * 8]);
    }
  };

  ISSUE(0);
  if (kTiles > 1) ISSUE(1);
  for (int kt = 0; kt < kTiles; ++kt) {
    if (kt + 1 < kTiles) asm volatile("s_waitcnt vmcnt(6)" ::: "memory");
    else                 asm volatile("s_waitcnt vmcnt(0)" ::: "memory");
    __builtin_amdgcn_s_barrier();
    __builtin_amdgcn_sched_barrier(0);
    if (kt + 2 < kTiles) ISSUE(kt + 2);   // overwrites b[(t-1)%3], released by the barrier
    const int buf = kt % 3;
#pragma unroll
    for (int ks = 0; ks < 2; ++ks) {
      bf16x8 af[4], bfr[4];
#pragma unroll
      for (int i = 0; i < 4; ++i)
        af[i] = *(const bf16x8*)(&As[buf][ks * 4096 + (wm + i * 16 + rowA) * 32 + kb]);
#pragma unroll
      for (int j = 0; j < 4; ++j)
        bfr[j] = *(const bf16x8*)(&Bs[buf][ks * 8192 + (wn + j * 16 + rowA) * 32 + kb]);
#pragma unroll
      for (int mi = 0; mi < 4; ++mi)
#pragma unroll
        for (int ni = 0; ni < 4; ++ni)
          acc[mi][ni] = __builtin_amdgcn_mfma_f32_16x16x32_bf16(af[mi], bfr[ni], acc[mi][ni], 0, 0, 0);
    }
    // no trailing barrier: next iter's leading barrier orders buffer reuse
  }

  const int col0 = lane & 15;
  const int row0 = (lane >> 4) << 2;
#pragma unroll
  for (int mi = 0; mi < 4; ++mi) {
#pragma unroll
    for (int ni = 0; ni < 4; ++ni) {
      int col = tn + wn + ni * 16 + col0;
      float bb = (col < nbias) ? bias[col] : 0.f;
      float vv[4];
#pragma unroll
      for (int r = 0; r < 4; ++r) {
        float v = acc[mi][ni][r] + bb;
        if (MODE == 1) v = fmaxf(v, 0.f);
        else if (MODE == 2) v = gelu_f(v);
        vv[r] = v;
      }
      unsigned w0 = cvt_pk_bf16(vv[0], vv[1]);
      unsigned w1 = cvt_pk_bf16(vv[2], vv[3]);
      size_t row = (size_t)(tm + wm + mi * 16 + row0);
      u16* cp = (u16*)C + row * ldc + col;
      cp[0] = (u16)w0;
      cp[(size_t)ldc] = (u16)(w0 >> 16);
      cp[(size_t)ldc * 2] = (u16)w1;
      cp[(size_t)ldc * 3] = (u16)(w1 >> 16);
    }
  }
}

// ---------------- 64x128 M-split GEMM for low-grid latency-bound dispatches -----------------
// R11 WIN: doubles the grid (3/CU) with A-traffic unchanged (FETCH stayed 43 MB) by
// splitting M and making M fastest so consecutive blocks share the B(weight)-panel.
// 4 waves: wave w = cols [w*32,w*32+32), all 64 rows; acc[4][2]. LDS 24 KB. MODE 0/1.
template<int MODE>
__global__ __launch_bounds__(256)
void gemm_bt_m64(const u16* __restrict__ A, const u16* __restrict__ Bt,
                 void* __restrict__ C, const float* __restrict__ bias,
                 int K, int ldc, int nbias) {
  __shared__ u16 As[2 * 64 * 32];    // [ks][row 0..63][chunk-swizzled][8]   8 KB
  __shared__ u16 Bs[2 * 128 * 32];   // [ks][ncol 0..127][chunk-swizzled][8] 16 KB
  const int t = threadIdx.x;
  const int lane = t & 63;
  const int wid = t >> 6;
  const int wn = wid * 32;                 // wave's 32-col strip
  const int tm = blockIdx.x * 64;          // M fastest: consecutive blocks share B-panel
  const int tn = blockIdx.y * 128;

  f32x4 zero = {0.f, 0.f, 0.f, 0.f};
  f32x4 acc[4][2];
#pragma unroll
  for (int i = 0; i < 4; ++i)
#pragma unroll
    for (int j = 0; j < 2; ++j) acc[i][j] = zero;

  const int rowA = lane & 15;
  const int kb = (((lane >> 4) ^ ((rowA >> 1) & 3)) << 3);
  const int kTiles = K >> 6;
  for (int kt = 0; kt < kTiles; ++kt) {
    const int kk = kt << 6;
#pragma unroll
    for (int i = 0; i < 2; ++i) {          // A: 512 slots, 2/thread
      const int c = i * 256 + t;
      const int r = (c >> 2) & 63;
      const int cc = ((c >> 8) << 5) + ((((c & 3) ^ ((r >> 1) & 3))) << 3);
      GLD_LDS16(A + (size_t)(tm + r) * K + kk + cc, As + c * 8);
    }
#pragma unroll
    for (int i = 0; i < 4; ++i) {          // B: 1024 slots, 4/thread
      const int c = i * 256 + t;
      const int r = (c >> 2) & 127;
      const int cc = ((c >> 9) << 5) + ((((c & 3) ^ ((r >> 1) & 3))) << 3);
      GLD_LDS16(Bt + (size_t)(tn + r) * K + kk + cc, Bs + c * 8);
    }
    __syncthreads();
#pragma unroll
    for (int ks = 0; ks < 2; ++ks) {
      bf16x8 af[4], bfr[2];
#pragma unroll
      for (int i = 0; i < 4; ++i)
        af[i] = *(const bf16x8*)(As + ks * 2048 + (i * 16 + rowA) * 32 + kb);
#pragma unroll
      for (int j = 0; j < 2; ++j)
        bfr[j] = *(const bf16x8*)(Bs + ks * 4096 + (wn + j * 16 + rowA) * 32 + kb);
#pragma unroll
      for (int mi = 0; mi < 4; ++mi)
#pragma unroll
        for (int ni = 0; ni < 2; ++ni)
          acc[mi][ni] = __builtin_amdgcn_mfma_f32_16x16x32_bf16(af[mi], bfr[ni], acc[mi][ni], 0, 0, 0);
    }
    __syncthreads();
  }
  const int col0 = lane & 15;
  const int row0 = (lane >> 4) << 2;
#pragma unroll
  for (int mi = 0; mi < 4; ++mi) {
#pragma unroll
    for (int ni = 0; ni < 2; ++ni) {
      int col = tn + wn + ni * 16 + col0;
      float bb = (col < nbias) ? bias[col] : 0.f;
      float vv[4];
#pragma unroll
      for (int r = 0; r < 4; ++r) {
        float v = acc[mi][ni][r] + bb;
        if (MODE == 1) v = fmaxf(v, 0.f);
        vv[r] = v;
      }
      unsigned w0 = cvt_pk_bf16(vv[0], vv[1]);
      unsigned w1 = cvt_pk_bf16(vv[2], vv[3]);
      size_t row = (size_t)(tm + mi * 16 + row0);
      u16* cp = (u16*)C + row * ldc + col;
      cp[0] = (u16)w0;
      cp[(size_t)ldc] = (u16)(w0 >> 16);
      cp[(size_t)ldc * 2] = (u16)w1;
      cp[(size_t)ldc * 3] = (u16)(w1 >> 16);
    }
  }
}

// ---------------- 64x64 GEMM for ad1 (N=192 unpadded; R13) ----------------------------------
// Native N=192 needs a 64-col tile: grid (M/64, N/64), M fastest (B-panel shared). 4 waves:
// wave w = cols [w*16, w*16+16), all 64 rows; acc[4]. LDS 16 KB. MODE 1 (relu).
template<int MODE>
__global__ __launch_bounds__(256)
void gemm_bt_6464(const u16* __restrict__ A, const u16* __restrict__ Bt,
                  void* __restrict__ C, const float* __restrict__ bias,
                  int K, int ldc, int nbias) {
  __shared__ u16 As[2 * 64 * 32];    // 8 KB
  __shared__ u16 Bs[2 * 64 * 32];    // 8 KB
  const int t = threadIdx.x;
  const int lane = t & 63;
  const int wid = t >> 6;
  const int wn = wid * 16;                 // wave's 16-col strip
  const int tm = blockIdx.x * 64;          // M fastest
  const int tn = blockIdx.y * 64;

  f32x4 acc[4];
#pragma unroll
  for (int i = 0; i < 4; ++i) acc[i] = (f32x4){0.f, 0.f, 0.f, 0.f};

  const int rowA = lane & 15;
  const int kb = (((lane >> 4) ^ ((rowA >> 1) & 3)) << 3);
  const int kTiles = K >> 6;
  for (int kt = 0; kt < kTiles; ++kt) {
    const int kk = kt << 6;
#pragma unroll
    for (int i = 0; i < 2; ++i) {          // A and B: 512 slots each, 2/thread each
      const int c = i * 256 + t;
      const int r = (c >> 2) & 63;
      const int cc = ((c >> 8) << 5) + ((((c & 3) ^ ((r >> 1) & 3))) << 3);
      GLD_LDS16(A + (size_t)(tm + r) * K + kk + cc, As + c * 8);
      GLD_LDS16(Bt + (size_t)(tn + r) * K + kk + cc, Bs + c * 8);
    }
    __syncthreads();
#pragma unroll
    for (int ks = 0; ks < 2; ++ks) {
      bf16x8 af[4], bfr;
#pragma unroll
      for (int i = 0; i < 4; ++i)
        af[i] = *(const bf16x8*)(As + ks * 2048 + (i * 16 + rowA) * 32 + kb);
      bfr = *(const bf16x8*)(Bs + ks * 2048 + (wn + rowA) * 32 + kb);
#pragma unroll
      for (int mi = 0; mi < 4; ++mi)
        acc[mi] = __builtin_amdgcn_mfma_f32_16x16x32_bf16(af[mi], bfr, acc[mi], 0, 0, 0);
    }
    __syncthreads();
  }
  const int col0 = lane & 15;
  const int row0 = (lane >> 4) << 2;
#pragma unroll
  for (int mi = 0; mi < 4; ++mi) {
    int col = tn + wn + col0;
    float bb = (col < nbias) ? bias[col] : 0.f;
    float vv[4];
#pragma unroll
    for (int r = 0; r < 4; ++r) {
      float v = acc[mi][r] + bb;
      if (MODE == 1) v = fmaxf(v, 0.f);
      vv[r] = v;
    }
    unsigned w0 = cvt_pk_bf16(vv[0], vv[1]);
    unsigned w1 = cvt_pk_bf16(vv[2], vv[3]);
    size_t row = (size_t)(tm + mi * 16 + row0);
    u16* cp = (u16*)C + row * ldc + col;
    cp[0] = (u16)w0;
    cp[(size_t)ldc] = (u16)(w0 >> 16);
    cp[(size_t)ldc * 2] = (u16)w1;
    cp[(size_t)ldc * 3] = (u16)(w1 >> 16);
  }
}

// ---------------- dual GEMM: two independent mode-0 GEMMs fused into one dispatch -----------
struct GemmJob {
  const u16* A; const u16* Bt; u16* C; const float* bias;
  int K, ldc, nbias, mblocks;
};
__global__ __launch_bounds__(256)
void gemm_bt_dual(GemmJob j0, GemmJob j1, int split) {
  __shared__ u16 As[2 * 128 * 32];
  __shared__ u16 Bs[2 * 128 * 32];
  const int bid = blockIdx.x;
  const GemmJob& J = (bid < split) ? j0 : j1;
  const int lb = (bid < split) ? bid : bid - split;
  const int tm = (lb % J.mblocks) * 128;
  const int tn = (lb / J.mblocks) * 128;
  const u16* A = J.A;
  const u16* Bt = J.Bt;
  const int K = J.K;

  const int t = threadIdx.x;
  const int lane = t & 63;
  const int wid = t >> 6;
  const int wm = (wid >> 1) * 64;
  const int wn = (wid & 1) * 64;

  f32x4 zero = {0.f, 0.f, 0.f, 0.f};
  f32x4 acc[4][4];
#pragma unroll
  for (int i = 0; i < 4; ++i)
#pragma unroll
    for (int j = 0; j < 4; ++j) acc[i][j] = zero;

  const int rowA = lane & 15;
  const int kb = (((lane >> 4) ^ ((rowA >> 1) & 3)) << 3);
  const int kTiles = K >> 6;
  for (int kt = 0; kt < kTiles; ++kt) {
    const int kk = kt << 6;
#pragma unroll
    for (int i = 0; i < 4; ++i) {
      const int c = i * 256 + t;
      const int r = (c >> 2) & 127;
      const int cc = ((c >> 9) << 5) + ((((c & 3) ^ ((r >> 1) & 3))) << 3);
      GLD_LDS16(A + (size_t)(tm + r) * K + kk + cc, As + c * 8);
      GLD_LDS16(Bt + (size_t)(tn + r) * K + kk + cc, Bs + c * 8);
    }
    __syncthreads();
#pragma unroll
    for (int ks = 0; ks < 2; ++ks) {
      bf16x8 af[4], bfr[4];
      const int base = ks * 4096;
#pragma unroll
      for (int i = 0; i < 4; ++i) {
        af[i] = *(const bf16x8*)(As + base + (wm + i * 16 + rowA) * 32 + kb);
        bfr[i] = *(const bf16x8*)(Bs + base + (wn + i * 16 + rowA) * 32 + kb);
      }
#pragma unroll
      for (int mi = 0; mi < 4; ++mi)
#pragma unroll
        for (int ni = 0; ni < 4; ++ni)
          acc[mi][ni] = __builtin_amdgcn_mfma_f32_16x16x32_bf16(af[mi], bfr[ni], acc[mi][ni], 0, 0, 0);
    }
    __syncthreads();
  }
  const int col0 = lane & 15;
  const int row0 = (lane >> 4) << 2;
#pragma unroll
  for (int mi = 0; mi < 4; ++mi) {
#pragma unroll
    for (int ni = 0; ni < 4; ++ni) {
      int col = tn + wn + ni * 16 + col0;
      float bb = (col < J.nbias) ? J.bias[col] : 0.f;
      unsigned w0 = cvt_pk_bf16(acc[mi][ni][0] + bb, acc[mi][ni][1] + bb);
      unsigned w1 = cvt_pk_bf16(acc[mi][ni][2] + bb, acc[mi][ni][3] + bb);
      size_t row = (size_t)(tm + wm + mi * 16 + row0);
      u16* cp = J.C + row * J.ldc + col;
      cp[0] = (u16)w0;
      cp[(size_t)J.ldc] = (u16)(w0 >> 16);
      cp[(size_t)J.ldc * 2] = (u16)w1;
      cp[(size_t)J.ldc * 3] = (u16)(w1 >> 16);
    }
  }
}

// ---------------- MFMA flash attention, QBLK=128 + tr-read V/P ------------------------------
// Single-pass normalized output; QBLK=128 (512 threads, 8 waves): each staged K/V tile
// serves 128 q rows. Causal grid (B*H, 8): yq = 7-blockIdx.y (heavy first), kv tiles
// [0, 2*yq+2); mask on the last two (diagonal) tiles via kv>q. Softmax in exp2 domain,
// VALU-thinned; T13 defer-max (THR=8); rowsum-l via P x ones MFMA. LDS 32 KB.
// LDS layouts (per 64x64 kv tile, verified R3..R13):
//   Ks: [kv][dchunk ^ (kv&7)]*8  (XOR swizzle, conflict-free b128 r/w)
//   Vs/Ps: blocked-transpose layout for ds_read_b64_tr_b16 (canonical addr = base+8*lane)
template<bool CAUSAL>
__global__ __launch_bounds__(512)
void attn_mfma(const u16* __restrict__ Q, const u16* __restrict__ Kp,
               const u16* __restrict__ Vp, u16* __restrict__ O,
               int seqkv, int qrs, int krs,
               long long qBatch, long long kBatch,
               int qoff, int koff, int voff) {
  __shared__ __align__(16) u16 Ks[64 * 64];
  __shared__ __align__(16) u16 Vs[4096];
  __shared__ __align__(16) u16 Ps[8][1024];
  const int t = threadIdx.x;
  const int lane = t & 63;
  const int wid = t >> 6;                 // 0..7
  const int b = blockIdx.x / 12, h = blockIdx.x % 12;
  const int yq = CAUSAL ? ((int)gridDim.y - 1 - (int)blockIdx.y) : (int)blockIdx.y;
  const int q0 = yq * 128;
  const int colid = lane & 15;
  const int rgrp = lane >> 4;

  const int kt_end = CAUSAL ? (2 * yq + 2) : ((seqkv + 63) >> 6);

  const u16* qp = Q + (size_t)b * qBatch + qoff + (size_t)(q0 + wid * 16 + colid) * qrs + h * 64;
  bf16x8 qa[2];
#pragma unroll
  for (int s = 0; s < 2; ++s) qa[s] = *(const bf16x8*)(qp + s * 32 + (rgrp << 3));

  f32x4 oacc[4];
#pragma unroll
  for (int i = 0; i < 4; ++i) oacc[i] = (f32x4){0.f, 0.f, 0.f, 0.f};
  float m[4] = {-1e30f, -1e30f, -1e30f, -1e30f};
  float l[4] = {0.f, 0.f, 0.f, 0.f};

  // all-ones bf16 B-fragment for the P-rowsum MFMA
  const u16x4 one4 = {0x3F80, 0x3F80, 0x3F80, 0x3F80};
  const bf16x8 ones8 = pack8(one4, one4);

  const u16* kbase = Kp + (size_t)b * kBatch + koff + h * 64;
  const u16* vbase = Vp + (size_t)b * kBatch + voff + h * 64;

  // staging geometry: 512 threads cover the 64x64 tile exactly once:
  // thread -> kv row r = t>>3, d chunk sdc*8
  const int srr = t >> 3, sdc = t & 7;    // srr 0..63
  const int kwo = srr * 64 + ((sdc ^ (srr & 7)) << 3);
  const int vwo = ((sdc >> 1) << 10) + ((srr >> 5) << 9) + (((srr >> 2) & 1) << 8)
                + (((srr >> 3) & 3) << 6) + ((srr & 3) << 4) + (((2 * sdc) & 3) << 2);
  // canonical tr-read per-lane byte bases (low 32 bits of generic shared ptr = LDS offset)
  const unsigned vs_base = (unsigned)(size_t)&Vs[0] + 8u * (unsigned)lane;
  const unsigned ps_base = (unsigned)(size_t)&Ps[wid][0] + 8u * (unsigned)lane;

  bf16x8 kz, vz;
  auto LOADT = [&](int kt) {
    const int tk = kt * 64 + srr;
    const int dc = sdc << 3;
    kz = (bf16x8){0, 0, 0, 0, 0, 0, 0, 0};
    vz = (bf16x8){0, 0, 0, 0, 0, 0, 0, 0};
    if (tk < seqkv) {
      kz = *(const bf16x8*)(kbase + (size_t)tk * krs + dc);
      vz = *(const bf16x8*)(vbase + (size_t)tk * krs + dc);
    }
  };
  LOADT(0);

  constexpr float SC2 = 0.18033688011112042f;   // 0.125 * log2(e): exp2 domain

  for (int kt = 0; kt < kt_end; ++kt) {
    const int k0 = kt * 64;
    *(bf16x8*)&Ks[kwo] = kz;
    *(bf16x8*)&Vs[vwo] = vz;
    __syncthreads();
    if (kt + 1 < kt_end) LOADT(kt + 1);   // T14 prefetch

    // ---- S = Q.K^T (raw) ----
    f32x4 sacc[4];
#pragma unroll
    for (int c = 0; c < 4; ++c) sacc[c] = (f32x4){0.f, 0.f, 0.f, 0.f};
#pragma unroll
    for (int c = 0; c < 4; ++c)
#pragma unroll
      for (int s = 0; s < 2; ++s) {
        bf16x8 kf = *(const bf16x8*)&Ks[(c * 16 + colid) * 64 +
                                        ((((s << 2) + rgrp) ^ (colid & 7)) << 3)];
        sacc[c] = __builtin_amdgcn_mfma_f32_16x16x32_bf16(qa[s], kf, sacc[c], 0, 0, 0);
      }

    // ---- mask in raw domain (causal diagonal tiles / kv-padding tile only) ----
    const bool domask = CAUSAL ? (kt >= 2 * yq) : (kt == kt_end - 1);
    if (domask) {
#pragma unroll
      for (int c = 0; c < 4; ++c) {
        int kv = k0 + c * 16 + colid;
#pragma unroll
        for (int r = 0; r < 4; ++r) {
          int q = q0 + wid * 16 + rgrp * 4 + r;
          if ((CAUSAL && kv > q) || (!CAUSAL && kv >= seqkv)) sacc[c][r] = -1e30f;
        }
      }
    }

    // ---- row max over raw sacc, scaled once per row ----
    float pms[4];
#pragma unroll
    for (int r = 0; r < 4; ++r) {
      float v = fmaxf(fmaxf(sacc[0][r], sacc[1][r]), fmaxf(sacc[2][r], sacc[3][r]));
#pragma unroll
      for (int off = 1; off < 16; off <<= 1) v = fmaxf(v, __shfl_xor(v, off));
      pms[r] = v * SC2;
    }
    // ---- T13 defer-max: rescale only when some row exceeds m+8 (wave-uniform) ----
    bool ok = (pms[0] <= m[0] + 8.f) && (pms[1] <= m[1] + 8.f) &&
              (pms[2] <= m[2] + 8.f) && (pms[3] <= m[3] + 8.f);
    if (!__all(ok)) {
#pragma unroll
      for (int r = 0; r < 4; ++r) {
        float newm = fmaxf(m[r], pms[r]);
        float corr = exp2f(m[r] - newm);
        m[r] = newm;
        l[r] *= corr;
#pragma unroll
        for (int dc2 = 0; dc2 < 4; ++dc2) oacc[dc2][r] *= corr;
      }
    }

    // ---- P = exp2(fma(sacc, SC2, -m)) ----
    float pv[4][4];
#pragma unroll
    for (int c = 0; c < 4; ++c)
#pragma unroll
      for (int r = 0; r < 4; ++r)
        pv[c][r] = exp2f(__builtin_fmaf(sacc[c][r], SC2, -m[r]));

    // ---- P^T -> LDS (blocked layout): cvt_pk x2 + one b64 store per c ----
#pragma unroll
    for (int c = 0; c < 4; ++c) {
      unsigned w0 = cvt_pk_bf16(pv[c][0], pv[c][1]);
      unsigned w1 = cvt_pk_bf16(pv[c][2], pv[c][3]);
      const int pa = ((c >> 1) << 9) + (((colid >> 2) & 1) << 8)
                   + (((2 * c + (colid >> 3)) & 3) << 6) + ((colid & 3) << 4) + (rgrp << 2);
      *(u16x4*)&Ps[wid][pa] = pack4(w0, w1);
    }
    __builtin_amdgcn_sched_barrier(0);   // pin store->tr-read order (DS in-order per wave)

    // ---- pf via canonical tr reads ----
    u16x4 p00 = tr16<0>(ps_base);
    u16x4 p01 = tr16<512>(ps_base);
    u16x4 p10 = tr16<1024>(ps_base);
    u16x4 p11 = tr16<1536>(ps_base);
    asm volatile("s_waitcnt lgkmcnt(0)" ::: "memory");
    __builtin_amdgcn_sched_barrier(0);   // rule #18: fence MFMA hoisting past asm waitcnt
    bf16x8 pf0 = pack8(p00, p01);
    bf16x8 pf1 = pack8(p10, p11);

    // ---- l += rowsum(P) via P x ones MFMA ----
    f32x4 sum_acc = (f32x4){0.f, 0.f, 0.f, 0.f};
    sum_acc = __builtin_amdgcn_mfma_f32_16x16x32_bf16(pf0, ones8, sum_acc, 0, 0, 0);
    sum_acc = __builtin_amdgcn_mfma_f32_16x16x32_bf16(pf1, ones8, sum_acc, 0, 0, 0);

    // ---- O += P.V : per-d0 batch {tr_read x4, lgkmcnt(0), sched_barrier, 2 MFMA} ----
#pragma unroll
    for (int dc2 = 0; dc2 < 4; ++dc2) {
      const unsigned va = vs_base + (unsigned)(dc2 * 2048);
      u16x4 v00 = tr16<0>(va);
      u16x4 v01 = tr16<512>(va);
      u16x4 v10 = tr16<1024>(va);
      u16x4 v11 = tr16<1536>(va);
      asm volatile("s_waitcnt lgkmcnt(0)" ::: "memory");
      __builtin_amdgcn_sched_barrier(0);
      bf16x8 vf0 = pack8(v00, v01);
      bf16x8 vf1 = pack8(v10, v11);
      oacc[dc2] = __builtin_amdgcn_mfma_f32_16x16x32_bf16(pf0, vf0, oacc[dc2], 0, 0, 0);
      oacc[dc2] = __builtin_amdgcn_mfma_f32_16x16x32_bf16(pf1, vf1, oacc[dc2], 0, 0, 0);
    }
#pragma unroll
    for (int r = 0; r < 4; ++r) l[r] += sum_acc[r];
    __syncthreads();
  }

  // ---- epilogue: normalized write (cvt_pk conversions) ----
#pragma unroll
  for (int r = 0; r < 4; ++r) {
    int qrow = q0 + wid * 16 + rgrp * 4 + r;
    u16* op = O + ((size_t)b * 1024 + qrow) * 768 + h * 64;
    float inv = 1.f / l[r];
    unsigned w0 = cvt_pk_bf16(oacc[0][r] * inv, oacc[1][r] * inv);
    unsigned w1 = cvt_pk_bf16(oacc[2][r] * inv, oacc[3][r] * inv);
    op[colid] = (u16)w0;
    op[16 + colid] = (u16)(w0 >> 16);
    op[32 + colid] = (u16)w1;
    op[48 + colid] = (u16)(w1 >> 16);
  }
}

// =============================================================================================
extern "C" void kernel_launch(void* const* d_in, const int* in_sizes, int n_in,
                              void* d_out, int out_size, void* d_ws, size_t ws_size,
                              hipStream_t stream) {
  const float* x        = (const float*)d_in[0];
  const float* x_enc    = (const float*)d_in[1];
  const float* ln1_g    = (const float*)d_in[2];
  const float* ln1_b    = (const float*)d_in[3];
  const float* ln2_g    = (const float*)d_in[4];
  const float* ln2_b    = (const float*)d_in[5];
  const float* ln3_g    = (const float*)d_in[6];
  const float* ln3_b    = (const float*)d_in[7];
  const float* attn_w   = (const float*)d_in[8];
  const float* attn_bias= (const float*)d_in[9];
  const float* proj_w   = (const float*)d_in[10];
  const float* proj_b   = (const float*)d_in[11];
  const float* img_w    = (const float*)d_in[12];
  const float* img_b    = (const float*)d_in[13];
  const float* cap_w    = (const float*)d_in[14];
  const float* cap_b    = (const float*)d_in[15];
  const float* cross_w  = (const float*)d_in[16];
  const float* cross_b  = (const float*)d_in[17];
  const float* ad1_w    = (const float*)d_in[18];
  const float* ad1_b    = (const float*)d_in[19];
  const float* ad2_w    = (const float*)d_in[20];
  const float* ad2_b    = (const float*)d_in[21];
  const float* fc_w     = (const float*)d_in[22];
  const float* fc_b     = (const float*)d_in[23];
  const float* mproj_w  = (const float*)d_in[24];
  const float* mproj_b  = (const float*)d_in[25];

  const int Mx = 8192;            // B*T
  const int Me = 2056;            // B*N_ENC
  const int MeP = 2176;           // padded to 17*128

  float* out_x  = (float*)d_out;                    // [8192][768] fp32, residual master
  float* out_xe = out_x + (size_t)Mx * 768;         // [2056][768] fp32 pass-through

  char* ws = (char*)d_ws;
  size_t off = 0;
  auto alloc = [&](size_t elems) {
    u16* p = (u16*)(ws + off);
    off = (off + elems * 2 + 255) & ~(size_t)255;
    return p;
  };
  u16* wt_attn  = alloc((size_t)2304 * 768);
  u16* wt_proj  = alloc((size_t)768 * 768);
  u16* wt_img   = alloc((size_t)1536 * 768);
  u16* wt_cap   = alloc((size_t)768 * 768);
  u16* wt_cross = alloc((size_t)768 * 768);
  u16* wt_ad1   = alloc((size_t)192 * 768);         // unpadded N=192
  u16* wt_ad2   = alloc((size_t)768 * 192);         // unpadded K=192
  u16* wt_fc    = alloc((size_t)3072 * 768);
  u16* wt_mproj = alloc((size_t)768 * 3072);
  u16* hbuf     = alloc((size_t)Mx * 768);          // LN outputs (h / hq / hm)
  u16* big      = alloc((size_t)Mx * 3072);         // qkv | q2+kv | mlp hidden
  u16* p0       = alloc((size_t)Mx * 768);
  u16* p1       = alloc((size_t)Mx * 768);
  u16* hid      = alloc((size_t)Mx * 192);          // adapter hidden (native 192)
  u16* q2  = big;                                   // [8192][768]
  u16* kvb = big + (size_t)Mx * 768;                // [2176][1536]

  // x_enc pass-through
  hipMemcpyAsync(out_xe, x_enc, (size_t)Me * 768 * 4, hipMemcpyDeviceToDevice, stream);

  // ---- batched weight convert+transpose (one launch for all 9) ----
  TrBatch tb;
  int nt = 0;
  tb.tstart[0] = 0;
  auto addT = [&](const float* W, u16* Bt, int K, int N, int Kp, int Np) {
    tb.W[nt] = W; tb.Bt[nt] = Bt; tb.K[nt] = K; tb.N[nt] = N;
    tb.Kpad[nt] = Kp; tb.Npad[nt] = Np;
    tb.tstart[nt + 1] = tb.tstart[nt] + (Np / 64) * (Kp / 64);
    ++nt;
  };
  addT(attn_w, wt_attn, 768, 2304, 768, 2304);
  addT(proj_w, wt_proj, 768, 768, 768, 768);
  addT(img_w, wt_img, 768, 1536, 768, 1536);
  addT(cap_w, wt_cap, 768, 768, 768, 768);
  addT(cross_w, wt_cross, 768, 768, 768, 768);
  addT(ad1_w, wt_ad1, 768, 192, 768, 192);
  addT(ad2_w, wt_ad2, 192, 768, 192, 768);
  addT(fc_w, wt_fc, 768, 3072, 768, 3072);
  addT(mproj_w, wt_mproj, 3072, 768, 3072, 768);
  transpose_all<<<tb.tstart[9], 256, 0, stream>>>(tb);

  // Routing: gemm_bt_dp (depth-2 pipeline, 128x256) for fc/qkv; gemm_bt (128x128) for dual;
  // gemm_bt_m64 for low-grid latency-bound (proj/cross/mproj/ad2); gemm_bt_6464 for ad1.
  auto GEMM_DP = [&](const u16* A, const u16* Bt, void* C, const float* bias,
                     int M, int N, int K, int ldc, int nbias, int mode) {
    dim3 g(M / 128, N / 256);   // M fastest: consecutive blocks share the B(weight)-panel
    if (mode == 0) gemm_bt_dp<0><<<g, 512, 0, stream>>>(A, Bt, C, bias, K, ldc, nbias);
    else           gemm_bt_dp<2><<<g, 512, 0, stream>>>(A, Bt, C, bias, K, ldc, nbias);
  };
  auto GEMM_M64 = [&](const u16* A, const u16* Bt, void* C, const float* bias,
                      int M, int N, int K, int ldc, int nbias, int mode) {
    dim3 g(M / 64, N / 128);    // M fastest
    if (mode == 0) gemm_bt_m64<0><<<g, 256, 0, stream>>>(A, Bt, C, bias, K, ldc, nbias);
    else           gemm_bt_m64<1><<<g, 256, 0, stream>>>(A, Bt, C, bias, K, ldc, nbias);
  };
  auto ADAPTER = [&](const u16* in, u16* padw) {   // padw = adapter(in) incl. bias, bf16
    dim3 g1(Mx / 64, 192 / 64);                    // 128 x 3 = 384 blocks
    gemm_bt_6464<1><<<g1, 256, 0, stream>>>(in, wt_ad1, hid, ad1_b, 768, 192, 192);
    GEMM_M64(hid, wt_ad2, padw, ad2_b, Mx, 768, 192, 768, 768, 0);  // K=192: 3 ktiles
  };

  // ---- init: out_x = x; hbuf = ln1(out_x) (fused copy+LN) ----
  resid_ln<true, false><<<Mx, 64, 0, stream>>>(x, out_x, nullptr, ln1_g, ln1_b, hbuf);

  // ---- causal self-attention branch (single-pass, normalized -> p0) ----
  GEMM_DP(hbuf, wt_attn, big, attn_bias, Mx, 2304, 768, 2304, 2304, 0); // qkv (64x9=576 blk)
  attn_mfma<true><<<dim3(96, 8), 512, 0, stream>>>(
      big, big, big, p0, 1024, 2304, 2304,
      (long long)1024 * 2304, (long long)1024 * 2304, 0, 768, 1536);
  GEMM_M64(p0, wt_proj, p1, proj_b, Mx, 768, 768, 768, 768, 0);        // sa (768 blocks)
  ADAPTER(p1, p0);
  resid_ln<true, true><<<Mx, 64, 0, stream>>>(out_x, out_x, p0, ln1_g, ln1_b, hbuf);  // hq

  // ---- cross-attention branch (kv + q2 GEMMs fused into one dispatch) ----
  ln_kernel<<<MeP, 64, 0, stream>>>(x_enc, ln3_g, ln3_b, p0, Me);      // he (padded rows zero)
  {
    GemmJob jkv = { p0,   wt_img, kvb, img_b, 768, 1536, 1536, MeP / 128 };  // 17x12 = 204
    GemmJob jq2 = { hbuf, wt_cap, q2,  cap_b, 768, 768,  768,  Mx / 128 };   // 64x6  = 384
    const int split = (MeP / 128) * (1536 / 128);
    const int total = split + (Mx / 128) * (768 / 128);
    gemm_bt_dual<<<total, 256, 0, stream>>>(jkv, jq2, split);
  }
  attn_mfma<false><<<dim3(96, 8), 512, 0, stream>>>(
      q2, kvb, kvb, p1, 257, 768, 1536,
      (long long)1024 * 768, (long long)257 * 1536, 0, 0, 768);
  GEMM_M64(p1, wt_cross, p0, cross_b, Mx, 768, 768, 768, 768, 0);      // ca (768 blocks)
  ADAPTER(p0, p1);
  resid_ln<true, true><<<Mx, 64, 0, stream>>>(out_x, out_x, p1, ln2_g, ln2_b, hbuf);  // hm

  // ---- MLP branch ----
  GEMM_DP(hbuf, wt_fc, big, fc_b, Mx, 3072, 768, 3072, 3072, 2);       // fc (64x12=768 blk)
  GEMM_M64(big, wt_mproj, p0, mproj_b, Mx, 768, 3072, 768, 768, 0);    // mproj (768 blocks)
  ADAPTER(p0, p1);
  resid_ln<false, true><<<Mx, 64, 0, stream>>>(out_x, out_x, p1, nullptr, nullptr, nullptr);

  (void)in_sizes; (void)n_in; (void)out_size; (void)ws_size;
}

// Round 15
// 418.839 us; speedup vs baseline: 1.0674x; 1.0674x over previous
//
#include <hip/hip_runtime.h>

typedef unsigned short u16;
typedef short bf16x8 __attribute__((ext_vector_type(8)));
typedef float f32x4 __attribute__((ext_vector_type(4)));
typedef unsigned short u16x4 __attribute__((ext_vector_type(4)));

__device__ __forceinline__ u16 f2bf(float f) {
  union { float f; unsigned u; } v; v.f = f;
  unsigned u = v.u;
  unsigned r = (u + 0x7FFFu + ((u >> 16) & 1u)) >> 16;
  return (u16)r;
}
__device__ __forceinline__ float bf2f(u16 h) {
  union { unsigned u; float f; } v; v.u = ((unsigned)h) << 16;
  return v.f;
}
// packed f32x2 -> bf16x2 (RTNE, matches f2bf); 1 inst per 2 values
__device__ __forceinline__ unsigned cvt_pk_bf16(float lo, float hi) {
  unsigned d;
  asm("v_cvt_pk_bf16_f32 %0, %1, %2" : "=v"(d) : "v"(lo), "v"(hi));
  return d;
}
// gelu(x) = x * sigmoid(1.5957691(x+0.044715x^3)); exp2-domain (log2e folded), rcp approx.
__device__ __forceinline__ float gelu_f(float x) {
  const float c1 = -2.302585093f;          // -1.5957691216 * log2(e)
  const float c2 = -0.1029620967f;         // c1 * 0.044715
  float t = __builtin_fmaf(x * x, c2, c1) * x;
  float e = exp2f(t);
  return x * __builtin_amdgcn_rcpf(e + 1.0f);
}

#define GLD_LDS16(gp, lp)                                             \
  __builtin_amdgcn_global_load_lds(                                   \
      (const __attribute__((address_space(1))) void*)(gp),            \
      (__attribute__((address_space(3))) void*)(lp), 16, 0, 0)

// ds_read_b64_tr_b16 semantics (m156/m162): per 16-lane group, lane l elem e receives
// u16 #(l&3) of the 8-byte block addressed by lane (4e + ((l&15)>>2)) of the group.
// With per-lane addr = base + 8*lane over a blocked layout (4 q/d per 8B block), this
// delivers transposed MFMA fragments conflict-free. OFF is an additive byte immediate.
template<int OFF>
__device__ __forceinline__ u16x4 tr16(unsigned a) {
  u16x4 d;
  asm volatile("ds_read_b64_tr_b16 %0, %1 offset:%2" : "=&v"(d) : "v"(a), "n"(OFF));
  return d;
}
// bit-preserving pack of two u16x4 into one bf16x8 (avoids narrowing diagnostics)
__device__ __forceinline__ bf16x8 pack8(u16x4 a, u16x4 b) {
  union { u16x4 p[2]; bf16x8 v; } u;
  u.p[0] = a; u.p[1] = b;
  return u.v;
}
// two packed-bf16 words -> u16x4 (for b64 LDS store)
__device__ __forceinline__ u16x4 pack4(unsigned w0, unsigned w1) {
  union { unsigned w[2]; u16x4 v; } u;
  u.w[0] = w0; u.w[1] = w1;
  return u.v;
}

// ---------------- batched weight transpose+convert: W[K][N] f32 -> Bt[Npad][Kpad] bf16 ------
struct TrBatch {
  const float* W[9];
  u16* Bt[9];
  int K[9], N[9], Kpad[9], Npad[9];
  int tstart[10];   // prefix sum of (Npad/64)*(Kpad/64)
};
__global__ __launch_bounds__(256)
void transpose_all(TrBatch tb) {
  __shared__ float tile[64][65];
  const int tid = blockIdx.x;
  int mi = 0;
  while (mi < 8 && tid >= tb.tstart[mi + 1]) ++mi;
  const int lt = tid - tb.tstart[mi];
  const int tx = tb.Npad[mi] >> 6;
  const int n0 = (lt % tx) * 64;
  const int k0 = (lt / tx) * 64;
  const float* W = tb.W[mi];
  u16* Bt = tb.Bt[mi];
  const int K = tb.K[mi], N = tb.N[mi], Kpad = tb.Kpad[mi];
  const int t = threadIdx.x;
  const int c = t & 63;
  const int rb = t >> 6;
#pragma unroll
  for (int i = 0; i < 16; ++i) {
    int r = i * 4 + rb;
    float v = 0.f;
    if (k0 + r < K && n0 + c < N) v = W[(size_t)(k0 + r) * N + n0 + c];
    tile[r][c] = v;
  }
  __syncthreads();
#pragma unroll
  for (int i = 0; i < 16; ++i) {
    int r = i * 4 + rb;  // row in N-dim
    Bt[(size_t)(n0 + r) * Kpad + k0 + c] = f2bf(tile[c][r]);
  }
}

// ---------------- layernorm: fp32 [M][768] -> bf16 [Mpad][768], pad rows zeroed -------------
__global__ __launch_bounds__(64)
void ln_kernel(const float* __restrict__ X, const float* __restrict__ G,
               const float* __restrict__ Bv, u16* __restrict__ O, int Mreal) {
  const int row = blockIdx.x;
  const int l = threadIdx.x;
  u16* op = O + (size_t)row * 768;
  if (row >= Mreal) {
    u16x4 z = {0, 0, 0, 0};
#pragma unroll
    for (int i = 0; i < 3; ++i) *(u16x4*)(op + (i * 64 + l) * 4) = z;
    return;
  }
  const float* xp = X + (size_t)row * 768;
  float v[12];
  float s = 0.f, s2 = 0.f;
#pragma unroll
  for (int i = 0; i < 3; ++i) {
    float4 t4 = *(const float4*)(xp + (i * 64 + l) * 4);
    v[i * 4 + 0] = t4.x; v[i * 4 + 1] = t4.y; v[i * 4 + 2] = t4.z; v[i * 4 + 3] = t4.w;
    s += t4.x + t4.y + t4.z + t4.w;
    s2 += t4.x * t4.x + t4.y * t4.y + t4.z * t4.z + t4.w * t4.w;
  }
#pragma unroll
  for (int off = 32; off > 0; off >>= 1) {
    s += __shfl_xor(s, off);
    s2 += __shfl_xor(s2, off);
  }
  const float mean = s * (1.0f / 768.0f);
  const float var = s2 * (1.0f / 768.0f) - mean * mean;
  const float rstd = rsqrtf(var + 1e-5f);
#pragma unroll
  for (int i = 0; i < 3; ++i) {
    int base = (i * 64 + l) * 4;
    float4 g4 = *(const float4*)(G + base);
    float4 b4 = *(const float4*)(Bv + base);
    u16x4 o4;
    o4[0] = f2bf((v[i * 4 + 0] - mean) * rstd * g4.x + b4.x);
    o4[1] = f2bf((v[i * 4 + 1] - mean) * rstd * g4.y + b4.y);
    o4[2] = f2bf((v[i * 4 + 2] - mean) * rstd * g4.z + b4.z);
    o4[3] = f2bf((v[i * 4 + 3] - mean) * rstd * g4.w + b4.w);
    *(u16x4*)(op + base) = o4;
  }
}

// ---------------- fused residual-add (+optional LN): D = S (+P);  O = LN(D)*G+B -------------
template<bool DOLN, bool RESID>
__global__ __launch_bounds__(64)
void resid_ln(const float* __restrict__ S, float* __restrict__ D,
              const u16* __restrict__ P,
              const float* __restrict__ G, const float* __restrict__ Bv,
              u16* __restrict__ O) {
  const int row = blockIdx.x;
  const int l = threadIdx.x;
  const float* sp = S + (size_t)row * 768;
  float* dp = D + (size_t)row * 768;
  float v[12];
  float s = 0.f, s2 = 0.f;
#pragma unroll
  for (int i = 0; i < 3; ++i) {
    const int base = (i * 64 + l) * 4;
    float4 t4 = *(const float4*)(sp + base);
    if (RESID) {
      u16x4 p4 = *(const u16x4*)(P + (size_t)row * 768 + base);
      t4.x += bf2f(p4[0]); t4.y += bf2f(p4[1]);
      t4.z += bf2f(p4[2]); t4.w += bf2f(p4[3]);
    }
    v[i * 4 + 0] = t4.x; v[i * 4 + 1] = t4.y; v[i * 4 + 2] = t4.z; v[i * 4 + 3] = t4.w;
    s += t4.x + t4.y + t4.z + t4.w;
    s2 += t4.x * t4.x + t4.y * t4.y + t4.z * t4.z + t4.w * t4.w;
    *(float4*)(dp + base) = t4;
  }
  if (DOLN) {
#pragma unroll
    for (int off = 32; off > 0; off >>= 1) {
      s += __shfl_xor(s, off);
      s2 += __shfl_xor(s2, off);
    }
    const float mean = s * (1.0f / 768.0f);
    const float var = s2 * (1.0f / 768.0f) - mean * mean;
    const float rstd = rsqrtf(var + 1e-5f);
    u16* op = O + (size_t)row * 768;
#pragma unroll
    for (int i = 0; i < 3; ++i) {
      int base = (i * 64 + l) * 4;
      float4 g4 = *(const float4*)(G + base);
      float4 b4 = *(const float4*)(Bv + base);
      u16x4 o4;
      o4[0] = f2bf((v[i * 4 + 0] - mean) * rstd * g4.x + b4.x);
      o4[1] = f2bf((v[i * 4 + 1] - mean) * rstd * g4.y + b4.y);
      o4[2] = f2bf((v[i * 4 + 2] - mean) * rstd * g4.z + b4.z);
      o4[3] = f2bf((v[i * 4 + 3] - mean) * rstd * g4.w + b4.w);
      *(u16x4*)(op + base) = o4;
    }
  }
}

// ---------------- GEMM 128x128, BK=64, split-half LDS (rule #21 staging) --------------------
// MODE 0: store bf16   1: relu->bf16   2: gelu->bf16
// 4-wave 1-phase structure. Chunk-XOR bank swizzle (R6: SQ_LDS_BANK_CONFLICT 4.7M -> 0).
// cvt_pk epilogue. For high-occupancy grids (qkv/fc/dual) where inter-block TLP hides
// the stage drain. R14 falsified the depth-2 pipelined 128x256 alternative (1 block/CU
// lost the inter-block TLP: 58.8 -> 75.2 us). No XCD swizzle (L3-resident working set).
template<int MODE>
__global__ void gemm_bt(const u16* __restrict__ A, const u16* __restrict__ Bt,
                        void* __restrict__ C, const float* __restrict__ bias,
                        int K, int ldc, int nbias) {
  __shared__ u16 As[2 * 128 * 32];   // [ks][row][chunk-swizzled][8]
  __shared__ u16 Bs[2 * 128 * 32];
  const int t = threadIdx.x;
  const int lane = t & 63;
  const int wid = t >> 6;
  const int wm = (wid >> 1) * 64;
  const int wn = (wid & 1) * 64;
  const int tm = blockIdx.x * 128;
  const int tn = blockIdx.y * 128;

  f32x4 zero = {0.f, 0.f, 0.f, 0.f};
  f32x4 acc[4][4];
#pragma unroll
  for (int i = 0; i < 4; ++i)
#pragma unroll
    for (int j = 0; j < 4; ++j) acc[i][j] = zero;

  const int rowA = lane & 15;
  const int kb = (((lane >> 4) ^ ((rowA >> 1) & 3)) << 3);   // swizzled chunk slot
  const int kTiles = K >> 6;
  for (int kt = 0; kt < kTiles; ++kt) {
    const int kk = kt << 6;
#pragma unroll
    for (int i = 0; i < 4; ++i) {
      const int c = i * 256 + t;                       // linear LDS slot index
      const int r = (c >> 2) & 127;                    // permuted global row
      const int cc = ((c >> 9) << 5) + ((((c & 3) ^ ((r >> 1) & 3))) << 3); // swizzled k-chunk
      GLD_LDS16(A + (size_t)(tm + r) * K + kk + cc, As + c * 8);
      GLD_LDS16(Bt + (size_t)(tn + r) * K + kk + cc, Bs + c * 8);
    }
    __syncthreads();
#pragma unroll
    for (int ks = 0; ks < 2; ++ks) {
      bf16x8 af[4], bfr[4];
      const int base = ks * 4096;
#pragma unroll
      for (int i = 0; i < 4; ++i) {
        af[i] = *(const bf16x8*)(As + base + (wm + i * 16 + rowA) * 32 + kb);
        bfr[i] = *(const bf16x8*)(Bs + base + (wn + i * 16 + rowA) * 32 + kb);
      }
#pragma unroll
      for (int mi = 0; mi < 4; ++mi)
#pragma unroll
        for (int ni = 0; ni < 4; ++ni)
          acc[mi][ni] = __builtin_amdgcn_mfma_f32_16x16x32_bf16(af[mi], bfr[ni], acc[mi][ni], 0, 0, 0);
    }
    __syncthreads();
  }
  const int col0 = lane & 15;
  const int row0 = (lane >> 4) << 2;
#pragma unroll
  for (int mi = 0; mi < 4; ++mi) {
#pragma unroll
    for (int ni = 0; ni < 4; ++ni) {
      int col = tn + wn + ni * 16 + col0;
      float bb = (col < nbias) ? bias[col] : 0.f;
      float vv[4];
#pragma unroll
      for (int r = 0; r < 4; ++r) {
        float v = acc[mi][ni][r] + bb;
        if (MODE == 1) v = fmaxf(v, 0.f);
        else if (MODE == 2) v = gelu_f(v);
        vv[r] = v;
      }
      unsigned w0 = cvt_pk_bf16(vv[0], vv[1]);
      unsigned w1 = cvt_pk_bf16(vv[2], vv[3]);
      size_t row = (size_t)(tm + wm + mi * 16 + row0);
      u16* cp = (u16*)C + row * ldc + col;
      cp[0] = (u16)w0;
      cp[(size_t)ldc] = (u16)(w0 >> 16);
      cp[(size_t)ldc * 2] = (u16)w1;
      cp[(size_t)ldc * 3] = (u16)(w1 >> 16);
    }
  }
}

// ---------------- 64x128 M-split GEMM for low-grid latency-bound dispatches -----------------
// R11 WIN: doubles the grid (3/CU) with A-traffic unchanged (FETCH stayed 43 MB) by
// splitting M and making M fastest so consecutive blocks share the B(weight)-panel.
// 4 waves: wave w = cols [w*32,w*32+32), all 64 rows; acc[4][2]. LDS 24 KB. MODE 0/1.
template<int MODE>
__global__ __launch_bounds__(256)
void gemm_bt_m64(const u16* __restrict__ A, const u16* __restrict__ Bt,
                 void* __restrict__ C, const float* __restrict__ bias,
                 int K, int ldc, int nbias) {
  __shared__ u16 As[2 * 64 * 32];    // [ks][row 0..63][chunk-swizzled][8]   8 KB
  __shared__ u16 Bs[2 * 128 * 32];   // [ks][ncol 0..127][chunk-swizzled][8] 16 KB
  const int t = threadIdx.x;
  const int lane = t & 63;
  const int wid = t >> 6;
  const int wn = wid * 32;                 // wave's 32-col strip
  const int tm = blockIdx.x * 64;          // M fastest: consecutive blocks share B-panel
  const int tn = blockIdx.y * 128;

  f32x4 zero = {0.f, 0.f, 0.f, 0.f};
  f32x4 acc[4][2];
#pragma unroll
  for (int i = 0; i < 4; ++i)
#pragma unroll
    for (int j = 0; j < 2; ++j) acc[i][j] = zero;

  const int rowA = lane & 15;
  const int kb = (((lane >> 4) ^ ((rowA >> 1) & 3)) << 3);
  const int kTiles = K >> 6;
  for (int kt = 0; kt < kTiles; ++kt) {
    const int kk = kt << 6;
#pragma unroll
    for (int i = 0; i < 2; ++i) {          // A: 512 slots, 2/thread
      const int c = i * 256 + t;
      const int r = (c >> 2) & 63;
      const int cc = ((c >> 8) << 5) + ((((c & 3) ^ ((r >> 1) & 3))) << 3);
      GLD_LDS16(A + (size_t)(tm + r) * K + kk + cc, As + c * 8);
    }
#pragma unroll
    for (int i = 0; i < 4; ++i) {          // B: 1024 slots, 4/thread
      const int c = i * 256 + t;
      const int r = (c >> 2) & 127;
      const int cc = ((c >> 9) << 5) + ((((c & 3) ^ ((r >> 1) & 3))) << 3);
      GLD_LDS16(Bt + (size_t)(tn + r) * K + kk + cc, Bs + c * 8);
    }
    __syncthreads();
#pragma unroll
    for (int ks = 0; ks < 2; ++ks) {
      bf16x8 af[4], bfr[2];
#pragma unroll
      for (int i = 0; i < 4; ++i)
        af[i] = *(const bf16x8*)(As + ks * 2048 + (i * 16 + rowA) * 32 + kb);
#pragma unroll
      for (int j = 0; j < 2; ++j)
        bfr[j] = *(const bf16x8*)(Bs + ks * 4096 + (wn + j * 16 + rowA) * 32 + kb);
#pragma unroll
      for (int mi = 0; mi < 4; ++mi)
#pragma unroll
        for (int ni = 0; ni < 2; ++ni)
          acc[mi][ni] = __builtin_amdgcn_mfma_f32_16x16x32_bf16(af[mi], bfr[ni], acc[mi][ni], 0, 0, 0);
    }
    __syncthreads();
  }
  const int col0 = lane & 15;
  const int row0 = (lane >> 4) << 2;
#pragma unroll
  for (int mi = 0; mi < 4; ++mi) {
#pragma unroll
    for (int ni = 0; ni < 2; ++ni) {
      int col = tn + wn + ni * 16 + col0;
      float bb = (col < nbias) ? bias[col] : 0.f;
      float vv[4];
#pragma unroll
      for (int r = 0; r < 4; ++r) {
        float v = acc[mi][ni][r] + bb;
        if (MODE == 1) v = fmaxf(v, 0.f);
        vv[r] = v;
      }
      unsigned w0 = cvt_pk_bf16(vv[0], vv[1]);
      unsigned w1 = cvt_pk_bf16(vv[2], vv[3]);
      size_t row = (size_t)(tm + mi * 16 + row0);
      u16* cp = (u16*)C + row * ldc + col;
      cp[0] = (u16)w0;
      cp[(size_t)ldc] = (u16)(w0 >> 16);
      cp[(size_t)ldc * 2] = (u16)w1;
      cp[(size_t)ldc * 3] = (u16)(w1 >> 16);
    }
  }
}

// ---------------- 64x64 GEMM for ad1 (N=192 unpadded; R13) ----------------------------------
// Native N=192 needs a 64-col tile: grid (M/64, N/64), M fastest (B-panel shared). 4 waves:
// wave w = cols [w*16, w*16+16), all 64 rows; acc[4]. LDS 16 KB. MODE 1 (relu).
template<int MODE>
__global__ __launch_bounds__(256)
void gemm_bt_6464(const u16* __restrict__ A, const u16* __restrict__ Bt,
                  void* __restrict__ C, const float* __restrict__ bias,
                  int K, int ldc, int nbias) {
  __shared__ u16 As[2 * 64 * 32];    // 8 KB
  __shared__ u16 Bs[2 * 64 * 32];    // 8 KB
  const int t = threadIdx.x;
  const int lane = t & 63;
  const int wid = t >> 6;
  const int wn = wid * 16;                 // wave's 16-col strip
  const int tm = blockIdx.x * 64;          // M fastest
  const int tn = blockIdx.y * 64;

  f32x4 acc[4];
#pragma unroll
  for (int i = 0; i < 4; ++i) acc[i] = (f32x4){0.f, 0.f, 0.f, 0.f};

  const int rowA = lane & 15;
  const int kb = (((lane >> 4) ^ ((rowA >> 1) & 3)) << 3);
  const int kTiles = K >> 6;
  for (int kt = 0; kt < kTiles; ++kt) {
    const int kk = kt << 6;
#pragma unroll
    for (int i = 0; i < 2; ++i) {          // A and B: 512 slots each, 2/thread each
      const int c = i * 256 + t;
      const int r = (c >> 2) & 63;
      const int cc = ((c >> 8) << 5) + ((((c & 3) ^ ((r >> 1) & 3))) << 3);
      GLD_LDS16(A + (size_t)(tm + r) * K + kk + cc, As + c * 8);
      GLD_LDS16(Bt + (size_t)(tn + r) * K + kk + cc, Bs + c * 8);
    }
    __syncthreads();
#pragma unroll
    for (int ks = 0; ks < 2; ++ks) {
      bf16x8 af[4], bfr;
#pragma unroll
      for (int i = 0; i < 4; ++i)
        af[i] = *(const bf16x8*)(As + ks * 2048 + (i * 16 + rowA) * 32 + kb);
      bfr = *(const bf16x8*)(Bs + ks * 2048 + (wn + rowA) * 32 + kb);
#pragma unroll
      for (int mi = 0; mi < 4; ++mi)
        acc[mi] = __builtin_amdgcn_mfma_f32_16x16x32_bf16(af[mi], bfr, acc[mi], 0, 0, 0);
    }
    __syncthreads();
  }
  const int col0 = lane & 15;
  const int row0 = (lane >> 4) << 2;
#pragma unroll
  for (int mi = 0; mi < 4; ++mi) {
    int col = tn + wn + col0;
    float bb = (col < nbias) ? bias[col] : 0.f;
    float vv[4];
#pragma unroll
    for (int r = 0; r < 4; ++r) {
      float v = acc[mi][r] + bb;
      if (MODE == 1) v = fmaxf(v, 0.f);
      vv[r] = v;
    }
    unsigned w0 = cvt_pk_bf16(vv[0], vv[1]);
    unsigned w1 = cvt_pk_bf16(vv[2], vv[3]);
    size_t row = (size_t)(tm + mi * 16 + row0);
    u16* cp = (u16*)C + row * ldc + col;
    cp[0] = (u16)w0;
    cp[(size_t)ldc] = (u16)(w0 >> 16);
    cp[(size_t)ldc * 2] = (u16)w1;
    cp[(size_t)ldc * 3] = (u16)(w1 >> 16);
  }
}

// ---------------- dual GEMM: two independent mode-0 GEMMs fused into one dispatch -----------
struct GemmJob {
  const u16* A; const u16* Bt; u16* C; const float* bias;
  int K, ldc, nbias, mblocks;
};
__global__ __launch_bounds__(256)
void gemm_bt_dual(GemmJob j0, GemmJob j1, int split) {
  __shared__ u16 As[2 * 128 * 32];
  __shared__ u16 Bs[2 * 128 * 32];
  const int bid = blockIdx.x;
  const GemmJob& J = (bid < split) ? j0 : j1;
  const int lb = (bid < split) ? bid : bid - split;
  const int tm = (lb % J.mblocks) * 128;
  const int tn = (lb / J.mblocks) * 128;
  const u16* A = J.A;
  const u16* Bt = J.Bt;
  const int K = J.K;

  const int t = threadIdx.x;
  const int lane = t & 63;
  const int wid = t >> 6;
  const int wm = (wid >> 1) * 64;
  const int wn = (wid & 1) * 64;

  f32x4 zero = {0.f, 0.f, 0.f, 0.f};
  f32x4 acc[4][4];
#pragma unroll
  for (int i = 0; i < 4; ++i)
#pragma unroll
    for (int j = 0; j < 4; ++j) acc[i][j] = zero;

  const int rowA = lane & 15;
  const int kb = (((lane >> 4) ^ ((rowA >> 1) & 3)) << 3);
  const int kTiles = K >> 6;
  for (int kt = 0; kt < kTiles; ++kt) {
    const int kk = kt << 6;
#pragma unroll
    for (int i = 0; i < 4; ++i) {
      const int c = i * 256 + t;
      const int r = (c >> 2) & 127;
      const int cc = ((c >> 9) << 5) + ((((c & 3) ^ ((r >> 1) & 3))) << 3);
      GLD_LDS16(A + (size_t)(tm + r) * K + kk + cc, As + c * 8);
      GLD_LDS16(Bt + (size_t)(tn + r) * K + kk + cc, Bs + c * 8);
    }
    __syncthreads();
#pragma unroll
    for (int ks = 0; ks < 2; ++ks) {
      bf16x8 af[4], bfr[4];
      const int base = ks * 4096;
#pragma unroll
      for (int i = 0; i < 4; ++i) {
        af[i] = *(const bf16x8*)(As + base + (wm + i * 16 + rowA) * 32 + kb);
        bfr[i] = *(const bf16x8*)(Bs + base + (wn + i * 16 + rowA) * 32 + kb);
      }
#pragma unroll
      for (int mi = 0; mi < 4; ++mi)
#pragma unroll
        for (int ni = 0; ni < 4; ++ni)
          acc[mi][ni] = __builtin_amdgcn_mfma_f32_16x16x32_bf16(af[mi], bfr[ni], acc[mi][ni], 0, 0, 0);
    }
    __syncthreads();
  }
  const int col0 = lane & 15;
  const int row0 = (lane >> 4) << 2;
#pragma unroll
  for (int mi = 0; mi < 4; ++mi) {
#pragma unroll
    for (int ni = 0; ni < 4; ++ni) {
      int col = tn + wn + ni * 16 + col0;
      float bb = (col < J.nbias) ? J.bias[col] : 0.f;
      unsigned w0 = cvt_pk_bf16(acc[mi][ni][0] + bb, acc[mi][ni][1] + bb);
      unsigned w1 = cvt_pk_bf16(acc[mi][ni][2] + bb, acc[mi][ni][3] + bb);
      size_t row = (size_t)(tm + wm + mi * 16 + row0);
      u16* cp = J.C + row * J.ldc + col;
      cp[0] = (u16)w0;
      cp[(size_t)J.ldc] = (u16)(w0 >> 16);
      cp[(size_t)J.ldc * 2] = (u16)w1;
      cp[(size_t)J.ldc * 3] = (u16)(w1 >> 16);
    }
  }
}

// ---------------- MFMA flash attention, QBLK=128 + tr-read V/P ------------------------------
// Single-pass normalized output; QBLK=128 (512 threads, 8 waves): each staged K/V tile
// serves 128 q rows. Causal grid (B*H, 8): yq = 7-blockIdx.y (heavy first), kv tiles
// [0, 2*yq+2); mask on the last two (diagonal) tiles via kv>q. Softmax in exp2 domain,
// VALU-thinned; T13 defer-max (THR=8); rowsum-l via P x ones MFMA. LDS 32 KB.
// LDS layouts (per 64x64 kv tile, verified R3..R13):
//   Ks: [kv][dchunk ^ (kv&7)]*8  (XOR swizzle, conflict-free b128 r/w)
//   Vs/Ps: blocked-transpose layout for ds_read_b64_tr_b16 (canonical addr = base+8*lane)
template<bool CAUSAL>
__global__ __launch_bounds__(512)
void attn_mfma(const u16* __restrict__ Q, const u16* __restrict__ Kp,
               const u16* __restrict__ Vp, u16* __restrict__ O,
               int seqkv, int qrs, int krs,
               long long qBatch, long long kBatch,
               int qoff, int koff, int voff) {
  __shared__ __align__(16) u16 Ks[64 * 64];
  __shared__ __align__(16) u16 Vs[4096];
  __shared__ __align__(16) u16 Ps[8][1024];
  const int t = threadIdx.x;
  const int lane = t & 63;
  const int wid = t >> 6;                 // 0..7
  const int b = blockIdx.x / 12, h = blockIdx.x % 12;
  const int yq = CAUSAL ? ((int)gridDim.y - 1 - (int)blockIdx.y) : (int)blockIdx.y;
  const int q0 = yq * 128;
  const int colid = lane & 15;
  const int rgrp = lane >> 4;

  const int kt_end = CAUSAL ? (2 * yq + 2) : ((seqkv + 63) >> 6);

  const u16* qp = Q + (size_t)b * qBatch + qoff + (size_t)(q0 + wid * 16 + colid) * qrs + h * 64;
  bf16x8 qa[2];
#pragma unroll
  for (int s = 0; s < 2; ++s) qa[s] = *(const bf16x8*)(qp + s * 32 + (rgrp << 3));

  f32x4 oacc[4];
#pragma unroll
  for (int i = 0; i < 4; ++i) oacc[i] = (f32x4){0.f, 0.f, 0.f, 0.f};
  float m[4] = {-1e30f, -1e30f, -1e30f, -1e30f};
  float l[4] = {0.f, 0.f, 0.f, 0.f};

  // all-ones bf16 B-fragment for the P-rowsum MFMA
  const u16x4 one4 = {0x3F80, 0x3F80, 0x3F80, 0x3F80};
  const bf16x8 ones8 = pack8(one4, one4);

  const u16* kbase = Kp + (size_t)b * kBatch + koff + h * 64;
  const u16* vbase = Vp + (size_t)b * kBatch + voff + h * 64;

  // staging geometry: 512 threads cover the 64x64 tile exactly once:
  // thread -> kv row r = t>>3, d chunk sdc*8
  const int srr = t >> 3, sdc = t & 7;    // srr 0..63
  const int kwo = srr * 64 + ((sdc ^ (srr & 7)) << 3);
  const int vwo = ((sdc >> 1) << 10) + ((srr >> 5) << 9) + (((srr >> 2) & 1) << 8)
                + (((srr >> 3) & 3) << 6) + ((srr & 3) << 4) + (((2 * sdc) & 3) << 2);
  // canonical tr-read per-lane byte bases (low 32 bits of generic shared ptr = LDS offset)
  const unsigned vs_base = (unsigned)(size_t)&Vs[0] + 8u * (unsigned)lane;
  const unsigned ps_base = (unsigned)(size_t)&Ps[wid][0] + 8u * (unsigned)lane;

  bf16x8 kz, vz;
  auto LOADT = [&](int kt) {
    const int tk = kt * 64 + srr;
    const int dc = sdc << 3;
    kz = (bf16x8){0, 0, 0, 0, 0, 0, 0, 0};
    vz = (bf16x8){0, 0, 0, 0, 0, 0, 0, 0};
    if (tk < seqkv) {
      kz = *(const bf16x8*)(kbase + (size_t)tk * krs + dc);
      vz = *(const bf16x8*)(vbase + (size_t)tk * krs + dc);
    }
  };
  LOADT(0);

  constexpr float SC2 = 0.18033688011112042f;   // 0.125 * log2(e): exp2 domain

  for (int kt = 0; kt < kt_end; ++kt) {
    const int k0 = kt * 64;
    *(bf16x8*)&Ks[kwo] = kz;
    *(bf16x8*)&Vs[vwo] = vz;
    __syncthreads();
    if (kt + 1 < kt_end) LOADT(kt + 1);   // T14 prefetch

    // ---- S = Q.K^T (raw) ----
    f32x4 sacc[4];
#pragma unroll
    for (int c = 0; c < 4; ++c) sacc[c] = (f32x4){0.f, 0.f, 0.f, 0.f};
#pragma unroll
    for (int c = 0; c < 4; ++c)
#pragma unroll
      for (int s = 0; s < 2; ++s) {
        bf16x8 kf = *(const bf16x8*)&Ks[(c * 16 + colid) * 64 +
                                        ((((s << 2) + rgrp) ^ (colid & 7)) << 3)];
        sacc[c] = __builtin_amdgcn_mfma_f32_16x16x32_bf16(qa[s], kf, sacc[c], 0, 0, 0);
      }

    // ---- mask in raw domain (causal diagonal tiles / kv-padding tile only) ----
    const bool domask = CAUSAL ? (kt >= 2 * yq) : (kt == kt_end - 1);
    if (domask) {
#pragma unroll
      for (int c = 0; c < 4; ++c) {
        int kv = k0 + c * 16 + colid;
#pragma unroll
        for (int r = 0; r < 4; ++r) {
          int q = q0 + wid * 16 + rgrp * 4 + r;
          if ((CAUSAL && kv > q) || (!CAUSAL && kv >= seqkv)) sacc[c][r] = -1e30f;
        }
      }
    }

    // ---- row max over raw sacc, scaled once per row ----
    float pms[4];
#pragma unroll
    for (int r = 0; r < 4; ++r) {
      float v = fmaxf(fmaxf(sacc[0][r], sacc[1][r]), fmaxf(sacc[2][r], sacc[3][r]));
#pragma unroll
      for (int off = 1; off < 16; off <<= 1) v = fmaxf(v, __shfl_xor(v, off));
      pms[r] = v * SC2;
    }
    // ---- T13 defer-max: rescale only when some row exceeds m+8 (wave-uniform) ----
    bool ok = (pms[0] <= m[0] + 8.f) && (pms[1] <= m[1] + 8.f) &&
              (pms[2] <= m[2] + 8.f) && (pms[3] <= m[3] + 8.f);
    if (!__all(ok)) {
#pragma unroll
      for (int r = 0; r < 4; ++r) {
        float newm = fmaxf(m[r], pms[r]);
        float corr = exp2f(m[r] - newm);
        m[r] = newm;
        l[r] *= corr;
#pragma unroll
        for (int dc2 = 0; dc2 < 4; ++dc2) oacc[dc2][r] *= corr;
      }
    }

    // ---- P = exp2(fma(sacc, SC2, -m)) ----
    float pv[4][4];
#pragma unroll
    for (int c = 0; c < 4; ++c)
#pragma unroll
      for (int r = 0; r < 4; ++r)
        pv[c][r] = exp2f(__builtin_fmaf(sacc[c][r], SC2, -m[r]));

    // ---- P^T -> LDS (blocked layout): cvt_pk x2 + one b64 store per c ----
#pragma unroll
    for (int c = 0; c < 4; ++c) {
      unsigned w0 = cvt_pk_bf16(pv[c][0], pv[c][1]);
      unsigned w1 = cvt_pk_bf16(pv[c][2], pv[c][3]);
      const int pa = ((c >> 1) << 9) + (((colid >> 2) & 1) << 8)
                   + (((2 * c + (colid >> 3)) & 3) << 6) + ((colid & 3) << 4) + (rgrp << 2);
      *(u16x4*)&Ps[wid][pa] = pack4(w0, w1);
    }
    __builtin_amdgcn_sched_barrier(0);   // pin store->tr-read order (DS in-order per wave)

    // ---- pf via canonical tr reads ----
    u16x4 p00 = tr16<0>(ps_base);
    u16x4 p01 = tr16<512>(ps_base);
    u16x4 p10 = tr16<1024>(ps_base);
    u16x4 p11 = tr16<1536>(ps_base);
    asm volatile("s_waitcnt lgkmcnt(0)" ::: "memory");
    __builtin_amdgcn_sched_barrier(0);   // rule #18: fence MFMA hoisting past asm waitcnt
    bf16x8 pf0 = pack8(p00, p01);
    bf16x8 pf1 = pack8(p10, p11);

    // ---- l += rowsum(P) via P x ones MFMA ----
    f32x4 sum_acc = (f32x4){0.f, 0.f, 0.f, 0.f};
    sum_acc = __builtin_amdgcn_mfma_f32_16x16x32_bf16(pf0, ones8, sum_acc, 0, 0, 0);
    sum_acc = __builtin_amdgcn_mfma_f32_16x16x32_bf16(pf1, ones8, sum_acc, 0, 0, 0);

    // ---- O += P.V : per-d0 batch {tr_read x4, lgkmcnt(0), sched_barrier, 2 MFMA} ----
#pragma unroll
    for (int dc2 = 0; dc2 < 4; ++dc2) {
      const unsigned va = vs_base + (unsigned)(dc2 * 2048);
      u16x4 v00 = tr16<0>(va);
      u16x4 v01 = tr16<512>(va);
      u16x4 v10 = tr16<1024>(va);
      u16x4 v11 = tr16<1536>(va);
      asm volatile("s_waitcnt lgkmcnt(0)" ::: "memory");
      __builtin_amdgcn_sched_barrier(0);
      bf16x8 vf0 = pack8(v00, v01);
      bf16x8 vf1 = pack8(v10, v11);
      oacc[dc2] = __builtin_amdgcn_mfma_f32_16x16x32_bf16(pf0, vf0, oacc[dc2], 0, 0, 0);
      oacc[dc2] = __builtin_amdgcn_mfma_f32_16x16x32_bf16(pf1, vf1, oacc[dc2], 0, 0, 0);
    }
#pragma unroll
    for (int r = 0; r < 4; ++r) l[r] += sum_acc[r];
    __syncthreads();
  }

  // ---- epilogue: normalized write (cvt_pk conversions) ----
#pragma unroll
  for (int r = 0; r < 4; ++r) {
    int qrow = q0 + wid * 16 + rgrp * 4 + r;
    u16* op = O + ((size_t)b * 1024 + qrow) * 768 + h * 64;
    float inv = 1.f / l[r];
    unsigned w0 = cvt_pk_bf16(oacc[0][r] * inv, oacc[1][r] * inv);
    unsigned w1 = cvt_pk_bf16(oacc[2][r] * inv, oacc[3][r] * inv);
    op[colid] = (u16)w0;
    op[16 + colid] = (u16)(w0 >> 16);
    op[32 + colid] = (u16)w1;
    op[48 + colid] = (u16)(w1 >> 16);
  }
}

// =============================================================================================
extern "C" void kernel_launch(void* const* d_in, const int* in_sizes, int n_in,
                              void* d_out, int out_size, void* d_ws, size_t ws_size,
                              hipStream_t stream) {
  const float* x        = (const float*)d_in[0];
  const float* x_enc    = (const float*)d_in[1];
  const float* ln1_g    = (const float*)d_in[2];
  const float* ln1_b    = (const float*)d_in[3];
  const float* ln2_g    = (const float*)d_in[4];
  const float* ln2_b    = (const float*)d_in[5];
  const float* ln3_g    = (const float*)d_in[6];
  const float* ln3_b    = (const float*)d_in[7];
  const float* attn_w   = (const float*)d_in[8];
  const float* attn_bias= (const float*)d_in[9];
  const float* proj_w   = (const float*)d_in[10];
  const float* proj_b   = (const float*)d_in[11];
  const float* img_w    = (const float*)d_in[12];
  const float* img_b    = (const float*)d_in[13];
  const float* cap_w    = (const float*)d_in[14];
  const float* cap_b    = (const float*)d_in[15];
  const float* cross_w  = (const float*)d_in[16];
  const float* cross_b  = (const float*)d_in[17];
  const float* ad1_w    = (const float*)d_in[18];
  const float* ad1_b    = (const float*)d_in[19];
  const float* ad2_w    = (const float*)d_in[20];
  const float* ad2_b    = (const float*)d_in[21];
  const float* fc_w     = (const float*)d_in[22];
  const float* fc_b     = (const float*)d_in[23];
  const float* mproj_w  = (const float*)d_in[24];
  const float* mproj_b  = (const float*)d_in[25];

  const int Mx = 8192;            // B*T
  const int Me = 2056;            // B*N_ENC
  const int MeP = 2176;           // padded to 17*128

  float* out_x  = (float*)d_out;                    // [8192][768] fp32, residual master
  float* out_xe = out_x + (size_t)Mx * 768;         // [2056][768] fp32 pass-through

  char* ws = (char*)d_ws;
  size_t off = 0;
  auto alloc = [&](size_t elems) {
    u16* p = (u16*)(ws + off);
    off = (off + elems * 2 + 255) & ~(size_t)255;
    return p;
  };
  u16* wt_attn  = alloc((size_t)2304 * 768);
  u16* wt_proj  = alloc((size_t)768 * 768);
  u16* wt_img   = alloc((size_t)1536 * 768);
  u16* wt_cap   = alloc((size_t)768 * 768);
  u16* wt_cross = alloc((size_t)768 * 768);
  u16* wt_ad1   = alloc((size_t)192 * 768);         // unpadded N=192
  u16* wt_ad2   = alloc((size_t)768 * 192);         // unpadded K=192
  u16* wt_fc    = alloc((size_t)3072 * 768);
  u16* wt_mproj = alloc((size_t)768 * 3072);
  u16* hbuf     = alloc((size_t)Mx * 768);          // LN outputs (h / hq / hm)
  u16* big      = alloc((size_t)Mx * 3072);         // qkv | q2+kv | mlp hidden
  u16* p0       = alloc((size_t)Mx * 768);
  u16* p1       = alloc((size_t)Mx * 768);
  u16* hid      = alloc((size_t)Mx * 192);          // adapter hidden (native 192)
  u16* q2  = big;                                   // [8192][768]
  u16* kvb = big + (size_t)Mx * 768;                // [2176][1536]

  // x_enc pass-through
  hipMemcpyAsync(out_xe, x_enc, (size_t)Me * 768 * 4, hipMemcpyDeviceToDevice, stream);

  // ---- batched weight convert+transpose (one launch for all 9) ----
  TrBatch tb;
  int nt = 0;
  tb.tstart[0] = 0;
  auto addT = [&](const float* W, u16* Bt, int K, int N, int Kp, int Np) {
    tb.W[nt] = W; tb.Bt[nt] = Bt; tb.K[nt] = K; tb.N[nt] = N;
    tb.Kpad[nt] = Kp; tb.Npad[nt] = Np;
    tb.tstart[nt + 1] = tb.tstart[nt] + (Np / 64) * (Kp / 64);
    ++nt;
  };
  addT(attn_w, wt_attn, 768, 2304, 768, 2304);
  addT(proj_w, wt_proj, 768, 768, 768, 768);
  addT(img_w, wt_img, 768, 1536, 768, 1536);
  addT(cap_w, wt_cap, 768, 768, 768, 768);
  addT(cross_w, wt_cross, 768, 768, 768, 768);
  addT(ad1_w, wt_ad1, 768, 192, 768, 192);
  addT(ad2_w, wt_ad2, 192, 768, 192, 768);
  addT(fc_w, wt_fc, 768, 3072, 768, 3072);
  addT(mproj_w, wt_mproj, 3072, 768, 3072, 768);
  transpose_all<<<tb.tstart[9], 256, 0, stream>>>(tb);

  // gemm_bt (128x128) for high-occupancy grids (qkv/fc/dual); gemm_bt_m64 (64x128 M-split)
  // for latency-bound low-grid GEMMs; gemm_bt_6464 for ad1 (N=192).
  auto GEMM = [&](const u16* A, const u16* Bt, void* C, const float* bias,
                  int M, int N, int K, int ldc, int nbias, int mode) {
    dim3 g(M / 128, N / 128);
    if (mode == 0)      gemm_bt<0><<<g, 256, 0, stream>>>(A, Bt, C, bias, K, ldc, nbias);
    else if (mode == 1) gemm_bt<1><<<g, 256, 0, stream>>>(A, Bt, C, bias, K, ldc, nbias);
    else                gemm_bt<2><<<g, 256, 0, stream>>>(A, Bt, C, bias, K, ldc, nbias);
  };
  auto GEMM_M64 = [&](const u16* A, const u16* Bt, void* C, const float* bias,
                      int M, int N, int K, int ldc, int nbias, int mode) {
    dim3 g(M / 64, N / 128);    // M fastest: consecutive blocks share the B(weight)-panel
    if (mode == 0) gemm_bt_m64<0><<<g, 256, 0, stream>>>(A, Bt, C, bias, K, ldc, nbias);
    else           gemm_bt_m64<1><<<g, 256, 0, stream>>>(A, Bt, C, bias, K, ldc, nbias);
  };
  auto ADAPTER = [&](const u16* in, u16* padw) {   // padw = adapter(in) incl. bias, bf16
    dim3 g1(Mx / 64, 192 / 64);                    // 128 x 3 = 384 blocks
    gemm_bt_6464<1><<<g1, 256, 0, stream>>>(in, wt_ad1, hid, ad1_b, 768, 192, 192);
    GEMM_M64(hid, wt_ad2, padw, ad2_b, Mx, 768, 192, 768, 768, 0);  // K=192: 3 ktiles
  };

  // ---- init: out_x = x; hbuf = ln1(out_x) (fused copy+LN) ----
  resid_ln<true, false><<<Mx, 64, 0, stream>>>(x, out_x, nullptr, ln1_g, ln1_b, hbuf);

  // ---- causal self-attention branch (single-pass, normalized -> p0) ----
  GEMM(hbuf, wt_attn, big, attn_bias, Mx, 2304, 768, 2304, 2304, 0);   // qkv (1152 blocks)
  attn_mfma<true><<<dim3(96, 8), 512, 0, stream>>>(
      big, big, big, p0, 1024, 2304, 2304,
      (long long)1024 * 2304, (long long)1024 * 2304, 0, 768, 1536);
  GEMM_M64(p0, wt_proj, p1, proj_b, Mx, 768, 768, 768, 768, 0);        // sa (768 blocks)
  ADAPTER(p1, p0);
  resid_ln<true, true><<<Mx, 64, 0, stream>>>(out_x, out_x, p0, ln1_g, ln1_b, hbuf);  // hq

  // ---- cross-attention branch (kv + q2 GEMMs fused into one dispatch) ----
  ln_kernel<<<MeP, 64, 0, stream>>>(x_enc, ln3_g, ln3_b, p0, Me);      // he (padded rows zero)
  {
    GemmJob jkv = { p0,   wt_img, kvb, img_b, 768, 1536, 1536, MeP / 128 };  // 17x12 = 204
    GemmJob jq2 = { hbuf, wt_cap, q2,  cap_b, 768, 768,  768,  Mx / 128 };   // 64x6  = 384
    const int split = (MeP / 128) * (1536 / 128);
    const int total = split + (Mx / 128) * (768 / 128);
    gemm_bt_dual<<<total, 256, 0, stream>>>(jkv, jq2, split);
  }
  attn_mfma<false><<<dim3(96, 8), 512, 0, stream>>>(
      q2, kvb, kvb, p1, 257, 768, 1536,
      (long long)1024 * 768, (long long)257 * 1536, 0, 0, 768);
  GEMM_M64(p1, wt_cross, p0, cross_b, Mx, 768, 768, 768, 768, 0);      // ca (768 blocks)
  ADAPTER(p0, p1);
  resid_ln<true, true><<<Mx, 64, 0, stream>>>(out_x, out_x, p1, ln2_g, ln2_b, hbuf);  // hm

  // ---- MLP branch ----
  GEMM(hbuf, wt_fc, big, fc_b, Mx, 3072, 768, 3072, 3072, 2);          // fc (1536 blocks)
  GEMM_M64(big, wt_mproj, p0, mproj_b, Mx, 768, 3072, 768, 768, 0);    // mproj (768 blocks)
  ADAPTER(p0, p1);
  resid_ln<false, true><<<Mx, 64, 0, stream>>>(out_x, out_x, p1, nullptr, nullptr, nullptr);

  (void)in_sizes; (void)n_in; (void)out_size; (void)ws_size;
}

// Round 16
// 416.285 us; speedup vs baseline: 1.0740x; 1.0061x over previous
//
#include <hip/hip_runtime.h>

typedef unsigned short u16;
typedef short bf16x8 __attribute__((ext_vector_type(8)));
typedef float f32x4 __attribute__((ext_vector_type(4)));
typedef unsigned short u16x4 __attribute__((ext_vector_type(4)));

__device__ __forceinline__ u16 f2bf(float f) {
  union { float f; unsigned u; } v; v.f = f;
  unsigned u = v.u;
  unsigned r = (u + 0x7FFFu + ((u >> 16) & 1u)) >> 16;
  return (u16)r;
}
__device__ __forceinline__ float bf2f(u16 h) {
  union { unsigned u; float f; } v; v.u = ((unsigned)h) << 16;
  return v.f;
}
// packed f32x2 -> bf16x2 (RTNE, matches f2bf); 1 inst per 2 values
__device__ __forceinline__ unsigned cvt_pk_bf16(float lo, float hi) {
  unsigned d;
  asm("v_cvt_pk_bf16_f32 %0, %1, %2" : "=v"(d) : "v"(lo), "v"(hi));
  return d;
}
// gelu(x) = x * sigmoid(1.5957691(x+0.044715x^3)); exp2-domain (log2e folded), rcp approx.
__device__ __forceinline__ float gelu_f(float x) {
  const float c1 = -2.302585093f;          // -1.5957691216 * log2(e)
  const float c2 = -0.1029620967f;         // c1 * 0.044715
  float t = __builtin_fmaf(x * x, c2, c1) * x;
  float e = exp2f(t);
  return x * __builtin_amdgcn_rcpf(e + 1.0f);
}

#define GLD_LDS16(gp, lp)                                             \
  __builtin_amdgcn_global_load_lds(                                   \
      (const __attribute__((address_space(1))) void*)(gp),            \
      (__attribute__((address_space(3))) void*)(lp), 16, 0, 0)

// ds_read_b64_tr_b16 semantics (m156/m162): per 16-lane group, lane l elem e receives
// u16 #(l&3) of the 8-byte block addressed by lane (4e + ((l&15)>>2)) of the group.
// With per-lane addr = base + 8*lane over a blocked layout (4 q/d per 8B block), this
// delivers transposed MFMA fragments conflict-free. OFF is an additive byte immediate.
template<int OFF>
__device__ __forceinline__ u16x4 tr16(unsigned a) {
  u16x4 d;
  asm volatile("ds_read_b64_tr_b16 %0, %1 offset:%2" : "=&v"(d) : "v"(a), "n"(OFF));
  return d;
}
// bit-preserving pack of two u16x4 into one bf16x8 (avoids narrowing diagnostics)
__device__ __forceinline__ bf16x8 pack8(u16x4 a, u16x4 b) {
  union { u16x4 p[2]; bf16x8 v; } u;
  u.p[0] = a; u.p[1] = b;
  return u.v;
}
// two packed-bf16 words -> u16x4 (for b64 LDS store)
__device__ __forceinline__ u16x4 pack4(unsigned w0, unsigned w1) {
  union { unsigned w[2]; u16x4 v; } u;
  u.w[0] = w0; u.w[1] = w1;
  return u.v;
}

// ---------------- batched weight transpose+convert: W[K][N] f32 -> Bt[Npad][Kpad] bf16 ------
struct TrBatch {
  const float* W[9];
  u16* Bt[9];
  int K[9], N[9], Kpad[9], Npad[9];
  int tstart[10];   // prefix sum of (Npad/64)*(Kpad/64)
};
__global__ __launch_bounds__(256)
void transpose_all(TrBatch tb) {
  __shared__ float tile[64][65];
  const int tid = blockIdx.x;
  int mi = 0;
  while (mi < 8 && tid >= tb.tstart[mi + 1]) ++mi;
  const int lt = tid - tb.tstart[mi];
  const int tx = tb.Npad[mi] >> 6;
  const int n0 = (lt % tx) * 64;
  const int k0 = (lt / tx) * 64;
  const float* W = tb.W[mi];
  u16* Bt = tb.Bt[mi];
  const int K = tb.K[mi], N = tb.N[mi], Kpad = tb.Kpad[mi];
  const int t = threadIdx.x;
  const int c = t & 63;
  const int rb = t >> 6;
#pragma unroll
  for (int i = 0; i < 16; ++i) {
    int r = i * 4 + rb;
    float v = 0.f;
    if (k0 + r < K && n0 + c < N) v = W[(size_t)(k0 + r) * N + n0 + c];
    tile[r][c] = v;
  }
  __syncthreads();
#pragma unroll
  for (int i = 0; i < 16; ++i) {
    int r = i * 4 + rb;  // row in N-dim
    Bt[(size_t)(n0 + r) * Kpad + k0 + c] = f2bf(tile[c][r]);
  }
}

// ---------------- layernorm: fp32 [M][768] -> bf16 [Mpad][768], pad rows zeroed -------------
__global__ __launch_bounds__(64)
void ln_kernel(const float* __restrict__ X, const float* __restrict__ G,
               const float* __restrict__ Bv, u16* __restrict__ O, int Mreal) {
  const int row = blockIdx.x;
  const int l = threadIdx.x;
  u16* op = O + (size_t)row * 768;
  if (row >= Mreal) {
    u16x4 z = {0, 0, 0, 0};
#pragma unroll
    for (int i = 0; i < 3; ++i) *(u16x4*)(op + (i * 64 + l) * 4) = z;
    return;
  }
  const float* xp = X + (size_t)row * 768;
  float v[12];
  float s = 0.f, s2 = 0.f;
#pragma unroll
  for (int i = 0; i < 3; ++i) {
    float4 t4 = *(const float4*)(xp + (i * 64 + l) * 4);
    v[i * 4 + 0] = t4.x; v[i * 4 + 1] = t4.y; v[i * 4 + 2] = t4.z; v[i * 4 + 3] = t4.w;
    s += t4.x + t4.y + t4.z + t4.w;
    s2 += t4.x * t4.x + t4.y * t4.y + t4.z * t4.z + t4.w * t4.w;
  }
#pragma unroll
  for (int off = 32; off > 0; off >>= 1) {
    s += __shfl_xor(s, off);
    s2 += __shfl_xor(s2, off);
  }
  const float mean = s * (1.0f / 768.0f);
  const float var = s2 * (1.0f / 768.0f) - mean * mean;
  const float rstd = rsqrtf(var + 1e-5f);
#pragma unroll
  for (int i = 0; i < 3; ++i) {
    int base = (i * 64 + l) * 4;
    float4 g4 = *(const float4*)(G + base);
    float4 b4 = *(const float4*)(Bv + base);
    u16x4 o4;
    o4[0] = f2bf((v[i * 4 + 0] - mean) * rstd * g4.x + b4.x);
    o4[1] = f2bf((v[i * 4 + 1] - mean) * rstd * g4.y + b4.y);
    o4[2] = f2bf((v[i * 4 + 2] - mean) * rstd * g4.z + b4.z);
    o4[3] = f2bf((v[i * 4 + 3] - mean) * rstd * g4.w + b4.w);
    *(u16x4*)(op + base) = o4;
  }
}

// ---------------- fused residual-add (+optional LN): D = S (+P);  O = LN(D)*G+B -------------
template<bool DOLN, bool RESID>
__global__ __launch_bounds__(64)
void resid_ln(const float* __restrict__ S, float* __restrict__ D,
              const u16* __restrict__ P,
              const float* __restrict__ G, const float* __restrict__ Bv,
              u16* __restrict__ O) {
  const int row = blockIdx.x;
  const int l = threadIdx.x;
  const float* sp = S + (size_t)row * 768;
  float* dp = D + (size_t)row * 768;
  float v[12];
  float s = 0.f, s2 = 0.f;
#pragma unroll
  for (int i = 0; i < 3; ++i) {
    const int base = (i * 64 + l) * 4;
    float4 t4 = *(const float4*)(sp + base);
    if (RESID) {
      u16x4 p4 = *(const u16x4*)(P + (size_t)row * 768 + base);
      t4.x += bf2f(p4[0]); t4.y += bf2f(p4[1]);
      t4.z += bf2f(p4[2]); t4.w += bf2f(p4[3]);
    }
    v[i * 4 + 0] = t4.x; v[i * 4 + 1] = t4.y; v[i * 4 + 2] = t4.z; v[i * 4 + 3] = t4.w;
    s += t4.x + t4.y + t4.z + t4.w;
    s2 += t4.x * t4.x + t4.y * t4.y + t4.z * t4.z + t4.w * t4.w;
    *(float4*)(dp + base) = t4;
  }
  if (DOLN) {
#pragma unroll
    for (int off = 32; off > 0; off >>= 1) {
      s += __shfl_xor(s, off);
      s2 += __shfl_xor(s2, off);
    }
    const float mean = s * (1.0f / 768.0f);
    const float var = s2 * (1.0f / 768.0f) - mean * mean;
    const float rstd = rsqrtf(var + 1e-5f);
    u16* op = O + (size_t)row * 768;
#pragma unroll
    for (int i = 0; i < 3; ++i) {
      int base = (i * 64 + l) * 4;
      float4 g4 = *(const float4*)(G + base);
      float4 b4 = *(const float4*)(Bv + base);
      u16x4 o4;
      o4[0] = f2bf((v[i * 4 + 0] - mean) * rstd * g4.x + b4.x);
      o4[1] = f2bf((v[i * 4 + 1] - mean) * rstd * g4.y + b4.y);
      o4[2] = f2bf((v[i * 4 + 2] - mean) * rstd * g4.z + b4.z);
      o4[3] = f2bf((v[i * 4 + 3] - mean) * rstd * g4.w + b4.w);
      *(u16x4*)(op + base) = o4;
    }
  }
}

// ---------------- GEMM 128x128, BK=64, split-half LDS (rule #21 staging) --------------------
// MODE 0: store bf16   1: relu->bf16   2: gelu->bf16
// 4-wave 1-phase structure. Chunk-XOR bank swizzle (R6: SQ_LDS_BANK_CONFLICT 4.7M -> 0).
// cvt_pk epilogue. For high-occupancy grids (qkv/fc/dual) where inter-block TLP hides
// the stage drain. R14 falsified the depth-2 pipelined 128x256 alternative (1 block/CU
// lost the inter-block TLP: 58.8 -> 75.2 us). No XCD swizzle (L3-resident working set).
template<int MODE>
__global__ void gemm_bt(const u16* __restrict__ A, const u16* __restrict__ Bt,
                        void* __restrict__ C, const float* __restrict__ bias,
                        int K, int ldc, int nbias) {
  __shared__ u16 As[2 * 128 * 32];   // [ks][row][chunk-swizzled][8]
  __shared__ u16 Bs[2 * 128 * 32];
  const int t = threadIdx.x;
  const int lane = t & 63;
  const int wid = t >> 6;
  const int wm = (wid >> 1) * 64;
  const int wn = (wid & 1) * 64;
  const int tm = blockIdx.x * 128;
  const int tn = blockIdx.y * 128;

  f32x4 zero = {0.f, 0.f, 0.f, 0.f};
  f32x4 acc[4][4];
#pragma unroll
  for (int i = 0; i < 4; ++i)
#pragma unroll
    for (int j = 0; j < 4; ++j) acc[i][j] = zero;

  const int rowA = lane & 15;
  const int kb = (((lane >> 4) ^ ((rowA >> 1) & 3)) << 3);   // swizzled chunk slot
  const int kTiles = K >> 6;
  for (int kt = 0; kt < kTiles; ++kt) {
    const int kk = kt << 6;
#pragma unroll
    for (int i = 0; i < 4; ++i) {
      const int c = i * 256 + t;                       // linear LDS slot index
      const int r = (c >> 2) & 127;                    // permuted global row
      const int cc = ((c >> 9) << 5) + ((((c & 3) ^ ((r >> 1) & 3))) << 3); // swizzled k-chunk
      GLD_LDS16(A + (size_t)(tm + r) * K + kk + cc, As + c * 8);
      GLD_LDS16(Bt + (size_t)(tn + r) * K + kk + cc, Bs + c * 8);
    }
    __syncthreads();
#pragma unroll
    for (int ks = 0; ks < 2; ++ks) {
      bf16x8 af[4], bfr[4];
      const int base = ks * 4096;
#pragma unroll
      for (int i = 0; i < 4; ++i) {
        af[i] = *(const bf16x8*)(As + base + (wm + i * 16 + rowA) * 32 + kb);
        bfr[i] = *(const bf16x8*)(Bs + base + (wn + i * 16 + rowA) * 32 + kb);
      }
#pragma unroll
      for (int mi = 0; mi < 4; ++mi)
#pragma unroll
        for (int ni = 0; ni < 4; ++ni)
          acc[mi][ni] = __builtin_amdgcn_mfma_f32_16x16x32_bf16(af[mi], bfr[ni], acc[mi][ni], 0, 0, 0);
    }
    __syncthreads();
  }
  const int col0 = lane & 15;
  const int row0 = (lane >> 4) << 2;
#pragma unroll
  for (int mi = 0; mi < 4; ++mi) {
#pragma unroll
    for (int ni = 0; ni < 4; ++ni) {
      int col = tn + wn + ni * 16 + col0;
      float bb = (col < nbias) ? bias[col] : 0.f;
      float vv[4];
#pragma unroll
      for (int r = 0; r < 4; ++r) {
        float v = acc[mi][ni][r] + bb;
        if (MODE == 1) v = fmaxf(v, 0.f);
        else if (MODE == 2) v = gelu_f(v);
        vv[r] = v;
      }
      unsigned w0 = cvt_pk_bf16(vv[0], vv[1]);
      unsigned w1 = cvt_pk_bf16(vv[2], vv[3]);
      size_t row = (size_t)(tm + wm + mi * 16 + row0);
      u16* cp = (u16*)C + row * ldc + col;
      cp[0] = (u16)w0;
      cp[(size_t)ldc] = (u16)(w0 >> 16);
      cp[(size_t)ldc * 2] = (u16)w1;
      cp[(size_t)ldc * 3] = (u16)(w1 >> 16);
    }
  }
}

// ---------------- 64x128 M-split GEMM for low-grid latency-bound dispatches -----------------
// R11 WIN: doubles the grid (3/CU) with A-traffic unchanged (FETCH stayed 43 MB) by
// splitting M and making M fastest so consecutive blocks share the B(weight)-panel.
// 4 waves: wave w = cols [w*32,w*32+32), all 64 rows; acc[4][2]. LDS 24 KB. MODE 0/1.
template<int MODE>
__global__ __launch_bounds__(256)
void gemm_bt_m64(const u16* __restrict__ A, const u16* __restrict__ Bt,
                 void* __restrict__ C, const float* __restrict__ bias,
                 int K, int ldc, int nbias) {
  __shared__ u16 As[2 * 64 * 32];    // [ks][row 0..63][chunk-swizzled][8]   8 KB
  __shared__ u16 Bs[2 * 128 * 32];   // [ks][ncol 0..127][chunk-swizzled][8] 16 KB
  const int t = threadIdx.x;
  const int lane = t & 63;
  const int wid = t >> 6;
  const int wn = wid * 32;                 // wave's 32-col strip
  const int tm = blockIdx.x * 64;          // M fastest: consecutive blocks share B-panel
  const int tn = blockIdx.y * 128;

  f32x4 zero = {0.f, 0.f, 0.f, 0.f};
  f32x4 acc[4][2];
#pragma unroll
  for (int i = 0; i < 4; ++i)
#pragma unroll
    for (int j = 0; j < 2; ++j) acc[i][j] = zero;

  const int rowA = lane & 15;
  const int kb = (((lane >> 4) ^ ((rowA >> 1) & 3)) << 3);
  const int kTiles = K >> 6;
  for (int kt = 0; kt < kTiles; ++kt) {
    const int kk = kt << 6;
#pragma unroll
    for (int i = 0; i < 2; ++i) {          // A: 512 slots, 2/thread
      const int c = i * 256 + t;
      const int r = (c >> 2) & 63;
      const int cc = ((c >> 8) << 5) + ((((c & 3) ^ ((r >> 1) & 3))) << 3);
      GLD_LDS16(A + (size_t)(tm + r) * K + kk + cc, As + c * 8);
    }
#pragma unroll
    for (int i = 0; i < 4; ++i) {          // B: 1024 slots, 4/thread
      const int c = i * 256 + t;
      const int r = (c >> 2) & 127;
      const int cc = ((c >> 9) << 5) + ((((c & 3) ^ ((r >> 1) & 3))) << 3);
      GLD_LDS16(Bt + (size_t)(tn + r) * K + kk + cc, Bs + c * 8);
    }
    __syncthreads();
#pragma unroll
    for (int ks = 0; ks < 2; ++ks) {
      bf16x8 af[4], bfr[2];
#pragma unroll
      for (int i = 0; i < 4; ++i)
        af[i] = *(const bf16x8*)(As + ks * 2048 + (i * 16 + rowA) * 32 + kb);
#pragma unroll
      for (int j = 0; j < 2; ++j)
        bfr[j] = *(const bf16x8*)(Bs + ks * 4096 + (wn + j * 16 + rowA) * 32 + kb);
#pragma unroll
      for (int mi = 0; mi < 4; ++mi)
#pragma unroll
        for (int ni = 0; ni < 2; ++ni)
          acc[mi][ni] = __builtin_amdgcn_mfma_f32_16x16x32_bf16(af[mi], bfr[ni], acc[mi][ni], 0, 0, 0);
    }
    __syncthreads();
  }
  const int col0 = lane & 15;
  const int row0 = (lane >> 4) << 2;
#pragma unroll
  for (int mi = 0; mi < 4; ++mi) {
#pragma unroll
    for (int ni = 0; ni < 2; ++ni) {
      int col = tn + wn + ni * 16 + col0;
      float bb = (col < nbias) ? bias[col] : 0.f;
      float vv[4];
#pragma unroll
      for (int r = 0; r < 4; ++r) {
        float v = acc[mi][ni][r] + bb;
        if (MODE == 1) v = fmaxf(v, 0.f);
        vv[r] = v;
      }
      unsigned w0 = cvt_pk_bf16(vv[0], vv[1]);
      unsigned w1 = cvt_pk_bf16(vv[2], vv[3]);
      size_t row = (size_t)(tm + mi * 16 + row0);
      u16* cp = (u16*)C + row * ldc + col;
      cp[0] = (u16)w0;
      cp[(size_t)ldc] = (u16)(w0 >> 16);
      cp[(size_t)ldc * 2] = (u16)w1;
      cp[(size_t)ldc * 3] = (u16)(w1 >> 16);
    }
  }
}

// ---------------- 64x128 M-split GEMM + fused fp32 residual into out_x (R16) ----------------
// ad2 variant: instead of writing bf16 padw then a separate resid pass (read out_x 25MB +
// p 12.5MB, write out_x 25MB), the epilogue reads the out_x fp32 tile, adds acc+bias, and
// writes out_x in place. Saves the p round-trip per branch and eliminates the final
// resid_ln<false,true> dispatch. Slightly better precision (no bf16 round-trip of the
// adapter output). Same staging/swizzle/MFMA body as gemm_bt_m64.
__global__ __launch_bounds__(256)
void gemm_bt_m64_res(const u16* __restrict__ A, const u16* __restrict__ Bt,
                     float* __restrict__ OX, const float* __restrict__ bias,
                     int K, int ldc) {
  __shared__ u16 As[2 * 64 * 32];
  __shared__ u16 Bs[2 * 128 * 32];
  const int t = threadIdx.x;
  const int lane = t & 63;
  const int wid = t >> 6;
  const int wn = wid * 32;
  const int tm = blockIdx.x * 64;          // M fastest: consecutive blocks share B-panel
  const int tn = blockIdx.y * 128;

  f32x4 zero = {0.f, 0.f, 0.f, 0.f};
  f32x4 acc[4][2];
#pragma unroll
  for (int i = 0; i < 4; ++i)
#pragma unroll
    for (int j = 0; j < 2; ++j) acc[i][j] = zero;

  const int rowA = lane & 15;
  const int kb = (((lane >> 4) ^ ((rowA >> 1) & 3)) << 3);
  const int kTiles = K >> 6;
  for (int kt = 0; kt < kTiles; ++kt) {
    const int kk = kt << 6;
#pragma unroll
    for (int i = 0; i < 2; ++i) {          // A: 512 slots, 2/thread
      const int c = i * 256 + t;
      const int r = (c >> 2) & 63;
      const int cc = ((c >> 8) << 5) + ((((c & 3) ^ ((r >> 1) & 3))) << 3);
      GLD_LDS16(A + (size_t)(tm + r) * K + kk + cc, As + c * 8);
    }
#pragma unroll
    for (int i = 0; i < 4; ++i) {          // B: 1024 slots, 4/thread
      const int c = i * 256 + t;
      const int r = (c >> 2) & 127;
      const int cc = ((c >> 9) << 5) + ((((c & 3) ^ ((r >> 1) & 3))) << 3);
      GLD_LDS16(Bt + (size_t)(tn + r) * K + kk + cc, Bs + c * 8);
    }
    __syncthreads();
#pragma unroll
    for (int ks = 0; ks < 2; ++ks) {
      bf16x8 af[4], bfr[2];
#pragma unroll
      for (int i = 0; i < 4; ++i)
        af[i] = *(const bf16x8*)(As + ks * 2048 + (i * 16 + rowA) * 32 + kb);
#pragma unroll
      for (int j = 0; j < 2; ++j)
        bfr[j] = *(const bf16x8*)(Bs + ks * 4096 + (wn + j * 16 + rowA) * 32 + kb);
#pragma unroll
      for (int mi = 0; mi < 4; ++mi)
#pragma unroll
        for (int ni = 0; ni < 2; ++ni)
          acc[mi][ni] = __builtin_amdgcn_mfma_f32_16x16x32_bf16(af[mi], bfr[ni], acc[mi][ni], 0, 0, 0);
    }
    __syncthreads();
  }
  const int col0 = lane & 15;
  const int row0 = (lane >> 4) << 2;
#pragma unroll
  for (int mi = 0; mi < 4; ++mi) {
#pragma unroll
    for (int ni = 0; ni < 2; ++ni) {
      int col = tn + wn + ni * 16 + col0;
      float bb = bias[col];
      size_t row = (size_t)(tm + mi * 16 + row0);
#pragma unroll
      for (int r = 0; r < 4; ++r) {
        float* op = OX + (row + r) * (size_t)ldc + col;
        *op = *op + acc[mi][ni][r] + bb;
      }
    }
  }
}

// ---------------- 64x64 GEMM for ad1 (N=192 unpadded; R13) ----------------------------------
// Native N=192 needs a 64-col tile: grid (M/64, N/64), M fastest (B-panel shared). 4 waves:
// wave w = cols [w*16, w*16+16), all 64 rows; acc[4]. LDS 16 KB. MODE 1 (relu).
template<int MODE>
__global__ __launch_bounds__(256)
void gemm_bt_6464(const u16* __restrict__ A, const u16* __restrict__ Bt,
                  void* __restrict__ C, const float* __restrict__ bias,
                  int K, int ldc, int nbias) {
  __shared__ u16 As[2 * 64 * 32];    // 8 KB
  __shared__ u16 Bs[2 * 64 * 32];    // 8 KB
  const int t = threadIdx.x;
  const int lane = t & 63;
  const int wid = t >> 6;
  const int wn = wid * 16;                 // wave's 16-col strip
  const int tm = blockIdx.x * 64;          // M fastest
  const int tn = blockIdx.y * 64;

  f32x4 acc[4];
#pragma unroll
  for (int i = 0; i < 4; ++i) acc[i] = (f32x4){0.f, 0.f, 0.f, 0.f};

  const int rowA = lane & 15;
  const int kb = (((lane >> 4) ^ ((rowA >> 1) & 3)) << 3);
  const int kTiles = K >> 6;
  for (int kt = 0; kt < kTiles; ++kt) {
    const int kk = kt << 6;
#pragma unroll
    for (int i = 0; i < 2; ++i) {          // A and B: 512 slots each, 2/thread each
      const int c = i * 256 + t;
      const int r = (c >> 2) & 63;
      const int cc = ((c >> 8) << 5) + ((((c & 3) ^ ((r >> 1) & 3))) << 3);
      GLD_LDS16(A + (size_t)(tm + r) * K + kk + cc, As + c * 8);
      GLD_LDS16(Bt + (size_t)(tn + r) * K + kk + cc, Bs + c * 8);
    }
    __syncthreads();
#pragma unroll
    for (int ks = 0; ks < 2; ++ks) {
      bf16x8 af[4], bfr;
#pragma unroll
      for (int i = 0; i < 4; ++i)
        af[i] = *(const bf16x8*)(As + ks * 2048 + (i * 16 + rowA) * 32 + kb);
      bfr = *(const bf16x8*)(Bs + ks * 2048 + (wn + rowA) * 32 + kb);
#pragma unroll
      for (int mi = 0; mi < 4; ++mi)
        acc[mi] = __builtin_amdgcn_mfma_f32_16x16x32_bf16(af[mi], bfr, acc[mi], 0, 0, 0);
    }
    __syncthreads();
  }
  const int col0 = lane & 15;
  const int row0 = (lane >> 4) << 2;
#pragma unroll
  for (int mi = 0; mi < 4; ++mi) {
    int col = tn + wn + col0;
    float bb = (col < nbias) ? bias[col] : 0.f;
    float vv[4];
#pragma unroll
    for (int r = 0; r < 4; ++r) {
      float v = acc[mi][r] + bb;
      if (MODE == 1) v = fmaxf(v, 0.f);
      vv[r] = v;
    }
    unsigned w0 = cvt_pk_bf16(vv[0], vv[1]);
    unsigned w1 = cvt_pk_bf16(vv[2], vv[3]);
    size_t row = (size_t)(tm + mi * 16 + row0);
    u16* cp = (u16*)C + row * ldc + col;
    cp[0] = (u16)w0;
    cp[(size_t)ldc] = (u16)(w0 >> 16);
    cp[(size_t)ldc * 2] = (u16)w1;
    cp[(size_t)ldc * 3] = (u16)(w1 >> 16);
  }
}

// ---------------- dual GEMM: two independent mode-0 GEMMs fused into one dispatch -----------
struct GemmJob {
  const u16* A; const u16* Bt; u16* C; const float* bias;
  int K, ldc, nbias, mblocks;
};
__global__ __launch_bounds__(256)
void gemm_bt_dual(GemmJob j0, GemmJob j1, int split) {
  __shared__ u16 As[2 * 128 * 32];
  __shared__ u16 Bs[2 * 128 * 32];
  const int bid = blockIdx.x;
  const GemmJob& J = (bid < split) ? j0 : j1;
  const int lb = (bid < split) ? bid : bid - split;
  const int tm = (lb % J.mblocks) * 128;
  const int tn = (lb / J.mblocks) * 128;
  const u16* A = J.A;
  const u16* Bt = J.Bt;
  const int K = J.K;

  const int t = threadIdx.x;
  const int lane = t & 63;
  const int wid = t >> 6;
  const int wm = (wid >> 1) * 64;
  const int wn = (wid & 1) * 64;

  f32x4 zero = {0.f, 0.f, 0.f, 0.f};
  f32x4 acc[4][4];
#pragma unroll
  for (int i = 0; i < 4; ++i)
#pragma unroll
    for (int j = 0; j < 4; ++j) acc[i][j] = zero;

  const int rowA = lane & 15;
  const int kb = (((lane >> 4) ^ ((rowA >> 1) & 3)) << 3);
  const int kTiles = K >> 6;
  for (int kt = 0; kt < kTiles; ++kt) {
    const int kk = kt << 6;
#pragma unroll
    for (int i = 0; i < 4; ++i) {
      const int c = i * 256 + t;
      const int r = (c >> 2) & 127;
      const int cc = ((c >> 9) << 5) + ((((c & 3) ^ ((r >> 1) & 3))) << 3);
      GLD_LDS16(A + (size_t)(tm + r) * K + kk + cc, As + c * 8);
      GLD_LDS16(Bt + (size_t)(tn + r) * K + kk + cc, Bs + c * 8);
    }
    __syncthreads();
#pragma unroll
    for (int ks = 0; ks < 2; ++ks) {
      bf16x8 af[4], bfr[4];
      const int base = ks * 4096;
#pragma unroll
      for (int i = 0; i < 4; ++i) {
        af[i] = *(const bf16x8*)(As + base + (wm + i * 16 + rowA) * 32 + kb);
        bfr[i] = *(const bf16x8*)(Bs + base + (wn + i * 16 + rowA) * 32 + kb);
      }
#pragma unroll
      for (int mi = 0; mi < 4; ++mi)
#pragma unroll
        for (int ni = 0; ni < 4; ++ni)
          acc[mi][ni] = __builtin_amdgcn_mfma_f32_16x16x32_bf16(af[mi], bfr[ni], acc[mi][ni], 0, 0, 0);
    }
    __syncthreads();
  }
  const int col0 = lane & 15;
  const int row0 = (lane >> 4) << 2;
#pragma unroll
  for (int mi = 0; mi < 4; ++mi) {
#pragma unroll
    for (int ni = 0; ni < 4; ++ni) {
      int col = tn + wn + ni * 16 + col0;
      float bb = (col < J.nbias) ? J.bias[col] : 0.f;
      unsigned w0 = cvt_pk_bf16(acc[mi][ni][0] + bb, acc[mi][ni][1] + bb);
      unsigned w1 = cvt_pk_bf16(acc[mi][ni][2] + bb, acc[mi][ni][3] + bb);
      size_t row = (size_t)(tm + wm + mi * 16 + row0);
      u16* cp = J.C + row * J.ldc + col;
      cp[0] = (u16)w0;
      cp[(size_t)J.ldc] = (u16)(w0 >> 16);
      cp[(size_t)J.ldc * 2] = (u16)w1;
      cp[(size_t)J.ldc * 3] = (u16)(w1 >> 16);
    }
  }
}

// ---------------- MFMA flash attention, QBLK=128 + tr-read V/P ------------------------------
// Single-pass normalized output; QBLK=128 (512 threads, 8 waves): each staged K/V tile
// serves 128 q rows. Causal grid (B*H, 8): yq = 7-blockIdx.y (heavy first), kv tiles
// [0, 2*yq+2); mask on the last two (diagonal) tiles via kv>q. Softmax in exp2 domain,
// VALU-thinned; T13 defer-max (THR=8); rowsum-l via P x ones MFMA. LDS 32 KB.
// LDS layouts (per 64x64 kv tile, verified R3..R13):
//   Ks: [kv][dchunk ^ (kv&7)]*8  (XOR swizzle, conflict-free b128 r/w)
//   Vs/Ps: blocked-transpose layout for ds_read_b64_tr_b16 (canonical addr = base+8*lane)
template<bool CAUSAL>
__global__ __launch_bounds__(512)
void attn_mfma(const u16* __restrict__ Q, const u16* __restrict__ Kp,
               const u16* __restrict__ Vp, u16* __restrict__ O,
               int seqkv, int qrs, int krs,
               long long qBatch, long long kBatch,
               int qoff, int koff, int voff) {
  __shared__ __align__(16) u16 Ks[64 * 64];
  __shared__ __align__(16) u16 Vs[4096];
  __shared__ __align__(16) u16 Ps[8][1024];
  const int t = threadIdx.x;
  const int lane = t & 63;
  const int wid = t >> 6;                 // 0..7
  const int b = blockIdx.x / 12, h = blockIdx.x % 12;
  const int yq = CAUSAL ? ((int)gridDim.y - 1 - (int)blockIdx.y) : (int)blockIdx.y;
  const int q0 = yq * 128;
  const int colid = lane & 15;
  const int rgrp = lane >> 4;

  const int kt_end = CAUSAL ? (2 * yq + 2) : ((seqkv + 63) >> 6);

  const u16* qp = Q + (size_t)b * qBatch + qoff + (size_t)(q0 + wid * 16 + colid) * qrs + h * 64;
  bf16x8 qa[2];
#pragma unroll
  for (int s = 0; s < 2; ++s) qa[s] = *(const bf16x8*)(qp + s * 32 + (rgrp << 3));

  f32x4 oacc[4];
#pragma unroll
  for (int i = 0; i < 4; ++i) oacc[i] = (f32x4){0.f, 0.f, 0.f, 0.f};
  float m[4] = {-1e30f, -1e30f, -1e30f, -1e30f};
  float l[4] = {0.f, 0.f, 0.f, 0.f};

  // all-ones bf16 B-fragment for the P-rowsum MFMA
  const u16x4 one4 = {0x3F80, 0x3F80, 0x3F80, 0x3F80};
  const bf16x8 ones8 = pack8(one4, one4);

  const u16* kbase = Kp + (size_t)b * kBatch + koff + h * 64;
  const u16* vbase = Vp + (size_t)b * kBatch + voff + h * 64;

  // staging geometry: 512 threads cover the 64x64 tile exactly once:
  // thread -> kv row r = t>>3, d chunk sdc*8
  const int srr = t >> 3, sdc = t & 7;    // srr 0..63
  const int kwo = srr * 64 + ((sdc ^ (srr & 7)) << 3);
  const int vwo = ((sdc >> 1) << 10) + ((srr >> 5) << 9) + (((srr >> 2) & 1) << 8)
                + (((srr >> 3) & 3) << 6) + ((srr & 3) << 4) + (((2 * sdc) & 3) << 2);
  // canonical tr-read per-lane byte bases (low 32 bits of generic shared ptr = LDS offset)
  const unsigned vs_base = (unsigned)(size_t)&Vs[0] + 8u * (unsigned)lane;
  const unsigned ps_base = (unsigned)(size_t)&Ps[wid][0] + 8u * (unsigned)lane;

  bf16x8 kz, vz;
  auto LOADT = [&](int kt) {
    const int tk = kt * 64 + srr;
    const int dc = sdc << 3;
    kz = (bf16x8){0, 0, 0, 0, 0, 0, 0, 0};
    vz = (bf16x8){0, 0, 0, 0, 0, 0, 0, 0};
    if (tk < seqkv) {
      kz = *(const bf16x8*)(kbase + (size_t)tk * krs + dc);
      vz = *(const bf16x8*)(vbase + (size_t)tk * krs + dc);
    }
  };
  LOADT(0);

  constexpr float SC2 = 0.18033688011112042f;   // 0.125 * log2(e): exp2 domain

  for (int kt = 0; kt < kt_end; ++kt) {
    const int k0 = kt * 64;
    *(bf16x8*)&Ks[kwo] = kz;
    *(bf16x8*)&Vs[vwo] = vz;
    __syncthreads();
    if (kt + 1 < kt_end) LOADT(kt + 1);   // T14 prefetch

    // ---- S = Q.K^T (raw) ----
    f32x4 sacc[4];
#pragma unroll
    for (int c = 0; c < 4; ++c) sacc[c] = (f32x4){0.f, 0.f, 0.f, 0.f};
#pragma unroll
    for (int c = 0; c < 4; ++c)
#pragma unroll
      for (int s = 0; s < 2; ++s) {
        bf16x8 kf = *(const bf16x8*)&Ks[(c * 16 + colid) * 64 +
                                        ((((s << 2) + rgrp) ^ (colid & 7)) << 3)];
        sacc[c] = __builtin_amdgcn_mfma_f32_16x16x32_bf16(qa[s], kf, sacc[c], 0, 0, 0);
      }

    // ---- mask in raw domain (causal diagonal tiles / kv-padding tile only) ----
    const bool domask = CAUSAL ? (kt >= 2 * yq) : (kt == kt_end - 1);
    if (domask) {
#pragma unroll
      for (int c = 0; c < 4; ++c) {
        int kv = k0 + c * 16 + colid;
#pragma unroll
        for (int r = 0; r < 4; ++r) {
          int q = q0 + wid * 16 + rgrp * 4 + r;
          if ((CAUSAL && kv > q) || (!CAUSAL && kv >= seqkv)) sacc[c][r] = -1e30f;
        }
      }
    }

    // ---- row max over raw sacc, scaled once per row ----
    float pms[4];
#pragma unroll
    for (int r = 0; r < 4; ++r) {
      float v = fmaxf(fmaxf(sacc[0][r], sacc[1][r]), fmaxf(sacc[2][r], sacc[3][r]));
#pragma unroll
      for (int off = 1; off < 16; off <<= 1) v = fmaxf(v, __shfl_xor(v, off));
      pms[r] = v * SC2;
    }
    // ---- T13 defer-max: rescale only when some row exceeds m+8 (wave-uniform) ----
    bool ok = (pms[0] <= m[0] + 8.f) && (pms[1] <= m[1] + 8.f) &&
              (pms[2] <= m[2] + 8.f) && (pms[3] <= m[3] + 8.f);
    if (!__all(ok)) {
#pragma unroll
      for (int r = 0; r < 4; ++r) {
        float newm = fmaxf(m[r], pms[r]);
        float corr = exp2f(m[r] - newm);
        m[r] = newm;
        l[r] *= corr;
#pragma unroll
        for (int dc2 = 0; dc2 < 4; ++dc2) oacc[dc2][r] *= corr;
      }
    }

    // ---- P = exp2(fma(sacc, SC2, -m)) ----
    float pv[4][4];
#pragma unroll
    for (int c = 0; c < 4; ++c)
#pragma unroll
      for (int r = 0; r < 4; ++r)
        pv[c][r] = exp2f(__builtin_fmaf(sacc[c][r], SC2, -m[r]));

    // ---- P^T -> LDS (blocked layout): cvt_pk x2 + one b64 store per c ----
#pragma unroll
    for (int c = 0; c < 4; ++c) {
      unsigned w0 = cvt_pk_bf16(pv[c][0], pv[c][1]);
      unsigned w1 = cvt_pk_bf16(pv[c][2], pv[c][3]);
      const int pa = ((c >> 1) << 9) + (((colid >> 2) & 1) << 8)
                   + (((2 * c + (colid >> 3)) & 3) << 6) + ((colid & 3) << 4) + (rgrp << 2);
      *(u16x4*)&Ps[wid][pa] = pack4(w0, w1);
    }
    __builtin_amdgcn_sched_barrier(0);   // pin store->tr-read order (DS in-order per wave)

    // ---- pf via canonical tr reads ----
    u16x4 p00 = tr16<0>(ps_base);
    u16x4 p01 = tr16<512>(ps_base);
    u16x4 p10 = tr16<1024>(ps_base);
    u16x4 p11 = tr16<1536>(ps_base);
    asm volatile("s_waitcnt lgkmcnt(0)" ::: "memory");
    __builtin_amdgcn_sched_barrier(0);   // rule #18: fence MFMA hoisting past asm waitcnt
    bf16x8 pf0 = pack8(p00, p01);
    bf16x8 pf1 = pack8(p10, p11);

    // ---- l += rowsum(P) via P x ones MFMA ----
    f32x4 sum_acc = (f32x4){0.f, 0.f, 0.f, 0.f};
    sum_acc = __builtin_amdgcn_mfma_f32_16x16x32_bf16(pf0, ones8, sum_acc, 0, 0, 0);
    sum_acc = __builtin_amdgcn_mfma_f32_16x16x32_bf16(pf1, ones8, sum_acc, 0, 0, 0);

    // ---- O += P.V : per-d0 batch {tr_read x4, lgkmcnt(0), sched_barrier, 2 MFMA} ----
#pragma unroll
    for (int dc2 = 0; dc2 < 4; ++dc2) {
      const unsigned va = vs_base + (unsigned)(dc2 * 2048);
      u16x4 v00 = tr16<0>(va);
      u16x4 v01 = tr16<512>(va);
      u16x4 v10 = tr16<1024>(va);
      u16x4 v11 = tr16<1536>(va);
      asm volatile("s_waitcnt lgkmcnt(0)" ::: "memory");
      __builtin_amdgcn_sched_barrier(0);
      bf16x8 vf0 = pack8(v00, v01);
      bf16x8 vf1 = pack8(v10, v11);
      oacc[dc2] = __builtin_amdgcn_mfma_f32_16x16x32_bf16(pf0, vf0, oacc[dc2], 0, 0, 0);
      oacc[dc2] = __builtin_amdgcn_mfma_f32_16x16x32_bf16(pf1, vf1, oacc[dc2], 0, 0, 0);
    }
#pragma unroll
    for (int r = 0; r < 4; ++r) l[r] += sum_acc[r];
    __syncthreads();
  }

  // ---- epilogue: normalized write (cvt_pk conversions) ----
#pragma unroll
  for (int r = 0; r < 4; ++r) {
    int qrow = q0 + wid * 16 + rgrp * 4 + r;
    u16* op = O + ((size_t)b * 1024 + qrow) * 768 + h * 64;
    float inv = 1.f / l[r];
    unsigned w0 = cvt_pk_bf16(oacc[0][r] * inv, oacc[1][r] * inv);
    unsigned w1 = cvt_pk_bf16(oacc[2][r] * inv, oacc[3][r] * inv);
    op[colid] = (u16)w0;
    op[16 + colid] = (u16)(w0 >> 16);
    op[32 + colid] = (u16)w1;
    op[48 + colid] = (u16)(w1 >> 16);
  }
}

// =============================================================================================
extern "C" void kernel_launch(void* const* d_in, const int* in_sizes, int n_in,
                              void* d_out, int out_size, void* d_ws, size_t ws_size,
                              hipStream_t stream) {
  const float* x        = (const float*)d_in[0];
  const float* x_enc    = (const float*)d_in[1];
  const float* ln1_g    = (const float*)d_in[2];
  const float* ln1_b    = (const float*)d_in[3];
  const float* ln2_g    = (const float*)d_in[4];
  const float* ln2_b    = (const float*)d_in[5];
  const float* ln3_g    = (const float*)d_in[6];
  const float* ln3_b    = (const float*)d_in[7];
  const float* attn_w   = (const float*)d_in[8];
  const float* attn_bias= (const float*)d_in[9];
  const float* proj_w   = (const float*)d_in[10];
  const float* proj_b   = (const float*)d_in[11];
  const float* img_w    = (const float*)d_in[12];
  const float* img_b    = (const float*)d_in[13];
  const float* cap_w    = (const float*)d_in[14];
  const float* cap_b    = (const float*)d_in[15];
  const float* cross_w  = (const float*)d_in[16];
  const float* cross_b  = (const float*)d_in[17];
  const float* ad1_w    = (const float*)d_in[18];
  const float* ad1_b    = (const float*)d_in[19];
  const float* ad2_w    = (const float*)d_in[20];
  const float* ad2_b    = (const float*)d_in[21];
  const float* fc_w     = (const float*)d_in[22];
  const float* fc_b     = (const float*)d_in[23];
  const float* mproj_w  = (const float*)d_in[24];
  const float* mproj_b  = (const float*)d_in[25];

  const int Mx = 8192;            // B*T
  const int Me = 2056;            // B*N_ENC
  const int MeP = 2176;           // padded to 17*128

  float* out_x  = (float*)d_out;                    // [8192][768] fp32, residual master
  float* out_xe = out_x + (size_t)Mx * 768;         // [2056][768] fp32 pass-through

  char* ws = (char*)d_ws;
  size_t off = 0;
  auto alloc = [&](size_t elems) {
    u16* p = (u16*)(ws + off);
    off = (off + elems * 2 + 255) & ~(size_t)255;
    return p;
  };
  u16* wt_attn  = alloc((size_t)2304 * 768);
  u16* wt_proj  = alloc((size_t)768 * 768);
  u16* wt_img   = alloc((size_t)1536 * 768);
  u16* wt_cap   = alloc((size_t)768 * 768);
  u16* wt_cross = alloc((size_t)768 * 768);
  u16* wt_ad1   = alloc((size_t)192 * 768);         // unpadded N=192
  u16* wt_ad2   = alloc((size_t)768 * 192);         // unpadded K=192
  u16* wt_fc    = alloc((size_t)3072 * 768);
  u16* wt_mproj = alloc((size_t)768 * 3072);
  u16* hbuf     = alloc((size_t)Mx * 768);          // LN outputs (h / hq / hm)
  u16* big      = alloc((size_t)Mx * 3072);         // qkv | q2+kv | mlp hidden
  u16* p0       = alloc((size_t)Mx * 768);
  u16* p1       = alloc((size_t)Mx * 768);
  u16* hid      = alloc((size_t)Mx * 192);          // adapter hidden (native 192)
  u16* q2  = big;                                   // [8192][768]
  u16* kvb = big + (size_t)Mx * 768;                // [2176][1536]

  // x_enc pass-through
  hipMemcpyAsync(out_xe, x_enc, (size_t)Me * 768 * 4, hipMemcpyDeviceToDevice, stream);

  // ---- batched weight convert+transpose (one launch for all 9) ----
  TrBatch tb;
  int nt = 0;
  tb.tstart[0] = 0;
  auto addT = [&](const float* W, u16* Bt, int K, int N, int Kp, int Np) {
    tb.W[nt] = W; tb.Bt[nt] = Bt; tb.K[nt] = K; tb.N[nt] = N;
    tb.Kpad[nt] = Kp; tb.Npad[nt] = Np;
    tb.tstart[nt + 1] = tb.tstart[nt] + (Np / 64) * (Kp / 64);
    ++nt;
  };
  addT(attn_w, wt_attn, 768, 2304, 768, 2304);
  addT(proj_w, wt_proj, 768, 768, 768, 768);
  addT(img_w, wt_img, 768, 1536, 768, 1536);
  addT(cap_w, wt_cap, 768, 768, 768, 768);
  addT(cross_w, wt_cross, 768, 768, 768, 768);
  addT(ad1_w, wt_ad1, 768, 192, 768, 192);
  addT(ad2_w, wt_ad2, 192, 768, 192, 768);
  addT(fc_w, wt_fc, 768, 3072, 768, 3072);
  addT(mproj_w, wt_mproj, 3072, 768, 3072, 768);
  transpose_all<<<tb.tstart[9], 256, 0, stream>>>(tb);

  // gemm_bt (128x128) for high-occupancy grids (qkv/fc/dual); gemm_bt_m64 (64x128 M-split)
  // for latency-bound low-grid GEMMs; gemm_bt_6464 for ad1; gemm_bt_m64_res for ad2+residual.
  auto GEMM = [&](const u16* A, const u16* Bt, void* C, const float* bias,
                  int M, int N, int K, int ldc, int nbias, int mode) {
    dim3 g(M / 128, N / 128);
    if (mode == 0)      gemm_bt<0><<<g, 256, 0, stream>>>(A, Bt, C, bias, K, ldc, nbias);
    else if (mode == 1) gemm_bt<1><<<g, 256, 0, stream>>>(A, Bt, C, bias, K, ldc, nbias);
    else                gemm_bt<2><<<g, 256, 0, stream>>>(A, Bt, C, bias, K, ldc, nbias);
  };
  auto GEMM_M64 = [&](const u16* A, const u16* Bt, void* C, const float* bias,
                      int M, int N, int K, int ldc, int nbias, int mode) {
    dim3 g(M / 64, N / 128);    // M fastest: consecutive blocks share the B(weight)-panel
    if (mode == 0) gemm_bt_m64<0><<<g, 256, 0, stream>>>(A, Bt, C, bias, K, ldc, nbias);
    else           gemm_bt_m64<1><<<g, 256, 0, stream>>>(A, Bt, C, bias, K, ldc, nbias);
  };
  // ADAPTER_RES: ad1 -> hid; ad2 accumulates adapter output + bias directly into out_x (fp32)
  auto ADAPTER_RES = [&](const u16* in) {
    dim3 g1(Mx / 64, 192 / 64);                    // 128 x 3 = 384 blocks
    gemm_bt_6464<1><<<g1, 256, 0, stream>>>(in, wt_ad1, hid, ad1_b, 768, 192, 192);
    dim3 g2(Mx / 64, 768 / 128);                   // 128 x 6 = 768 blocks
    gemm_bt_m64_res<<<g2, 256, 0, stream>>>(hid, wt_ad2, out_x, ad2_b, 192, 768);
  };

  // ---- init: out_x = x; hbuf = ln1(out_x) (fused copy+LN) ----
  resid_ln<true, false><<<Mx, 64, 0, stream>>>(x, out_x, nullptr, ln1_g, ln1_b, hbuf);

  // ---- causal self-attention branch (single-pass, normalized -> p0) ----
  GEMM(hbuf, wt_attn, big, attn_bias, Mx, 2304, 768, 2304, 2304, 0);   // qkv (1152 blocks)
  attn_mfma<true><<<dim3(96, 8), 512, 0, stream>>>(
      big, big, big, p0, 1024, 2304, 2304,
      (long long)1024 * 2304, (long long)1024 * 2304, 0, 768, 1536);
  GEMM_M64(p0, wt_proj, p1, proj_b, Mx, 768, 768, 768, 768, 0);        // sa (768 blocks)
  ADAPTER_RES(p1);                                                     // out_x += adapter(sa)
  ln_kernel<<<Mx, 64, 0, stream>>>(out_x, ln1_g, ln1_b, hbuf, Mx);     // hq

  // ---- cross-attention branch (kv + q2 GEMMs fused into one dispatch) ----
  ln_kernel<<<MeP, 64, 0, stream>>>(x_enc, ln3_g, ln3_b, p0, Me);      // he (padded rows zero)
  {
    GemmJob jkv = { p0,   wt_img, kvb, img_b, 768, 1536, 1536, MeP / 128 };  // 17x12 = 204
    GemmJob jq2 = { hbuf, wt_cap, q2,  cap_b, 768, 768,  768,  Mx / 128 };   // 64x6  = 384
    const int split = (MeP / 128) * (1536 / 128);
    const int total = split + (Mx / 128) * (768 / 128);
    gemm_bt_dual<<<total, 256, 0, stream>>>(jkv, jq2, split);
  }
  attn_mfma<false><<<dim3(96, 8), 512, 0, stream>>>(
      q2, kvb, kvb, p1, 257, 768, 1536,
      (long long)1024 * 768, (long long)257 * 1536, 0, 0, 768);
  GEMM_M64(p1, wt_cross, p0, cross_b, Mx, 768, 768, 768, 768, 0);      // ca (768 blocks)
  ADAPTER_RES(p0);                                                     // out_x += adapter(ca)
  ln_kernel<<<Mx, 64, 0, stream>>>(out_x, ln2_g, ln2_b, hbuf, Mx);     // hm

  // ---- MLP branch ----
  GEMM(hbuf, wt_fc, big, fc_b, Mx, 3072, 768, 3072, 3072, 2);          // fc (1536 blocks)
  GEMM_M64(big, wt_mproj, p0, mproj_b, Mx, 768, 3072, 768, 768, 0);    // mproj (768 blocks)
  ADAPTER_RES(p0);                                                     // out_x += adapter(m)

  (void)in_sizes; (void)n_in; (void)out_size; (void)ws_size;
}

// Round 17
// 398.060 us; speedup vs baseline: 1.1232x; 1.0458x over previous
//
#include <hip/hip_runtime.h>

typedef unsigned short u16;
typedef short bf16x8 __attribute__((ext_vector_type(8)));
typedef float f32x4 __attribute__((ext_vector_type(4)));
typedef unsigned short u16x4 __attribute__((ext_vector_type(4)));

__device__ __forceinline__ u16 f2bf(float f) {
  union { float f; unsigned u; } v; v.f = f;
  unsigned u = v.u;
  unsigned r = (u + 0x7FFFu + ((u >> 16) & 1u)) >> 16;
  return (u16)r;
}
__device__ __forceinline__ float bf2f(u16 h) {
  union { unsigned u; float f; } v; v.u = ((unsigned)h) << 16;
  return v.f;
}
// packed f32x2 -> bf16x2 (RTNE, matches f2bf); 1 inst per 2 values
__device__ __forceinline__ unsigned cvt_pk_bf16(float lo, float hi) {
  unsigned d;
  asm("v_cvt_pk_bf16_f32 %0, %1, %2" : "=v"(d) : "v"(lo), "v"(hi));
  return d;
}
// gelu(x) = x * sigmoid(1.5957691(x+0.044715x^3)); exp2-domain (log2e folded), rcp approx.
__device__ __forceinline__ float gelu_f(float x) {
  const float c1 = -2.302585093f;          // -1.5957691216 * log2(e)
  const float c2 = -0.1029620967f;         // c1 * 0.044715
  float t = __builtin_fmaf(x * x, c2, c1) * x;
  float e = exp2f(t);
  return x * __builtin_amdgcn_rcpf(e + 1.0f);
}

#define GLD_LDS16(gp, lp)                                             \
  __builtin_amdgcn_global_load_lds(                                   \
      (const __attribute__((address_space(1))) void*)(gp),            \
      (__attribute__((address_space(3))) void*)(lp), 16, 0, 0)

// ds_read_b64_tr_b16 semantics (m156/m162): per 16-lane group, lane l elem e receives
// u16 #(l&3) of the 8-byte block addressed by lane (4e + ((l&15)>>2)) of the group.
// With per-lane addr = base + 8*lane over a blocked layout (4 q/d per 8B block), this
// delivers transposed MFMA fragments conflict-free. OFF is an additive byte immediate.
template<int OFF>
__device__ __forceinline__ u16x4 tr16(unsigned a) {
  u16x4 d;
  asm volatile("ds_read_b64_tr_b16 %0, %1 offset:%2" : "=&v"(d) : "v"(a), "n"(OFF));
  return d;
}
// bit-preserving pack of two u16x4 into one bf16x8 (avoids narrowing diagnostics)
__device__ __forceinline__ bf16x8 pack8(u16x4 a, u16x4 b) {
  union { u16x4 p[2]; bf16x8 v; } u;
  u.p[0] = a; u.p[1] = b;
  return u.v;
}
// two packed-bf16 words -> u16x4 (for b64 LDS store)
__device__ __forceinline__ u16x4 pack4(unsigned w0, unsigned w1) {
  union { unsigned w[2]; u16x4 v; } u;
  u.w[0] = w0; u.w[1] = w1;
  return u.v;
}

// ---------------- batched weight transpose+convert: W[K][N] f32 -> Bt[Npad][Kpad] bf16 ------
struct TrBatch {
  const float* W[9];
  u16* Bt[9];
  int K[9], N[9], Kpad[9], Npad[9];
  int tstart[10];   // prefix sum of (Npad/64)*(Kpad/64)
};
__global__ __launch_bounds__(256)
void transpose_all(TrBatch tb) {
  __shared__ float tile[64][65];
  const int tid = blockIdx.x;
  int mi = 0;
  while (mi < 8 && tid >= tb.tstart[mi + 1]) ++mi;
  const int lt = tid - tb.tstart[mi];
  const int tx = tb.Npad[mi] >> 6;
  const int n0 = (lt % tx) * 64;
  const int k0 = (lt / tx) * 64;
  const float* W = tb.W[mi];
  u16* Bt = tb.Bt[mi];
  const int K = tb.K[mi], N = tb.N[mi], Kpad = tb.Kpad[mi];
  const int t = threadIdx.x;
  const int c = t & 63;
  const int rb = t >> 6;
#pragma unroll
  for (int i = 0; i < 16; ++i) {
    int r = i * 4 + rb;
    float v = 0.f;
    if (k0 + r < K && n0 + c < N) v = W[(size_t)(k0 + r) * N + n0 + c];
    tile[r][c] = v;
  }
  __syncthreads();
#pragma unroll
  for (int i = 0; i < 16; ++i) {
    int r = i * 4 + rb;  // row in N-dim
    Bt[(size_t)(n0 + r) * Kpad + k0 + c] = f2bf(tile[c][r]);
  }
}

// ---------------- layernorm: fp32 [M][768] -> bf16 [Mpad][768], pad rows zeroed -------------
__global__ __launch_bounds__(64)
void ln_kernel(const float* __restrict__ X, const float* __restrict__ G,
               const float* __restrict__ Bv, u16* __restrict__ O, int Mreal) {
  const int row = blockIdx.x;
  const int l = threadIdx.x;
  u16* op = O + (size_t)row * 768;
  if (row >= Mreal) {
    u16x4 z = {0, 0, 0, 0};
#pragma unroll
    for (int i = 0; i < 3; ++i) *(u16x4*)(op + (i * 64 + l) * 4) = z;
    return;
  }
  const float* xp = X + (size_t)row * 768;
  float v[12];
  float s = 0.f, s2 = 0.f;
#pragma unroll
  for (int i = 0; i < 3; ++i) {
    float4 t4 = *(const float4*)(xp + (i * 64 + l) * 4);
    v[i * 4 + 0] = t4.x; v[i * 4 + 1] = t4.y; v[i * 4 + 2] = t4.z; v[i * 4 + 3] = t4.w;
    s += t4.x + t4.y + t4.z + t4.w;
    s2 += t4.x * t4.x + t4.y * t4.y + t4.z * t4.z + t4.w * t4.w;
  }
#pragma unroll
  for (int off = 32; off > 0; off >>= 1) {
    s += __shfl_xor(s, off);
    s2 += __shfl_xor(s2, off);
  }
  const float mean = s * (1.0f / 768.0f);
  const float var = s2 * (1.0f / 768.0f) - mean * mean;
  const float rstd = rsqrtf(var + 1e-5f);
#pragma unroll
  for (int i = 0; i < 3; ++i) {
    int base = (i * 64 + l) * 4;
    float4 g4 = *(const float4*)(G + base);
    float4 b4 = *(const float4*)(Bv + base);
    u16x4 o4;
    o4[0] = f2bf((v[i * 4 + 0] - mean) * rstd * g4.x + b4.x);
    o4[1] = f2bf((v[i * 4 + 1] - mean) * rstd * g4.y + b4.y);
    o4[2] = f2bf((v[i * 4 + 2] - mean) * rstd * g4.z + b4.z);
    o4[3] = f2bf((v[i * 4 + 3] - mean) * rstd * g4.w + b4.w);
    *(u16x4*)(op + base) = o4;
  }
}

// ---------------- dual-job layernorm: two independent LNs in one dispatch (R17) -------------
// Blocks [0,M0): LN(X0 row, G0/B0) -> O0. Blocks [M0, M0+M1pad): LN(X1 row, G1/B1) -> O1
// (rows >= M1real zero-padded). Used to merge hq-LN (out_x) with he-LN (x_enc).
__global__ __launch_bounds__(64)
void ln_dual(const float* __restrict__ X0, const float* __restrict__ G0,
             const float* __restrict__ B0, u16* __restrict__ O0, int M0,
             const float* __restrict__ X1, const float* __restrict__ G1,
             const float* __restrict__ B1, u16* __restrict__ O1, int M1real) {
  const int bid = blockIdx.x;
  const float* X; const float* G; const float* Bv; u16* O; int row; int Mreal;
  if (bid < M0) { X = X0; G = G0; Bv = B0; O = O0; row = bid; Mreal = M0; }
  else          { X = X1; G = G1; Bv = B1; O = O1; row = bid - M0; Mreal = M1real; }
  const int l = threadIdx.x;
  u16* op = O + (size_t)row * 768;
  if (row >= Mreal) {
    u16x4 z = {0, 0, 0, 0};
#pragma unroll
    for (int i = 0; i < 3; ++i) *(u16x4*)(op + (i * 64 + l) * 4) = z;
    return;
  }
  const float* xp = X + (size_t)row * 768;
  float v[12];
  float s = 0.f, s2 = 0.f;
#pragma unroll
  for (int i = 0; i < 3; ++i) {
    float4 t4 = *(const float4*)(xp + (i * 64 + l) * 4);
    v[i * 4 + 0] = t4.x; v[i * 4 + 1] = t4.y; v[i * 4 + 2] = t4.z; v[i * 4 + 3] = t4.w;
    s += t4.x + t4.y + t4.z + t4.w;
    s2 += t4.x * t4.x + t4.y * t4.y + t4.z * t4.z + t4.w * t4.w;
  }
#pragma unroll
  for (int off = 32; off > 0; off >>= 1) {
    s += __shfl_xor(s, off);
    s2 += __shfl_xor(s2, off);
  }
  const float mean = s * (1.0f / 768.0f);
  const float var = s2 * (1.0f / 768.0f) - mean * mean;
  const float rstd = rsqrtf(var + 1e-5f);
#pragma unroll
  for (int i = 0; i < 3; ++i) {
    int base = (i * 64 + l) * 4;
    float4 g4 = *(const float4*)(G + base);
    float4 b4 = *(const float4*)(Bv + base);
    u16x4 o4;
    o4[0] = f2bf((v[i * 4 + 0] - mean) * rstd * g4.x + b4.x);
    o4[1] = f2bf((v[i * 4 + 1] - mean) * rstd * g4.y + b4.y);
    o4[2] = f2bf((v[i * 4 + 2] - mean) * rstd * g4.z + b4.z);
    o4[3] = f2bf((v[i * 4 + 3] - mean) * rstd * g4.w + b4.w);
    *(u16x4*)(op + base) = o4;
  }
}

// ---------------- GEMM 128x128, BK=64, split-half LDS (rule #21 staging) --------------------
// MODE 0: store bf16   1: relu->bf16   2: gelu->bf16
// 4-wave 1-phase structure. Chunk-XOR bank swizzle (R6: SQ_LDS_BANK_CONFLICT 4.7M -> 0).
// cvt_pk epilogue. For high-occupancy grids (qkv/fc/dual) where inter-block TLP hides
// the stage drain. R14 falsified the depth-2 pipelined 128x256 alternative (1 block/CU
// lost the inter-block TLP: 58.8 -> 75.2 us). No XCD swizzle (L3-resident working set).
template<int MODE>
__global__ void gemm_bt(const u16* __restrict__ A, const u16* __restrict__ Bt,
                        void* __restrict__ C, const float* __restrict__ bias,
                        int K, int ldc, int nbias) {
  __shared__ u16 As[2 * 128 * 32];   // [ks][row][chunk-swizzled][8]
  __shared__ u16 Bs[2 * 128 * 32];
  const int t = threadIdx.x;
  const int lane = t & 63;
  const int wid = t >> 6;
  const int wm = (wid >> 1) * 64;
  const int wn = (wid & 1) * 64;
  const int tm = blockIdx.x * 128;
  const int tn = blockIdx.y * 128;

  f32x4 zero = {0.f, 0.f, 0.f, 0.f};
  f32x4 acc[4][4];
#pragma unroll
  for (int i = 0; i < 4; ++i)
#pragma unroll
    for (int j = 0; j < 4; ++j) acc[i][j] = zero;

  const int rowA = lane & 15;
  const int kb = (((lane >> 4) ^ ((rowA >> 1) & 3)) << 3);   // swizzled chunk slot
  const int kTiles = K >> 6;
  for (int kt = 0; kt < kTiles; ++kt) {
    const int kk = kt << 6;
#pragma unroll
    for (int i = 0; i < 4; ++i) {
      const int c = i * 256 + t;                       // linear LDS slot index
      const int r = (c >> 2) & 127;                    // permuted global row
      const int cc = ((c >> 9) << 5) + ((((c & 3) ^ ((r >> 1) & 3))) << 3); // swizzled k-chunk
      GLD_LDS16(A + (size_t)(tm + r) * K + kk + cc, As + c * 8);
      GLD_LDS16(Bt + (size_t)(tn + r) * K + kk + cc, Bs + c * 8);
    }
    __syncthreads();
#pragma unroll
    for (int ks = 0; ks < 2; ++ks) {
      bf16x8 af[4], bfr[4];
      const int base = ks * 4096;
#pragma unroll
      for (int i = 0; i < 4; ++i) {
        af[i] = *(const bf16x8*)(As + base + (wm + i * 16 + rowA) * 32 + kb);
        bfr[i] = *(const bf16x8*)(Bs + base + (wn + i * 16 + rowA) * 32 + kb);
      }
#pragma unroll
      for (int mi = 0; mi < 4; ++mi)
#pragma unroll
        for (int ni = 0; ni < 4; ++ni)
          acc[mi][ni] = __builtin_amdgcn_mfma_f32_16x16x32_bf16(af[mi], bfr[ni], acc[mi][ni], 0, 0, 0);
    }
    __syncthreads();
  }
  const int col0 = lane & 15;
  const int row0 = (lane >> 4) << 2;
#pragma unroll
  for (int mi = 0; mi < 4; ++mi) {
#pragma unroll
    for (int ni = 0; ni < 4; ++ni) {
      int col = tn + wn + ni * 16 + col0;
      float bb = (col < nbias) ? bias[col] : 0.f;
      float vv[4];
#pragma unroll
      for (int r = 0; r < 4; ++r) {
        float v = acc[mi][ni][r] + bb;
        if (MODE == 1) v = fmaxf(v, 0.f);
        else if (MODE == 2) v = gelu_f(v);
        vv[r] = v;
      }
      unsigned w0 = cvt_pk_bf16(vv[0], vv[1]);
      unsigned w1 = cvt_pk_bf16(vv[2], vv[3]);
      size_t row = (size_t)(tm + wm + mi * 16 + row0);
      u16* cp = (u16*)C + row * ldc + col;
      cp[0] = (u16)w0;
      cp[(size_t)ldc] = (u16)(w0 >> 16);
      cp[(size_t)ldc * 2] = (u16)w1;
      cp[(size_t)ldc * 3] = (u16)(w1 >> 16);
    }
  }
}

// ---------------- 64x128 M-split GEMM for low-grid latency-bound dispatches -----------------
// R11 WIN: doubles the grid (3/CU) with A-traffic unchanged (FETCH stayed 43 MB) by
// splitting M and making M fastest so consecutive blocks share the B(weight)-panel.
// 4 waves: wave w = cols [w*32,w*32+32), all 64 rows; acc[4][2]. LDS 24 KB. MODE 0/1.
template<int MODE>
__global__ __launch_bounds__(256)
void gemm_bt_m64(const u16* __restrict__ A, const u16* __restrict__ Bt,
                 void* __restrict__ C, const float* __restrict__ bias,
                 int K, int ldc, int nbias) {
  __shared__ u16 As[2 * 64 * 32];    // [ks][row 0..63][chunk-swizzled][8]   8 KB
  __shared__ u16 Bs[2 * 128 * 32];   // [ks][ncol 0..127][chunk-swizzled][8] 16 KB
  const int t = threadIdx.x;
  const int lane = t & 63;
  const int wid = t >> 6;
  const int wn = wid * 32;                 // wave's 32-col strip
  const int tm = blockIdx.x * 64;          // M fastest: consecutive blocks share B-panel
  const int tn = blockIdx.y * 128;

  f32x4 zero = {0.f, 0.f, 0.f, 0.f};
  f32x4 acc[4][2];
#pragma unroll
  for (int i = 0; i < 4; ++i)
#pragma unroll
    for (int j = 0; j < 2; ++j) acc[i][j] = zero;

  const int rowA = lane & 15;
  const int kb = (((lane >> 4) ^ ((rowA >> 1) & 3)) << 3);
  const int kTiles = K >> 6;
  for (int kt = 0; kt < kTiles; ++kt) {
    const int kk = kt << 6;
#pragma unroll
    for (int i = 0; i < 2; ++i) {          // A: 512 slots, 2/thread
      const int c = i * 256 + t;
      const int r = (c >> 2) & 63;
      const int cc = ((c >> 8) << 5) + ((((c & 3) ^ ((r >> 1) & 3))) << 3);
      GLD_LDS16(A + (size_t)(tm + r) * K + kk + cc, As + c * 8);
    }
#pragma unroll
    for (int i = 0; i < 4; ++i) {          // B: 1024 slots, 4/thread
      const int c = i * 256 + t;
      const int r = (c >> 2) & 127;
      const int cc = ((c >> 9) << 5) + ((((c & 3) ^ ((r >> 1) & 3))) << 3);
      GLD_LDS16(Bt + (size_t)(tn + r) * K + kk + cc, Bs + c * 8);
    }
    __syncthreads();
#pragma unroll
    for (int ks = 0; ks < 2; ++ks) {
      bf16x8 af[4], bfr[2];
#pragma unroll
      for (int i = 0; i < 4; ++i)
        af[i] = *(const bf16x8*)(As + ks * 2048 + (i * 16 + rowA) * 32 + kb);
#pragma unroll
      for (int j = 0; j < 2; ++j)
        bfr[j] = *(const bf16x8*)(Bs + ks * 4096 + (wn + j * 16 + rowA) * 32 + kb);
#pragma unroll
      for (int mi = 0; mi < 4; ++mi)
#pragma unroll
        for (int ni = 0; ni < 2; ++ni)
          acc[mi][ni] = __builtin_amdgcn_mfma_f32_16x16x32_bf16(af[mi], bfr[ni], acc[mi][ni], 0, 0, 0);
    }
    __syncthreads();
  }
  const int col0 = lane & 15;
  const int row0 = (lane >> 4) << 2;
#pragma unroll
  for (int mi = 0; mi < 4; ++mi) {
#pragma unroll
    for (int ni = 0; ni < 2; ++ni) {
      int col = tn + wn + ni * 16 + col0;
      float bb = (col < nbias) ? bias[col] : 0.f;
      float vv[4];
#pragma unroll
      for (int r = 0; r < 4; ++r) {
        float v = acc[mi][ni][r] + bb;
        if (MODE == 1) v = fmaxf(v, 0.f);
        vv[r] = v;
      }
      unsigned w0 = cvt_pk_bf16(vv[0], vv[1]);
      unsigned w1 = cvt_pk_bf16(vv[2], vv[3]);
      size_t row = (size_t)(tm + mi * 16 + row0);
      u16* cp = (u16*)C + row * ldc + col;
      cp[0] = (u16)w0;
      cp[(size_t)ldc] = (u16)(w0 >> 16);
      cp[(size_t)ldc * 2] = (u16)w1;
      cp[(size_t)ldc * 3] = (u16)(w1 >> 16);
    }
  }
}

// ---------------- 64x128 M-split GEMM + fused fp32 residual into out_x (R16/R17) ------------
// ad2 variant: epilogue reads SRC fp32 tile (x for the FIRST branch, out_x after), adds
// acc+bias, writes OX in place. Saves the bf16 p round-trip per branch and (R17) the
// initial out_x = x copy pass.
__global__ __launch_bounds__(256)
void gemm_bt_m64_res(const u16* __restrict__ A, const u16* __restrict__ Bt,
                     const float* __restrict__ SRC, float* __restrict__ OX,
                     const float* __restrict__ bias, int K, int ldc) {
  __shared__ u16 As[2 * 64 * 32];
  __shared__ u16 Bs[2 * 128 * 32];
  const int t = threadIdx.x;
  const int lane = t & 63;
  const int wid = t >> 6;
  const int wn = wid * 32;
  const int tm = blockIdx.x * 64;          // M fastest: consecutive blocks share B-panel
  const int tn = blockIdx.y * 128;

  f32x4 zero = {0.f, 0.f, 0.f, 0.f};
  f32x4 acc[4][2];
#pragma unroll
  for (int i = 0; i < 4; ++i)
#pragma unroll
    for (int j = 0; j < 2; ++j) acc[i][j] = zero;

  const int rowA = lane & 15;
  const int kb = (((lane >> 4) ^ ((rowA >> 1) & 3)) << 3);
  const int kTiles = K >> 6;
  for (int kt = 0; kt < kTiles; ++kt) {
    const int kk = kt << 6;
#pragma unroll
    for (int i = 0; i < 2; ++i) {          // A: 512 slots, 2/thread
      const int c = i * 256 + t;
      const int r = (c >> 2) & 63;
      const int cc = ((c >> 8) << 5) + ((((c & 3) ^ ((r >> 1) & 3))) << 3);
      GLD_LDS16(A + (size_t)(tm + r) * K + kk + cc, As + c * 8);
    }
#pragma unroll
    for (int i = 0; i < 4; ++i) {          // B: 1024 slots, 4/thread
      const int c = i * 256 + t;
      const int r = (c >> 2) & 127;
      const int cc = ((c >> 9) << 5) + ((((c & 3) ^ ((r >> 1) & 3))) << 3);
      GLD_LDS16(Bt + (size_t)(tn + r) * K + kk + cc, Bs + c * 8);
    }
    __syncthreads();
#pragma unroll
    for (int ks = 0; ks < 2; ++ks) {
      bf16x8 af[4], bfr[2];
#pragma unroll
      for (int i = 0; i < 4; ++i)
        af[i] = *(const bf16x8*)(As + ks * 2048 + (i * 16 + rowA) * 32 + kb);
#pragma unroll
      for (int j = 0; j < 2; ++j)
        bfr[j] = *(const bf16x8*)(Bs + ks * 4096 + (wn + j * 16 + rowA) * 32 + kb);
#pragma unroll
      for (int mi = 0; mi < 4; ++mi)
#pragma unroll
        for (int ni = 0; ni < 2; ++ni)
          acc[mi][ni] = __builtin_amdgcn_mfma_f32_16x16x32_bf16(af[mi], bfr[ni], acc[mi][ni], 0, 0, 0);
    }
    __syncthreads();
  }
  const int col0 = lane & 15;
  const int row0 = (lane >> 4) << 2;
#pragma unroll
  for (int mi = 0; mi < 2 * 2; ++mi) {
#pragma unroll
    for (int ni = 0; ni < 2; ++ni) {
      int col = tn + wn + ni * 16 + col0;
      float bb = bias[col];
      size_t row = (size_t)(tm + mi * 16 + row0);
#pragma unroll
      for (int r = 0; r < 4; ++r) {
        size_t idx = (row + r) * (size_t)ldc + col;
        OX[idx] = SRC[idx] + acc[mi][ni][r] + bb;
      }
    }
  }
}

// ---------------- 64x64 GEMM for ad1 (N=192 unpadded; R13) ----------------------------------
// Native N=192 needs a 64-col tile: grid (M/64, N/64), M fastest (B-panel shared). 4 waves:
// wave w = cols [w*16, w*16+16), all 64 rows; acc[4]. LDS 16 KB. MODE 1 (relu).
template<int MODE>
__global__ __launch_bounds__(256)
void gemm_bt_6464(const u16* __restrict__ A, const u16* __restrict__ Bt,
                  void* __restrict__ C, const float* __restrict__ bias,
                  int K, int ldc, int nbias) {
  __shared__ u16 As[2 * 64 * 32];    // 8 KB
  __shared__ u16 Bs[2 * 64 * 32];    // 8 KB
  const int t = threadIdx.x;
  const int lane = t & 63;
  const int wid = t >> 6;
  const int wn = wid * 16;                 // wave's 16-col strip
  const int tm = blockIdx.x * 64;          // M fastest
  const int tn = blockIdx.y * 64;

  f32x4 acc[4];
#pragma unroll
  for (int i = 0; i < 4; ++i) acc[i] = (f32x4){0.f, 0.f, 0.f, 0.f};

  const int rowA = lane & 15;
  const int kb = (((lane >> 4) ^ ((rowA >> 1) & 3)) << 3);
  const int kTiles = K >> 6;
  for (int kt = 0; kt < kTiles; ++kt) {
    const int kk = kt << 6;
#pragma unroll
    for (int i = 0; i < 2; ++i) {          // A and B: 512 slots each, 2/thread each
      const int c = i * 256 + t;
      const int r = (c >> 2) & 63;
      const int cc = ((c >> 8) << 5) + ((((c & 3) ^ ((r >> 1) & 3))) << 3);
      GLD_LDS16(A + (size_t)(tm + r) * K + kk + cc, As + c * 8);
      GLD_LDS16(Bt + (size_t)(tn + r) * K + kk + cc, Bs + c * 8);
    }
    __syncthreads();
#pragma unroll
    for (int ks = 0; ks < 2; ++ks) {
      bf16x8 af[4], bfr;
#pragma unroll
      for (int i = 0; i < 4; ++i)
        af[i] = *(const bf16x8*)(As + ks * 2048 + (i * 16 + rowA) * 32 + kb);
      bfr = *(const bf16x8*)(Bs + ks * 2048 + (wn + rowA) * 32 + kb);
#pragma unroll
      for (int mi = 0; mi < 4; ++mi)
        acc[mi] = __builtin_amdgcn_mfma_f32_16x16x32_bf16(af[mi], bfr, acc[mi], 0, 0, 0);
    }
    __syncthreads();
  }
  const int col0 = lane & 15;
  const int row0 = (lane >> 4) << 2;
#pragma unroll
  for (int mi = 0; mi < 4; ++mi) {
    int col = tn + wn + col0;
    float bb = (col < nbias) ? bias[col] : 0.f;
    float vv[4];
#pragma unroll
    for (int r = 0; r < 4; ++r) {
      float v = acc[mi][r] + bb;
      if (MODE == 1) v = fmaxf(v, 0.f);
      vv[r] = v;
    }
    unsigned w0 = cvt_pk_bf16(vv[0], vv[1]);
    unsigned w1 = cvt_pk_bf16(vv[2], vv[3]);
    size_t row = (size_t)(tm + mi * 16 + row0);
    u16* cp = (u16*)C + row * ldc + col;
    cp[0] = (u16)w0;
    cp[(size_t)ldc] = (u16)(w0 >> 16);
    cp[(size_t)ldc * 2] = (u16)w1;
    cp[(size_t)ldc * 3] = (u16)(w1 >> 16);
  }
}

// ---------------- dual GEMM: two independent mode-0 GEMMs fused into one dispatch -----------
struct GemmJob {
  const u16* A; const u16* Bt; u16* C; const float* bias;
  int K, ldc, nbias, mblocks;
};
__global__ __launch_bounds__(256)
void gemm_bt_dual(GemmJob j0, GemmJob j1, int split) {
  __shared__ u16 As[2 * 128 * 32];
  __shared__ u16 Bs[2 * 128 * 32];
  const int bid = blockIdx.x;
  const GemmJob& J = (bid < split) ? j0 : j1;
  const int lb = (bid < split) ? bid : bid - split;
  const int tm = (lb % J.mblocks) * 128;
  const int tn = (lb / J.mblocks) * 128;
  const u16* A = J.A;
  const u16* Bt = J.Bt;
  const int K = J.K;

  const int t = threadIdx.x;
  const int lane = t & 63;
  const int wid = t >> 6;
  const int wm = (wid >> 1) * 64;
  const int wn = (wid & 1) * 64;

  f32x4 zero = {0.f, 0.f, 0.f, 0.f};
  f32x4 acc[4][4];
#pragma unroll
  for (int i = 0; i < 4; ++i)
#pragma unroll
    for (int j = 0; j < 4; ++j) acc[i][j] = zero;

  const int rowA = lane & 15;
  const int kb = (((lane >> 4) ^ ((rowA >> 1) & 3)) << 3);
  const int kTiles = K >> 6;
  for (int kt = 0; kt < kTiles; ++kt) {
    const int kk = kt << 6;
#pragma unroll
    for (int i = 0; i < 4; ++i) {
      const int c = i * 256 + t;
      const int r = (c >> 2) & 127;
      const int cc = ((c >> 9) << 5) + ((((c & 3) ^ ((r >> 1) & 3))) << 3);
      GLD_LDS16(A + (size_t)(tm + r) * K + kk + cc, As + c * 8);
      GLD_LDS16(Bt + (size_t)(tn + r) * K + kk + cc, Bs + c * 8);
    }
    __syncthreads();
#pragma unroll
    for (int ks = 0; ks < 2; ++ks) {
      bf16x8 af[4], bfr[4];
      const int base = ks * 4096;
#pragma unroll
      for (int i = 0; i < 4; ++i) {
        af[i] = *(const bf16x8*)(As + base + (wm + i * 16 + rowA) * 32 + kb);
        bfr[i] = *(const bf16x8*)(Bs + base + (wn + i * 16 + rowA) * 32 + kb);
      }
#pragma unroll
      for (int mi = 0; mi < 4; ++mi)
#pragma unroll
        for (int ni = 0; ni < 4; ++ni)
          acc[mi][ni] = __builtin_amdgcn_mfma_f32_16x16x32_bf16(af[mi], bfr[ni], acc[mi][ni], 0, 0, 0);
    }
    __syncthreads();
  }
  const int col0 = lane & 15;
  const int row0 = (lane >> 4) << 2;
#pragma unroll
  for (int mi = 0; mi < 4; ++mi) {
#pragma unroll
    for (int ni = 0; ni < 4; ++ni) {
      int col = tn + wn + ni * 16 + col0;
      float bb = (col < J.nbias) ? J.bias[col] : 0.f;
      unsigned w0 = cvt_pk_bf16(acc[mi][ni][0] + bb, acc[mi][ni][1] + bb);
      unsigned w1 = cvt_pk_bf16(acc[mi][ni][2] + bb, acc[mi][ni][3] + bb);
      size_t row = (size_t)(tm + wm + mi * 16 + row0);
      u16* cp = J.C + row * J.ldc + col;
      cp[0] = (u16)w0;
      cp[(size_t)J.ldc] = (u16)(w0 >> 16);
      cp[(size_t)J.ldc * 2] = (u16)w1;
      cp[(size_t)J.ldc * 3] = (u16)(w1 >> 16);
    }
  }
}

// ---------------- MFMA flash attention, QBLK=128 + tr-read V/P ------------------------------
// Single-pass normalized output; QBLK=128 (512 threads, 8 waves): each staged K/V tile
// serves 128 q rows. Causal grid (B*H, 8): yq = 7-blockIdx.y (heavy first), kv tiles
// [0, 2*yq+2); mask on the last two (diagonal) tiles via kv>q. Softmax in exp2 domain,
// VALU-thinned; T13 defer-max (THR=8); rowsum-l via P x ones MFMA. LDS 32 KB.
// LDS layouts (per 64x64 kv tile, verified R3..R13):
//   Ks: [kv][dchunk ^ (kv&7)]*8  (XOR swizzle, conflict-free b128 r/w)
//   Vs/Ps: blocked-transpose layout for ds_read_b64_tr_b16 (canonical addr = base+8*lane)
template<bool CAUSAL>
__global__ __launch_bounds__(512)
void attn_mfma(const u16* __restrict__ Q, const u16* __restrict__ Kp,
               const u16* __restrict__ Vp, u16* __restrict__ O,
               int seqkv, int qrs, int krs,
               long long qBatch, long long kBatch,
               int qoff, int koff, int voff) {
  __shared__ __align__(16) u16 Ks[64 * 64];
  __shared__ __align__(16) u16 Vs[4096];
  __shared__ __align__(16) u16 Ps[8][1024];
  const int t = threadIdx.x;
  const int lane = t & 63;
  const int wid = t >> 6;                 // 0..7
  const int b = blockIdx.x / 12, h = blockIdx.x % 12;
  const int yq = CAUSAL ? ((int)gridDim.y - 1 - (int)blockIdx.y) : (int)blockIdx.y;
  const int q0 = yq * 128;
  const int colid = lane & 15;
  const int rgrp = lane >> 4;

  const int kt_end = CAUSAL ? (2 * yq + 2) : ((seqkv + 63) >> 6);

  const u16* qp = Q + (size_t)b * qBatch + qoff + (size_t)(q0 + wid * 16 + colid) * qrs + h * 64;
  bf16x8 qa[2];
#pragma unroll
  for (int s = 0; s < 2; ++s) qa[s] = *(const bf16x8*)(qp + s * 32 + (rgrp << 3));

  f32x4 oacc[4];
#pragma unroll
  for (int i = 0; i < 4; ++i) oacc[i] = (f32x4){0.f, 0.f, 0.f, 0.f};
  float m[4] = {-1e30f, -1e30f, -1e30f, -1e30f};
  float l[4] = {0.f, 0.f, 0.f, 0.f};

  // all-ones bf16 B-fragment for the P-rowsum MFMA
  const u16x4 one4 = {0x3F80, 0x3F80, 0x3F80, 0x3F80};
  const bf16x8 ones8 = pack8(one4, one4);

  const u16* kbase = Kp + (size_t)b * kBatch + koff + h * 64;
  const u16* vbase = Vp + (size_t)b * kBatch + voff + h * 64;

  // staging geometry: 512 threads cover the 64x64 tile exactly once:
  // thread -> kv row r = t>>3, d chunk sdc*8
  const int srr = t >> 3, sdc = t & 7;    // srr 0..63
  const int kwo = srr * 64 + ((sdc ^ (srr & 7)) << 3);
  const int vwo = ((sdc >> 1) << 10) + ((srr >> 5) << 9) + (((srr >> 2) & 1) << 8)
                + (((srr >> 3) & 3) << 6) + ((srr & 3) << 4) + (((2 * sdc) & 3) << 2);
  // canonical tr-read per-lane byte bases (low 32 bits of generic shared ptr = LDS offset)
  const unsigned vs_base = (unsigned)(size_t)&Vs[0] + 8u * (unsigned)lane;
  const unsigned ps_base = (unsigned)(size_t)&Ps[wid][0] + 8u * (unsigned)lane;

  bf16x8 kz, vz;
  auto LOADT = [&](int kt) {
    const int tk = kt * 64 + srr;
    const int dc = sdc << 3;
    kz = (bf16x8){0, 0, 0, 0, 0, 0, 0, 0};
    vz = (bf16x8){0, 0, 0, 0, 0, 0, 0, 0};
    if (tk < seqkv) {
      kz = *(const bf16x8*)(kbase + (size_t)tk * krs + dc);
      vz = *(const bf16x8*)(vbase + (size_t)tk * krs + dc);
    }
  };
  LOADT(0);

  constexpr float SC2 = 0.18033688011112042f;   // 0.125 * log2(e): exp2 domain

  for (int kt = 0; kt < kt_end; ++kt) {
    const int k0 = kt * 64;
    *(bf16x8*)&Ks[kwo] = kz;
    *(bf16x8*)&Vs[vwo] = vz;
    __syncthreads();
    if (kt + 1 < kt_end) LOADT(kt + 1);   // T14 prefetch

    // ---- S = Q.K^T (raw) ----
    f32x4 sacc[4];
#pragma unroll
    for (int c = 0; c < 4; ++c) sacc[c] = (f32x4){0.f, 0.f, 0.f, 0.f};
#pragma unroll
    for (int c = 0; c < 4; ++c)
#pragma unroll
      for (int s = 0; s < 2; ++s) {
        bf16x8 kf = *(const bf16x8*)&Ks[(c * 16 + colid) * 64 +
                                        ((((s << 2) + rgrp) ^ (colid & 7)) << 3)];
        sacc[c] = __builtin_amdgcn_mfma_f32_16x16x32_bf16(qa[s], kf, sacc[c], 0, 0, 0);
      }

    // ---- mask in raw domain (causal diagonal tiles / kv-padding tile only) ----
    const bool domask = CAUSAL ? (kt >= 2 * yq) : (kt == kt_end - 1);
    if (domask) {
#pragma unroll
      for (int c = 0; c < 4; ++c) {
        int kv = k0 + c * 16 + colid;
#pragma unroll
        for (int r = 0; r < 4; ++r) {
          int q = q0 + wid * 16 + rgrp * 4 + r;
          if ((CAUSAL && kv > q) || (!CAUSAL && kv >= seqkv)) sacc[c][r] = -1e30f;
        }
      }
    }

    // ---- row max over raw sacc, scaled once per row ----
    float pms[4];
#pragma unroll
    for (int r = 0; r < 4; ++r) {
      float v = fmaxf(fmaxf(sacc[0][r], sacc[1][r]), fmaxf(sacc[2][r], sacc[3][r]));
#pragma unroll
      for (int off = 1; off < 16; off <<= 1) v = fmaxf(v, __shfl_xor(v, off));
      pms[r] = v * SC2;
    }
    // ---- T13 defer-max: rescale only when some row exceeds m+8 (wave-uniform) ----
    bool ok = (pms[0] <= m[0] + 8.f) && (pms[1] <= m[1] + 8.f) &&
              (pms[2] <= m[2] + 8.f) && (pms[3] <= m[3] + 8.f);
    if (!__all(ok)) {
#pragma unroll
      for (int r = 0; r < 4; ++r) {
        float newm = fmaxf(m[r], pms[r]);
        float corr = exp2f(m[r] - newm);
        m[r] = newm;
        l[r] *= corr;
#pragma unroll
        for (int dc2 = 0; dc2 < 4; ++dc2) oacc[dc2][r] *= corr;
      }
    }

    // ---- P = exp2(fma(sacc, SC2, -m)) ----
    float pv[4][4];
#pragma unroll
    for (int c = 0; c < 4; ++c)
#pragma unroll
      for (int r = 0; r < 4; ++r)
        pv[c][r] = exp2f(__builtin_fmaf(sacc[c][r], SC2, -m[r]));

    // ---- P^T -> LDS (blocked layout): cvt_pk x2 + one b64 store per c ----
#pragma unroll
    for (int c = 0; c < 4; ++c) {
      unsigned w0 = cvt_pk_bf16(pv[c][0], pv[c][1]);
      unsigned w1 = cvt_pk_bf16(pv[c][2], pv[c][3]);
      const int pa = ((c >> 1) << 9) + (((colid >> 2) & 1) << 8)
                   + (((2 * c + (colid >> 3)) & 3) << 6) + ((colid & 3) << 4) + (rgrp << 2);
      *(u16x4*)&Ps[wid][pa] = pack4(w0, w1);
    }
    __builtin_amdgcn_sched_barrier(0);   // pin store->tr-read order (DS in-order per wave)

    // ---- pf via canonical tr reads ----
    u16x4 p00 = tr16<0>(ps_base);
    u16x4 p01 = tr16<512>(ps_base);
    u16x4 p10 = tr16<1024>(ps_base);
    u16x4 p11 = tr16<1536>(ps_base);
    asm volatile("s_waitcnt lgkmcnt(0)" ::: "memory");
    __builtin_amdgcn_sched_barrier(0);   // rule #18: fence MFMA hoisting past asm waitcnt
    bf16x8 pf0 = pack8(p00, p01);
    bf16x8 pf1 = pack8(p10, p11);

    // ---- l += rowsum(P) via P x ones MFMA ----
    f32x4 sum_acc = (f32x4){0.f, 0.f, 0.f, 0.f};
    sum_acc = __builtin_amdgcn_mfma_f32_16x16x32_bf16(pf0, ones8, sum_acc, 0, 0, 0);
    sum_acc = __builtin_amdgcn_mfma_f32_16x16x32_bf16(pf1, ones8, sum_acc, 0, 0, 0);

    // ---- O += P.V : per-d0 batch {tr_read x4, lgkmcnt(0), sched_barrier, 2 MFMA} ----
#pragma unroll
    for (int dc2 = 0; dc2 < 4; ++dc2) {
      const unsigned va = vs_base + (unsigned)(dc2 * 2048);
      u16x4 v00 = tr16<0>(va);
      u16x4 v01 = tr16<512>(va);
      u16x4 v10 = tr16<1024>(va);
      u16x4 v11 = tr16<1536>(va);
      asm volatile("s_waitcnt lgkmcnt(0)" ::: "memory");
      __builtin_amdgcn_sched_barrier(0);
      bf16x8 vf0 = pack8(v00, v01);
      bf16x8 vf1 = pack8(v10, v11);
      oacc[dc2] = __builtin_amdgcn_mfma_f32_16x16x32_bf16(pf0, vf0, oacc[dc2], 0, 0, 0);
      oacc[dc2] = __builtin_amdgcn_mfma_f32_16x16x32_bf16(pf1, vf1, oacc[dc2], 0, 0, 0);
    }
#pragma unroll
    for (int r = 0; r < 4; ++r) l[r] += sum_acc[r];
    __syncthreads();
  }

  // ---- epilogue: normalized write (cvt_pk conversions) ----
#pragma unroll
  for (int r = 0; r < 4; ++r) {
    int qrow = q0 + wid * 16 + rgrp * 4 + r;
    u16* op = O + ((size_t)b * 1024 + qrow) * 768 + h * 64;
    float inv = 1.f / l[r];
    unsigned w0 = cvt_pk_bf16(oacc[0][r] * inv, oacc[1][r] * inv);
    unsigned w1 = cvt_pk_bf16(oacc[2][r] * inv, oacc[3][r] * inv);
    op[colid] = (u16)w0;
    op[16 + colid] = (u16)(w0 >> 16);
    op[32 + colid] = (u16)w1;
    op[48 + colid] = (u16)(w1 >> 16);
  }
}

// =============================================================================================
extern "C" void kernel_launch(void* const* d_in, const int* in_sizes, int n_in,
                              void* d_out, int out_size, void* d_ws, size_t ws_size,
                              hipStream_t stream) {
  const float* x        = (const float*)d_in[0];
  const float* x_enc    = (const float*)d_in[1];
  const float* ln1_g    = (const float*)d_in[2];
  const float* ln1_b    = (const float*)d_in[3];
  const float* ln2_g    = (const float*)d_in[4];
  const float* ln2_b    = (const float*)d_in[5];
  const float* ln3_g    = (const float*)d_in[6];
  const float* ln3_b    = (const float*)d_in[7];
  const float* attn_w   = (const float*)d_in[8];
  const float* attn_bias= (const float*)d_in[9];
  const float* proj_w   = (const float*)d_in[10];
  const float* proj_b   = (const float*)d_in[11];
  const float* img_w    = (const float*)d_in[12];
  const float* img_b    = (const float*)d_in[13];
  const float* cap_w    = (const float*)d_in[14];
  const float* cap_b    = (const float*)d_in[15];
  const float* cross_w  = (const float*)d_in[16];
  const float* cross_b  = (const float*)d_in[17];
  const float* ad1_w    = (const float*)d_in[18];
  const float* ad1_b    = (const float*)d_in[19];
  const float* ad2_w    = (const float*)d_in[20];
  const float* ad2_b    = (const float*)d_in[21];
  const float* fc_w     = (const float*)d_in[22];
  const float* fc_b     = (const float*)d_in[23];
  const float* mproj_w  = (const float*)d_in[24];
  const float* mproj_b  = (const float*)d_in[25];

  const int Mx = 8192;            // B*T
  const int Me = 2056;            // B*N_ENC
  const int MeP = 2176;           // padded to 17*128

  float* out_x  = (float*)d_out;                    // [8192][768] fp32, residual master
  float* out_xe = out_x + (size_t)Mx * 768;         // [2056][768] fp32 pass-through

  char* ws = (char*)d_ws;
  size_t off = 0;
  auto alloc = [&](size_t elems) {
    u16* p = (u16*)(ws + off);
    off = (off + elems * 2 + 255) & ~(size_t)255;
    return p;
  };
  u16* wt_attn  = alloc((size_t)2304 * 768);
  u16* wt_proj  = alloc((size_t)768 * 768);
  u16* wt_img   = alloc((size_t)1536 * 768);
  u16* wt_cap   = alloc((size_t)768 * 768);
  u16* wt_cross = alloc((size_t)768 * 768);
  u16* wt_ad1   = alloc((size_t)192 * 768);         // unpadded N=192
  u16* wt_ad2   = alloc((size_t)768 * 192);         // unpadded K=192
  u16* wt_fc    = alloc((size_t)3072 * 768);
  u16* wt_mproj = alloc((size_t)768 * 3072);
  u16* hbuf     = alloc((size_t)Mx * 768);          // LN outputs (h / hq / hm)
  u16* big      = alloc((size_t)Mx * 3072);         // qkv | q2+kv | mlp hidden
  u16* p0       = alloc((size_t)Mx * 768);
  u16* p1       = alloc((size_t)Mx * 768);
  u16* hid      = alloc((size_t)Mx * 192);          // adapter hidden (native 192)
  u16* q2  = big;                                   // [8192][768]
  u16* kvb = big + (size_t)Mx * 768;                // [2176][1536]

  // x_enc pass-through
  hipMemcpyAsync(out_xe, x_enc, (size_t)Me * 768 * 4, hipMemcpyDeviceToDevice, stream);

  // ---- batched weight convert+transpose (one launch for all 9) ----
  TrBatch tb;
  int nt = 0;
  tb.tstart[0] = 0;
  auto addT = [&](const float* W, u16* Bt, int K, int N, int Kp, int Np) {
    tb.W[nt] = W; tb.Bt[nt] = Bt; tb.K[nt] = K; tb.N[nt] = N;
    tb.Kpad[nt] = Kp; tb.Npad[nt] = Np;
    tb.tstart[nt + 1] = tb.tstart[nt] + (Np / 64) * (Kp / 64);
    ++nt;
  };
  addT(attn_w, wt_attn, 768, 2304, 768, 2304);
  addT(proj_w, wt_proj, 768, 768, 768, 768);
  addT(img_w, wt_img, 768, 1536, 768, 1536);
  addT(cap_w, wt_cap, 768, 768, 768, 768);
  addT(cross_w, wt_cross, 768, 768, 768, 768);
  addT(ad1_w, wt_ad1, 768, 192, 768, 192);
  addT(ad2_w, wt_ad2, 192, 768, 192, 768);
  addT(fc_w, wt_fc, 768, 3072, 768, 3072);
  addT(mproj_w, wt_mproj, 3072, 768, 3072, 768);
  transpose_all<<<tb.tstart[9], 256, 0, stream>>>(tb);

  // gemm_bt (128x128) for high-occupancy grids (qkv/fc/dual); gemm_bt_m64 (64x128 M-split)
  // for latency-bound low-grid GEMMs; gemm_bt_6464 for ad1; gemm_bt_m64_res for ad2+residual.
  auto GEMM = [&](const u16* A, const u16* Bt, void* C, const float* bias,
                  int M, int N, int K, int ldc, int nbias, int mode) {
    dim3 g(M / 128, N / 128);
    if (mode == 0)      gemm_bt<0><<<g, 256, 0, stream>>>(A, Bt, C, bias, K, ldc, nbias);
    else if (mode == 1) gemm_bt<1><<<g, 256, 0, stream>>>(A, Bt, C, bias, K, ldc, nbias);
    else                gemm_bt<2><<<g, 256, 0, stream>>>(A, Bt, C, bias, K, ldc, nbias);
  };
  auto GEMM_M64 = [&](const u16* A, const u16* Bt, void* C, const float* bias,
                      int M, int N, int K, int ldc, int nbias, int mode) {
    dim3 g(M / 64, N / 128);    // M fastest: consecutive blocks share the B(weight)-panel
    if (mode == 0) gemm_bt_m64<0><<<g, 256, 0, stream>>>(A, Bt, C, bias, K, ldc, nbias);
    else           gemm_bt_m64<1><<<g, 256, 0, stream>>>(A, Bt, C, bias, K, ldc, nbias);
  };
  // ADAPTER_RES: ad1 -> hid; ad2 computes OX = SRC + adapter + bias (fp32).
  // First branch passes SRC = x (removes the init out_x = x copy); later branches SRC = out_x.
  auto ADAPTER_RES = [&](const u16* in, const float* srcResid) {
    dim3 g1(Mx / 64, 192 / 64);                    // 128 x 3 = 384 blocks
    gemm_bt_6464<1><<<g1, 256, 0, stream>>>(in, wt_ad1, hid, ad1_b, 768, 192, 192);
    dim3 g2(Mx / 64, 768 / 128);                   // 128 x 6 = 768 blocks
    gemm_bt_m64_res<<<g2, 256, 0, stream>>>(hid, wt_ad2, srcResid, out_x, ad2_b, 192, 768);
  };

  // ---- init: hbuf = ln1(x) (no out_x copy — first ad2_res reads x directly) ----
  ln_kernel<<<Mx, 64, 0, stream>>>(x, ln1_g, ln1_b, hbuf, Mx);

  // ---- causal self-attention branch (single-pass, normalized -> p0) ----
  GEMM(hbuf, wt_attn, big, attn_bias, Mx, 2304, 768, 2304, 2304, 0);   // qkv (1152 blocks)
  attn_mfma<true><<<dim3(96, 8), 512, 0, stream>>>(
      big, big, big, p0, 1024, 2304, 2304,
      (long long)1024 * 2304, (long long)1024 * 2304, 0, 768, 1536);
  GEMM_M64(p0, wt_proj, p1, proj_b, Mx, 768, 768, 768, 768, 0);        // sa (768 blocks)
  ADAPTER_RES(p1, x);                                                  // out_x = x + adapter(sa)
  // hq-LN (out_x) + he-LN (x_enc) merged into one dispatch (p0 is free after proj)
  ln_dual<<<Mx + MeP, 64, 0, stream>>>(out_x, ln1_g, ln1_b, hbuf, Mx,
                                       x_enc, ln3_g, ln3_b, p0, Me);

  // ---- cross-attention branch (kv + q2 GEMMs fused into one dispatch) ----
  {
    GemmJob jkv = { p0,   wt_img, kvb, img_b, 768, 1536, 1536, MeP / 128 };  // 17x12 = 204
    GemmJob jq2 = { hbuf, wt_cap, q2,  cap_b, 768, 768,  768,  Mx / 128 };   // 64x6  = 384
    const int split = (MeP / 128) * (1536 / 128);
    const int total = split + (Mx / 128) * (768 / 128);
    gemm_bt_dual<<<total, 256, 0, stream>>>(jkv, jq2, split);
  }
  attn_mfma<false><<<dim3(96, 8), 512, 0, stream>>>(
      q2, kvb, kvb, p1, 257, 768, 1536,
      (long long)1024 * 768, (long long)257 * 1536, 0, 0, 768);
  GEMM_M64(p1, wt_cross, p0, cross_b, Mx, 768, 768, 768, 768, 0);      // ca (768 blocks)
  ADAPTER_RES(p0, out_x);                                              // out_x += adapter(ca)
  ln_kernel<<<Mx, 64, 0, stream>>>(out_x, ln2_g, ln2_b, hbuf, Mx);     // hm

  // ---- MLP branch ----
  GEMM(hbuf, wt_fc, big, fc_b, Mx, 3072, 768, 3072, 3072, 2);          // fc (1536 blocks)
  GEMM_M64(big, wt_mproj, p0, mproj_b, Mx, 768, 3072, 768, 768, 0);    // mproj (768 blocks)
  ADAPTER_RES(p0, out_x);                                              // out_x += adapter(m)

  (void)in_sizes; (void)n_in; (void)out_size; (void)ws_size;
}

// Round 18
// 397.451 us; speedup vs baseline: 1.1249x; 1.0015x over previous
//
#include <hip/hip_runtime.h>

typedef unsigned short u16;
typedef short bf16x8 __attribute__((ext_vector_type(8)));
typedef float f32x4 __attribute__((ext_vector_type(4)));
typedef unsigned short u16x4 __attribute__((ext_vector_type(4)));

__device__ __forceinline__ u16 f2bf(float f) {
  union { float f; unsigned u; } v; v.f = f;
  unsigned u = v.u;
  unsigned r = (u + 0x7FFFu + ((u >> 16) & 1u)) >> 16;
  return (u16)r;
}
__device__ __forceinline__ float bf2f(u16 h) {
  union { unsigned u; float f; } v; v.u = ((unsigned)h) << 16;
  return v.f;
}
// packed f32x2 -> bf16x2 (RTNE, matches f2bf); 1 inst per 2 values
__device__ __forceinline__ unsigned cvt_pk_bf16(float lo, float hi) {
  unsigned d;
  asm("v_cvt_pk_bf16_f32 %0, %1, %2" : "=v"(d) : "v"(lo), "v"(hi));
  return d;
}
// gelu(x) = x * sigmoid(1.5957691(x+0.044715x^3)); exp2-domain (log2e folded), rcp approx.
__device__ __forceinline__ float gelu_f(float x) {
  const float c1 = -2.302585093f;          // -1.5957691216 * log2(e)
  const float c2 = -0.1029620967f;         // c1 * 0.044715
  float t = __builtin_fmaf(x * x, c2, c1) * x;
  float e = exp2f(t);
  return x * __builtin_amdgcn_rcpf(e + 1.0f);
}

#define GLD_LDS16(gp, lp)                                             \
  __builtin_amdgcn_global_load_lds(                                   \
      (const __attribute__((address_space(1))) void*)(gp),            \
      (__attribute__((address_space(3))) void*)(lp), 16, 0, 0)

// ds_read_b64_tr_b16 semantics (m156/m162): per 16-lane group, lane l elem e receives
// u16 #(l&3) of the 8-byte block addressed by lane (4e + ((l&15)>>2)) of the group.
// With per-lane addr = base + 8*lane over a blocked layout (4 q/d per 8B block), this
// delivers transposed MFMA fragments conflict-free. OFF is an additive byte immediate.
template<int OFF>
__device__ __forceinline__ u16x4 tr16(unsigned a) {
  u16x4 d;
  asm volatile("ds_read_b64_tr_b16 %0, %1 offset:%2" : "=&v"(d) : "v"(a), "n"(OFF));
  return d;
}
// bit-preserving pack of two u16x4 into one bf16x8 (avoids narrowing diagnostics)
__device__ __forceinline__ bf16x8 pack8(u16x4 a, u16x4 b) {
  union { u16x4 p[2]; bf16x8 v; } u;
  u.p[0] = a; u.p[1] = b;
  return u.v;
}
// two packed-bf16 words -> u16x4 (for b64 LDS store)
__device__ __forceinline__ u16x4 pack4(unsigned w0, unsigned w1) {
  union { unsigned w[2]; u16x4 v; } u;
  u.w[0] = w0; u.w[1] = w1;
  return u.v;
}

// ---------------- batched weight transpose+convert: W[K][N] f32 -> Bt[Npad][Kpad] bf16 ------
struct TrBatch {
  const float* W[9];
  u16* Bt[9];
  int K[9], N[9], Kpad[9], Npad[9];
  int tstart[10];   // prefix sum of (Npad/64)*(Kpad/64)
};
__global__ __launch_bounds__(256)
void transpose_all(TrBatch tb) {
  __shared__ float tile[64][65];
  const int tid = blockIdx.x;
  int mi = 0;
  while (mi < 8 && tid >= tb.tstart[mi + 1]) ++mi;
  const int lt = tid - tb.tstart[mi];
  const int tx = tb.Npad[mi] >> 6;
  const int n0 = (lt % tx) * 64;
  const int k0 = (lt / tx) * 64;
  const float* W = tb.W[mi];
  u16* Bt = tb.Bt[mi];
  const int K = tb.K[mi], N = tb.N[mi], Kpad = tb.Kpad[mi];
  const int t = threadIdx.x;
  const int c = t & 63;
  const int rb = t >> 6;
#pragma unroll
  for (int i = 0; i < 16; ++i) {
    int r = i * 4 + rb;
    float v = 0.f;
    if (k0 + r < K && n0 + c < N) v = W[(size_t)(k0 + r) * N + n0 + c];
    tile[r][c] = v;
  }
  __syncthreads();
#pragma unroll
  for (int i = 0; i < 16; ++i) {
    int r = i * 4 + rb;  // row in N-dim
    Bt[(size_t)(n0 + r) * Kpad + k0 + c] = f2bf(tile[c][r]);
  }
}

// ---------------- layernorm: fp32 [M][768] -> bf16 [Mpad][768], pad rows zeroed -------------
__global__ __launch_bounds__(64)
void ln_kernel(const float* __restrict__ X, const float* __restrict__ G,
               const float* __restrict__ Bv, u16* __restrict__ O, int Mreal) {
  const int row = blockIdx.x;
  const int l = threadIdx.x;
  u16* op = O + (size_t)row * 768;
  if (row >= Mreal) {
    u16x4 z = {0, 0, 0, 0};
#pragma unroll
    for (int i = 0; i < 3; ++i) *(u16x4*)(op + (i * 64 + l) * 4) = z;
    return;
  }
  const float* xp = X + (size_t)row * 768;
  float v[12];
  float s = 0.f, s2 = 0.f;
#pragma unroll
  for (int i = 0; i < 3; ++i) {
    float4 t4 = *(const float4*)(xp + (i * 64 + l) * 4);
    v[i * 4 + 0] = t4.x; v[i * 4 + 1] = t4.y; v[i * 4 + 2] = t4.z; v[i * 4 + 3] = t4.w;
    s += t4.x + t4.y + t4.z + t4.w;
    s2 += t4.x * t4.x + t4.y * t4.y + t4.z * t4.z + t4.w * t4.w;
  }
#pragma unroll
  for (int off = 32; off > 0; off >>= 1) {
    s += __shfl_xor(s, off);
    s2 += __shfl_xor(s2, off);
  }
  const float mean = s * (1.0f / 768.0f);
  const float var = s2 * (1.0f / 768.0f) - mean * mean;
  const float rstd = rsqrtf(var + 1e-5f);
#pragma unroll
  for (int i = 0; i < 3; ++i) {
    int base = (i * 64 + l) * 4;
    float4 g4 = *(const float4*)(G + base);
    float4 b4 = *(const float4*)(Bv + base);
    u16x4 o4;
    o4[0] = f2bf((v[i * 4 + 0] - mean) * rstd * g4.x + b4.x);
    o4[1] = f2bf((v[i * 4 + 1] - mean) * rstd * g4.y + b4.y);
    o4[2] = f2bf((v[i * 4 + 2] - mean) * rstd * g4.z + b4.z);
    o4[3] = f2bf((v[i * 4 + 3] - mean) * rstd * g4.w + b4.w);
    *(u16x4*)(op + base) = o4;
  }
}

// ---------------- dual-job layernorm: two independent LNs in one dispatch (R17) -------------
// Blocks [0,M0): LN(X0 row, G0/B0) -> O0. Blocks [M0, M0+M1pad): LN(X1 row, G1/B1) -> O1
// (rows >= M1real zero-padded). Used to merge hq-LN (out_x) with he-LN (x_enc).
__global__ __launch_bounds__(64)
void ln_dual(const float* __restrict__ X0, const float* __restrict__ G0,
             const float* __restrict__ B0, u16* __restrict__ O0, int M0,
             const float* __restrict__ X1, const float* __restrict__ G1,
             const float* __restrict__ B1, u16* __restrict__ O1, int M1real) {
  const int bid = blockIdx.x;
  const float* X; const float* G; const float* Bv; u16* O; int row; int Mreal;
  if (bid < M0) { X = X0; G = G0; Bv = B0; O = O0; row = bid; Mreal = M0; }
  else          { X = X1; G = G1; Bv = B1; O = O1; row = bid - M0; Mreal = M1real; }
  const int l = threadIdx.x;
  u16* op = O + (size_t)row * 768;
  if (row >= Mreal) {
    u16x4 z = {0, 0, 0, 0};
#pragma unroll
    for (int i = 0; i < 3; ++i) *(u16x4*)(op + (i * 64 + l) * 4) = z;
    return;
  }
  const float* xp = X + (size_t)row * 768;
  float v[12];
  float s = 0.f, s2 = 0.f;
#pragma unroll
  for (int i = 0; i < 3; ++i) {
    float4 t4 = *(const float4*)(xp + (i * 64 + l) * 4);
    v[i * 4 + 0] = t4.x; v[i * 4 + 1] = t4.y; v[i * 4 + 2] = t4.z; v[i * 4 + 3] = t4.w;
    s += t4.x + t4.y + t4.z + t4.w;
    s2 += t4.x * t4.x + t4.y * t4.y + t4.z * t4.z + t4.w * t4.w;
  }
#pragma unroll
  for (int off = 32; off > 0; off >>= 1) {
    s += __shfl_xor(s, off);
    s2 += __shfl_xor(s2, off);
  }
  const float mean = s * (1.0f / 768.0f);
  const float var = s2 * (1.0f / 768.0f) - mean * mean;
  const float rstd = rsqrtf(var + 1e-5f);
#pragma unroll
  for (int i = 0; i < 3; ++i) {
    int base = (i * 64 + l) * 4;
    float4 g4 = *(const float4*)(G + base);
    float4 b4 = *(const float4*)(Bv + base);
    u16x4 o4;
    o4[0] = f2bf((v[i * 4 + 0] - mean) * rstd * g4.x + b4.x);
    o4[1] = f2bf((v[i * 4 + 1] - mean) * rstd * g4.y + b4.y);
    o4[2] = f2bf((v[i * 4 + 2] - mean) * rstd * g4.z + b4.z);
    o4[3] = f2bf((v[i * 4 + 3] - mean) * rstd * g4.w + b4.w);
    *(u16x4*)(op + base) = o4;
  }
}

// ---------------- GEMM 128x128, BK=64, split-half LDS (rule #21 staging) --------------------
// MODE 0: store bf16   1: relu->bf16   2: gelu->bf16
// 4-wave 1-phase structure. Chunk-XOR bank swizzle (R6: SQ_LDS_BANK_CONFLICT 4.7M -> 0).
// cvt_pk epilogue. For high-occupancy grids (qkv/fc/dual) where inter-block TLP hides
// the stage drain. R14 falsified the depth-2 pipelined 128x256 alternative (1 block/CU
// lost the inter-block TLP: 58.8 -> 75.2 us). No XCD swizzle (L3-resident working set).
template<int MODE>
__global__ void gemm_bt(const u16* __restrict__ A, const u16* __restrict__ Bt,
                        void* __restrict__ C, const float* __restrict__ bias,
                        int K, int ldc, int nbias) {
  __shared__ u16 As[2 * 128 * 32];   // [ks][row][chunk-swizzled][8]
  __shared__ u16 Bs[2 * 128 * 32];
  const int t = threadIdx.x;
  const int lane = t & 63;
  const int wid = t >> 6;
  const int wm = (wid >> 1) * 64;
  const int wn = (wid & 1) * 64;
  const int tm = blockIdx.x * 128;
  const int tn = blockIdx.y * 128;

  f32x4 zero = {0.f, 0.f, 0.f, 0.f};
  f32x4 acc[4][4];
#pragma unroll
  for (int i = 0; i < 4; ++i)
#pragma unroll
    for (int j = 0; j < 4; ++j) acc[i][j] = zero;

  const int rowA = lane & 15;
  const int kb = (((lane >> 4) ^ ((rowA >> 1) & 3)) << 3);   // swizzled chunk slot
  const int kTiles = K >> 6;
  for (int kt = 0; kt < kTiles; ++kt) {
    const int kk = kt << 6;
#pragma unroll
    for (int i = 0; i < 4; ++i) {
      const int c = i * 256 + t;                       // linear LDS slot index
      const int r = (c >> 2) & 127;                    // permuted global row
      const int cc = ((c >> 9) << 5) + ((((c & 3) ^ ((r >> 1) & 3))) << 3); // swizzled k-chunk
      GLD_LDS16(A + (size_t)(tm + r) * K + kk + cc, As + c * 8);
      GLD_LDS16(Bt + (size_t)(tn + r) * K + kk + cc, Bs + c * 8);
    }
    __syncthreads();
#pragma unroll
    for (int ks = 0; ks < 2; ++ks) {
      bf16x8 af[4], bfr[4];
      const int base = ks * 4096;
#pragma unroll
      for (int i = 0; i < 4; ++i) {
        af[i] = *(const bf16x8*)(As + base + (wm + i * 16 + rowA) * 32 + kb);
        bfr[i] = *(const bf16x8*)(Bs + base + (wn + i * 16 + rowA) * 32 + kb);
      }
#pragma unroll
      for (int mi = 0; mi < 4; ++mi)
#pragma unroll
        for (int ni = 0; ni < 4; ++ni)
          acc[mi][ni] = __builtin_amdgcn_mfma_f32_16x16x32_bf16(af[mi], bfr[ni], acc[mi][ni], 0, 0, 0);
    }
    __syncthreads();
  }
  const int col0 = lane & 15;
  const int row0 = (lane >> 4) << 2;
#pragma unroll
  for (int mi = 0; mi < 4; ++mi) {
#pragma unroll
    for (int ni = 0; ni < 4; ++ni) {
      int col = tn + wn + ni * 16 + col0;
      float bb = (col < nbias) ? bias[col] : 0.f;
      float vv[4];
#pragma unroll
      for (int r = 0; r < 4; ++r) {
        float v = acc[mi][ni][r] + bb;
        if (MODE == 1) v = fmaxf(v, 0.f);
        else if (MODE == 2) v = gelu_f(v);
        vv[r] = v;
      }
      unsigned w0 = cvt_pk_bf16(vv[0], vv[1]);
      unsigned w1 = cvt_pk_bf16(vv[2], vv[3]);
      size_t row = (size_t)(tm + wm + mi * 16 + row0);
      u16* cp = (u16*)C + row * ldc + col;
      cp[0] = (u16)w0;
      cp[(size_t)ldc] = (u16)(w0 >> 16);
      cp[(size_t)ldc * 2] = (u16)w1;
      cp[(size_t)ldc * 3] = (u16)(w1 >> 16);
    }
  }
}

// ---------------- 64x128 M-split GEMM for low-grid latency-bound dispatches -----------------
// R11 WIN: doubles the grid (3/CU) with A-traffic unchanged (FETCH stayed 43 MB) by
// splitting M and making M fastest so consecutive blocks share the B(weight)-panel.
// 4 waves: wave w = cols [w*32,w*32+32), all 64 rows; acc[4][2]. LDS 24 KB. MODE 0/1.
template<int MODE>
__global__ __launch_bounds__(256)
void gemm_bt_m64(const u16* __restrict__ A, const u16* __restrict__ Bt,
                 void* __restrict__ C, const float* __restrict__ bias,
                 int K, int ldc, int nbias) {
  __shared__ u16 As[2 * 64 * 32];    // [ks][row 0..63][chunk-swizzled][8]   8 KB
  __shared__ u16 Bs[2 * 128 * 32];   // [ks][ncol 0..127][chunk-swizzled][8] 16 KB
  const int t = threadIdx.x;
  const int lane = t & 63;
  const int wid = t >> 6;
  const int wn = wid * 32;                 // wave's 32-col strip
  const int tm = blockIdx.x * 64;          // M fastest: consecutive blocks share B-panel
  const int tn = blockIdx.y * 128;

  f32x4 zero = {0.f, 0.f, 0.f, 0.f};
  f32x4 acc[4][2];
#pragma unroll
  for (int i = 0; i < 4; ++i)
#pragma unroll
    for (int j = 0; j < 2; ++j) acc[i][j] = zero;

  const int rowA = lane & 15;
  const int kb = (((lane >> 4) ^ ((rowA >> 1) & 3)) << 3);
  const int kTiles = K >> 6;
  for (int kt = 0; kt < kTiles; ++kt) {
    const int kk = kt << 6;
#pragma unroll
    for (int i = 0; i < 2; ++i) {          // A: 512 slots, 2/thread
      const int c = i * 256 + t;
      const int r = (c >> 2) & 63;
      const int cc = ((c >> 8) << 5) + ((((c & 3) ^ ((r >> 1) & 3))) << 3);
      GLD_LDS16(A + (size_t)(tm + r) * K + kk + cc, As + c * 8);
    }
#pragma unroll
    for (int i = 0; i < 4; ++i) {          // B: 1024 slots, 4/thread
      const int c = i * 256 + t;
      const int r = (c >> 2) & 127;
      const int cc = ((c >> 9) << 5) + ((((c & 3) ^ ((r >> 1) & 3))) << 3);
      GLD_LDS16(Bt + (size_t)(tn + r) * K + kk + cc, Bs + c * 8);
    }
    __syncthreads();
#pragma unroll
    for (int ks = 0; ks < 2; ++ks) {
      bf16x8 af[4], bfr[2];
#pragma unroll
      for (int i = 0; i < 4; ++i)
        af[i] = *(const bf16x8*)(As + ks * 2048 + (i * 16 + rowA) * 32 + kb);
#pragma unroll
      for (int j = 0; j < 2; ++j)
        bfr[j] = *(const bf16x8*)(Bs + ks * 4096 + (wn + j * 16 + rowA) * 32 + kb);
#pragma unroll
      for (int mi = 0; mi < 4; ++mi)
#pragma unroll
        for (int ni = 0; ni < 2; ++ni)
          acc[mi][ni] = __builtin_amdgcn_mfma_f32_16x16x32_bf16(af[mi], bfr[ni], acc[mi][ni], 0, 0, 0);
    }
    __syncthreads();
  }
  const int col0 = lane & 15;
  const int row0 = (lane >> 4) << 2;
#pragma unroll
  for (int mi = 0; mi < 4; ++mi) {
#pragma unroll
    for (int ni = 0; ni < 2; ++ni) {
      int col = tn + wn + ni * 16 + col0;
      float bb = (col < nbias) ? bias[col] : 0.f;
      float vv[4];
#pragma unroll
      for (int r = 0; r < 4; ++r) {
        float v = acc[mi][ni][r] + bb;
        if (MODE == 1) v = fmaxf(v, 0.f);
        vv[r] = v;
      }
      unsigned w0 = cvt_pk_bf16(vv[0], vv[1]);
      unsigned w1 = cvt_pk_bf16(vv[2], vv[3]);
      size_t row = (size_t)(tm + mi * 16 + row0);
      u16* cp = (u16*)C + row * ldc + col;
      cp[0] = (u16)w0;
      cp[(size_t)ldc] = (u16)(w0 >> 16);
      cp[(size_t)ldc * 2] = (u16)w1;
      cp[(size_t)ldc * 3] = (u16)(w1 >> 16);
    }
  }
}

// ---------------- 64x128 M-split GEMM + fused fp32 residual into out_x (R16/R17) ------------
// ad2 variant: epilogue reads SRC fp32 tile (x for the FIRST branch, out_x after), adds
// acc+bias, writes OX in place. Saves the bf16 p round-trip per branch and (R17) the
// initial out_x = x copy pass.
__global__ __launch_bounds__(256)
void gemm_bt_m64_res(const u16* __restrict__ A, const u16* __restrict__ Bt,
                     const float* __restrict__ SRC, float* __restrict__ OX,
                     const float* __restrict__ bias, int K, int ldc) {
  __shared__ u16 As[2 * 64 * 32];
  __shared__ u16 Bs[2 * 128 * 32];
  const int t = threadIdx.x;
  const int lane = t & 63;
  const int wid = t >> 6;
  const int wn = wid * 32;
  const int tm = blockIdx.x * 64;          // M fastest: consecutive blocks share B-panel
  const int tn = blockIdx.y * 128;

  f32x4 zero = {0.f, 0.f, 0.f, 0.f};
  f32x4 acc[4][2];
#pragma unroll
  for (int i = 0; i < 4; ++i)
#pragma unroll
    for (int j = 0; j < 2; ++j) acc[i][j] = zero;

  const int rowA = lane & 15;
  const int kb = (((lane >> 4) ^ ((rowA >> 1) & 3)) << 3);
  const int kTiles = K >> 6;
  for (int kt = 0; kt < kTiles; ++kt) {
    const int kk = kt << 6;
#pragma unroll
    for (int i = 0; i < 2; ++i) {          // A: 512 slots, 2/thread
      const int c = i * 256 + t;
      const int r = (c >> 2) & 63;
      const int cc = ((c >> 8) << 5) + ((((c & 3) ^ ((r >> 1) & 3))) << 3);
      GLD_LDS16(A + (size_t)(tm + r) * K + kk + cc, As + c * 8);
    }
#pragma unroll
    for (int i = 0; i < 4; ++i) {          // B: 1024 slots, 4/thread
      const int c = i * 256 + t;
      const int r = (c >> 2) & 127;
      const int cc = ((c >> 9) << 5) + ((((c & 3) ^ ((r >> 1) & 3))) << 3);
      GLD_LDS16(Bt + (size_t)(tn + r) * K + kk + cc, Bs + c * 8);
    }
    __syncthreads();
#pragma unroll
    for (int ks = 0; ks < 2; ++ks) {
      bf16x8 af[4], bfr[2];
#pragma unroll
      for (int i = 0; i < 4; ++i)
        af[i] = *(const bf16x8*)(As + ks * 2048 + (i * 16 + rowA) * 32 + kb);
#pragma unroll
      for (int j = 0; j < 2; ++j)
        bfr[j] = *(const bf16x8*)(Bs + ks * 4096 + (wn + j * 16 + rowA) * 32 + kb);
#pragma unroll
      for (int mi = 0; mi < 4; ++mi)
#pragma unroll
        for (int ni = 0; ni < 2; ++ni)
          acc[mi][ni] = __builtin_amdgcn_mfma_f32_16x16x32_bf16(af[mi], bfr[ni], acc[mi][ni], 0, 0, 0);
    }
    __syncthreads();
  }
  const int col0 = lane & 15;
  const int row0 = (lane >> 4) << 2;
#pragma unroll
  for (int mi = 0; mi < 2 * 2; ++mi) {
#pragma unroll
    for (int ni = 0; ni < 2; ++ni) {
      int col = tn + wn + ni * 16 + col0;
      float bb = bias[col];
      size_t row = (size_t)(tm + mi * 16 + row0);
#pragma unroll
      for (int r = 0; r < 4; ++r) {
        size_t idx = (row + r) * (size_t)ldc + col;
        OX[idx] = SRC[idx] + acc[mi][ni][r] + bb;
      }
    }
  }
}

// ---------------- 64x64 GEMM for ad1 (N=192 unpadded; R13) ----------------------------------
// Native N=192 needs a 64-col tile: grid (M/64, N/64), M fastest (B-panel shared). 4 waves:
// wave w = cols [w*16, w*16+16), all 64 rows; acc[4]. LDS 16 KB. MODE 1 (relu).
template<int MODE>
__global__ __launch_bounds__(256)
void gemm_bt_6464(const u16* __restrict__ A, const u16* __restrict__ Bt,
                  void* __restrict__ C, const float* __restrict__ bias,
                  int K, int ldc, int nbias) {
  __shared__ u16 As[2 * 64 * 32];    // 8 KB
  __shared__ u16 Bs[2 * 64 * 32];    // 8 KB
  const int t = threadIdx.x;
  const int lane = t & 63;
  const int wid = t >> 6;
  const int wn = wid * 16;                 // wave's 16-col strip
  const int tm = blockIdx.x * 64;          // M fastest
  const int tn = blockIdx.y * 64;

  f32x4 acc[4];
#pragma unroll
  for (int i = 0; i < 4; ++i) acc[i] = (f32x4){0.f, 0.f, 0.f, 0.f};

  const int rowA = lane & 15;
  const int kb = (((lane >> 4) ^ ((rowA >> 1) & 3)) << 3);
  const int kTiles = K >> 6;
  for (int kt = 0; kt < kTiles; ++kt) {
    const int kk = kt << 6;
#pragma unroll
    for (int i = 0; i < 2; ++i) {          // A and B: 512 slots each, 2/thread each
      const int c = i * 256 + t;
      const int r = (c >> 2) & 63;
      const int cc = ((c >> 8) << 5) + ((((c & 3) ^ ((r >> 1) & 3))) << 3);
      GLD_LDS16(A + (size_t)(tm + r) * K + kk + cc, As + c * 8);
      GLD_LDS16(Bt + (size_t)(tn + r) * K + kk + cc, Bs + c * 8);
    }
    __syncthreads();
#pragma unroll
    for (int ks = 0; ks < 2; ++ks) {
      bf16x8 af[4], bfr;
#pragma unroll
      for (int i = 0; i < 4; ++i)
        af[i] = *(const bf16x8*)(As + ks * 2048 + (i * 16 + rowA) * 32 + kb);
      bfr = *(const bf16x8*)(Bs + ks * 2048 + (wn + rowA) * 32 + kb);
#pragma unroll
      for (int mi = 0; mi < 4; ++mi)
        acc[mi] = __builtin_amdgcn_mfma_f32_16x16x32_bf16(af[mi], bfr, acc[mi], 0, 0, 0);
    }
    __syncthreads();
  }
  const int col0 = lane & 15;
  const int row0 = (lane >> 4) << 2;
#pragma unroll
  for (int mi = 0; mi < 4; ++mi) {
    int col = tn + wn + col0;
    float bb = (col < nbias) ? bias[col] : 0.f;
    float vv[4];
#pragma unroll
    for (int r = 0; r < 4; ++r) {
      float v = acc[mi][r] + bb;
      if (MODE == 1) v = fmaxf(v, 0.f);
      vv[r] = v;
    }
    unsigned w0 = cvt_pk_bf16(vv[0], vv[1]);
    unsigned w1 = cvt_pk_bf16(vv[2], vv[3]);
    size_t row = (size_t)(tm + mi * 16 + row0);
    u16* cp = (u16*)C + row * ldc + col;
    cp[0] = (u16)w0;
    cp[(size_t)ldc] = (u16)(w0 >> 16);
    cp[(size_t)ldc * 2] = (u16)w1;
    cp[(size_t)ldc * 3] = (u16)(w1 >> 16);
  }
}

// ---------------- dual GEMM: two independent mode-0 GEMMs fused into one dispatch -----------
struct GemmJob {
  const u16* A; const u16* Bt; u16* C; const float* bias;
  int K, ldc, nbias, mblocks;
};
__global__ __launch_bounds__(256)
void gemm_bt_dual(GemmJob j0, GemmJob j1, int split) {
  __shared__ u16 As[2 * 128 * 32];
  __shared__ u16 Bs[2 * 128 * 32];
  const int bid = blockIdx.x;
  const GemmJob& J = (bid < split) ? j0 : j1;
  const int lb = (bid < split) ? bid : bid - split;
  const int tm = (lb % J.mblocks) * 128;
  const int tn = (lb / J.mblocks) * 128;
  const u16* A = J.A;
  const u16* Bt = J.Bt;
  const int K = J.K;

  const int t = threadIdx.x;
  const int lane = t & 63;
  const int wid = t >> 6;
  const int wm = (wid >> 1) * 64;
  const int wn = (wid & 1) * 64;

  f32x4 zero = {0.f, 0.f, 0.f, 0.f};
  f32x4 acc[4][4];
#pragma unroll
  for (int i = 0; i < 4; ++i)
#pragma unroll
    for (int j = 0; j < 4; ++j) acc[i][j] = zero;

  const int rowA = lane & 15;
  const int kb = (((lane >> 4) ^ ((rowA >> 1) & 3)) << 3);
  const int kTiles = K >> 6;
  for (int kt = 0; kt < kTiles; ++kt) {
    const int kk = kt << 6;
#pragma unroll
    for (int i = 0; i < 4; ++i) {
      const int c = i * 256 + t;
      const int r = (c >> 2) & 127;
      const int cc = ((c >> 9) << 5) + ((((c & 3) ^ ((r >> 1) & 3))) << 3);
      GLD_LDS16(A + (size_t)(tm + r) * K + kk + cc, As + c * 8);
      GLD_LDS16(Bt + (size_t)(tn + r) * K + kk + cc, Bs + c * 8);
    }
    __syncthreads();
#pragma unroll
    for (int ks = 0; ks < 2; ++ks) {
      bf16x8 af[4], bfr[4];
      const int base = ks * 4096;
#pragma unroll
      for (int i = 0; i < 4; ++i) {
        af[i] = *(const bf16x8*)(As + base + (wm + i * 16 + rowA) * 32 + kb);
        bfr[i] = *(const bf16x8*)(Bs + base + (wn + i * 16 + rowA) * 32 + kb);
      }
#pragma unroll
      for (int mi = 0; mi < 4; ++mi)
#pragma unroll
        for (int ni = 0; ni < 4; ++ni)
          acc[mi][ni] = __builtin_amdgcn_mfma_f32_16x16x32_bf16(af[mi], bfr[ni], acc[mi][ni], 0, 0, 0);
    }
    __syncthreads();
  }
  const int col0 = lane & 15;
  const int row0 = (lane >> 4) << 2;
#pragma unroll
  for (int mi = 0; mi < 4; ++mi) {
#pragma unroll
    for (int ni = 0; ni < 4; ++ni) {
      int col = tn + wn + ni * 16 + col0;
      float bb = (col < J.nbias) ? J.bias[col] : 0.f;
      unsigned w0 = cvt_pk_bf16(acc[mi][ni][0] + bb, acc[mi][ni][1] + bb);
      unsigned w1 = cvt_pk_bf16(acc[mi][ni][2] + bb, acc[mi][ni][3] + bb);
      size_t row = (size_t)(tm + wm + mi * 16 + row0);
      u16* cp = J.C + row * J.ldc + col;
      cp[0] = (u16)w0;
      cp[(size_t)J.ldc] = (u16)(w0 >> 16);
      cp[(size_t)J.ldc * 2] = (u16)w1;
      cp[(size_t)J.ldc * 3] = (u16)(w1 >> 16);
    }
  }
}

// ---------------- MFMA flash attention, QBLK=128 + tr-read V/P ------------------------------
// Single-pass normalized output; QBLK=128 (512 threads, 8 waves): each staged K/V tile
// serves 128 q rows. Causal grid (B*H, 8): yq = 7-blockIdx.y (heavy first), kv tiles
// [0, 2*yq+2); mask on the last two (diagonal) tiles via kv>q. Softmax in exp2 domain,
// VALU-thinned; T13 defer-max (THR=8); rowsum-l via P x ones MFMA. LDS 32 KB.
// R18: T5 s_setprio(1/0) around the QK^T and rowsum+PV MFMA clusters — attn is the one
// kernel with per-phase wave-role diversity (stage/MFMA/softmax straddle), the regime where
// setprio measured +4-7% (m191); GEMMs left untouched (m190: lockstep null/negative).
// LDS layouts (per 64x64 kv tile, verified R3..R13):
//   Ks: [kv][dchunk ^ (kv&7)]*8  (XOR swizzle, conflict-free b128 r/w)
//   Vs/Ps: blocked-transpose layout for ds_read_b64_tr_b16 (canonical addr = base+8*lane)
template<bool CAUSAL>
__global__ __launch_bounds__(512)
void attn_mfma(const u16* __restrict__ Q, const u16* __restrict__ Kp,
               const u16* __restrict__ Vp, u16* __restrict__ O,
               int seqkv, int qrs, int krs,
               long long qBatch, long long kBatch,
               int qoff, int koff, int voff) {
  __shared__ __align__(16) u16 Ks[64 * 64];
  __shared__ __align__(16) u16 Vs[4096];
  __shared__ __align__(16) u16 Ps[8][1024];
  const int t = threadIdx.x;
  const int lane = t & 63;
  const int wid = t >> 6;                 // 0..7
  const int b = blockIdx.x / 12, h = blockIdx.x % 12;
  const int yq = CAUSAL ? ((int)gridDim.y - 1 - (int)blockIdx.y) : (int)blockIdx.y;
  const int q0 = yq * 128;
  const int colid = lane & 15;
  const int rgrp = lane >> 4;

  const int kt_end = CAUSAL ? (2 * yq + 2) : ((seqkv + 63) >> 6);

  const u16* qp = Q + (size_t)b * qBatch + qoff + (size_t)(q0 + wid * 16 + colid) * qrs + h * 64;
  bf16x8 qa[2];
#pragma unroll
  for (int s = 0; s < 2; ++s) qa[s] = *(const bf16x8*)(qp + s * 32 + (rgrp << 3));

  f32x4 oacc[4];
#pragma unroll
  for (int i = 0; i < 4; ++i) oacc[i] = (f32x4){0.f, 0.f, 0.f, 0.f};
  float m[4] = {-1e30f, -1e30f, -1e30f, -1e30f};
  float l[4] = {0.f, 0.f, 0.f, 0.f};

  // all-ones bf16 B-fragment for the P-rowsum MFMA
  const u16x4 one4 = {0x3F80, 0x3F80, 0x3F80, 0x3F80};
  const bf16x8 ones8 = pack8(one4, one4);

  const u16* kbase = Kp + (size_t)b * kBatch + koff + h * 64;
  const u16* vbase = Vp + (size_t)b * kBatch + voff + h * 64;

  // staging geometry: 512 threads cover the 64x64 tile exactly once:
  // thread -> kv row r = t>>3, d chunk sdc*8
  const int srr = t >> 3, sdc = t & 7;    // srr 0..63
  const int kwo = srr * 64 + ((sdc ^ (srr & 7)) << 3);
  const int vwo = ((sdc >> 1) << 10) + ((srr >> 5) << 9) + (((srr >> 2) & 1) << 8)
                + (((srr >> 3) & 3) << 6) + ((srr & 3) << 4) + (((2 * sdc) & 3) << 2);
  // canonical tr-read per-lane byte bases (low 32 bits of generic shared ptr = LDS offset)
  const unsigned vs_base = (unsigned)(size_t)&Vs[0] + 8u * (unsigned)lane;
  const unsigned ps_base = (unsigned)(size_t)&Ps[wid][0] + 8u * (unsigned)lane;

  bf16x8 kz, vz;
  auto LOADT = [&](int kt) {
    const int tk = kt * 64 + srr;
    const int dc = sdc << 3;
    kz = (bf16x8){0, 0, 0, 0, 0, 0, 0, 0};
    vz = (bf16x8){0, 0, 0, 0, 0, 0, 0, 0};
    if (tk < seqkv) {
      kz = *(const bf16x8*)(kbase + (size_t)tk * krs + dc);
      vz = *(const bf16x8*)(vbase + (size_t)tk * krs + dc);
    }
  };
  LOADT(0);

  constexpr float SC2 = 0.18033688011112042f;   // 0.125 * log2(e): exp2 domain

  for (int kt = 0; kt < kt_end; ++kt) {
    const int k0 = kt * 64;
    *(bf16x8*)&Ks[kwo] = kz;
    *(bf16x8*)&Vs[vwo] = vz;
    __syncthreads();
    if (kt + 1 < kt_end) LOADT(kt + 1);   // T14 prefetch

    // ---- S = Q.K^T (raw) ----
    f32x4 sacc[4];
#pragma unroll
    for (int c = 0; c < 4; ++c) sacc[c] = (f32x4){0.f, 0.f, 0.f, 0.f};
    __builtin_amdgcn_s_setprio(1);        // T5: favor MFMA-entering waves
#pragma unroll
    for (int c = 0; c < 4; ++c)
#pragma unroll
      for (int s = 0; s < 2; ++s) {
        bf16x8 kf = *(const bf16x8*)&Ks[(c * 16 + colid) * 64 +
                                        ((((s << 2) + rgrp) ^ (colid & 7)) << 3)];
        sacc[c] = __builtin_amdgcn_mfma_f32_16x16x32_bf16(qa[s], kf, sacc[c], 0, 0, 0);
      }
    __builtin_amdgcn_s_setprio(0);

    // ---- mask in raw domain (causal diagonal tiles / kv-padding tile only) ----
    const bool domask = CAUSAL ? (kt >= 2 * yq) : (kt == kt_end - 1);
    if (domask) {
#pragma unroll
      for (int c = 0; c < 4; ++c) {
        int kv = k0 + c * 16 + colid;
#pragma unroll
        for (int r = 0; r < 4; ++r) {
          int q = q0 + wid * 16 + rgrp * 4 + r;
          if ((CAUSAL && kv > q) || (!CAUSAL && kv >= seqkv)) sacc[c][r] = -1e30f;
        }
      }
    }

    // ---- row max over raw sacc, scaled once per row ----
    float pms[4];
#pragma unroll
    for (int r = 0; r < 4; ++r) {
      float v = fmaxf(fmaxf(sacc[0][r], sacc[1][r]), fmaxf(sacc[2][r], sacc[3][r]));
#pragma unroll
      for (int off = 1; off < 16; off <<= 1) v = fmaxf(v, __shfl_xor(v, off));
      pms[r] = v * SC2;
    }
    // ---- T13 defer-max: rescale only when some row exceeds m+8 (wave-uniform) ----
    bool ok = (pms[0] <= m[0] + 8.f) && (pms[1] <= m[1] + 8.f) &&
              (pms[2] <= m[2] + 8.f) && (pms[3] <= m[3] + 8.f);
    if (!__all(ok)) {
#pragma unroll
      for (int r = 0; r < 4; ++r) {
        float newm = fmaxf(m[r], pms[r]);
        float corr = exp2f(m[r] - newm);
        m[r] = newm;
        l[r] *= corr;
#pragma unroll
        for (int dc2 = 0; dc2 < 4; ++dc2) oacc[dc2][r] *= corr;
      }
    }

    // ---- P = exp2(fma(sacc, SC2, -m)) ----
    float pv[4][4];
#pragma unroll
    for (int c = 0; c < 4; ++c)
#pragma unroll
      for (int r = 0; r < 4; ++r)
        pv[c][r] = exp2f(__builtin_fmaf(sacc[c][r], SC2, -m[r]));

    // ---- P^T -> LDS (blocked layout): cvt_pk x2 + one b64 store per c ----
#pragma unroll
    for (int c = 0; c < 4; ++c) {
      unsigned w0 = cvt_pk_bf16(pv[c][0], pv[c][1]);
      unsigned w1 = cvt_pk_bf16(pv[c][2], pv[c][3]);
      const int pa = ((c >> 1) << 9) + (((colid >> 2) & 1) << 8)
                   + (((2 * c + (colid >> 3)) & 3) << 6) + ((colid & 3) << 4) + (rgrp << 2);
      *(u16x4*)&Ps[wid][pa] = pack4(w0, w1);
    }
    __builtin_amdgcn_sched_barrier(0);   // pin store->tr-read order (DS in-order per wave)

    // ---- pf via canonical tr reads ----
    u16x4 p00 = tr16<0>(ps_base);
    u16x4 p01 = tr16<512>(ps_base);
    u16x4 p10 = tr16<1024>(ps_base);
    u16x4 p11 = tr16<1536>(ps_base);
    asm volatile("s_waitcnt lgkmcnt(0)" ::: "memory");
    __builtin_amdgcn_sched_barrier(0);   // rule #18: fence MFMA hoisting past asm waitcnt
    bf16x8 pf0 = pack8(p00, p01);
    bf16x8 pf1 = pack8(p10, p11);

    // ---- l += rowsum(P) via P x ones MFMA; O += P.V (setprio-wrapped cluster) ----
    __builtin_amdgcn_s_setprio(1);        // T5
    f32x4 sum_acc = (f32x4){0.f, 0.f, 0.f, 0.f};
    sum_acc = __builtin_amdgcn_mfma_f32_16x16x32_bf16(pf0, ones8, sum_acc, 0, 0, 0);
    sum_acc = __builtin_amdgcn_mfma_f32_16x16x32_bf16(pf1, ones8, sum_acc, 0, 0, 0);

#pragma unroll
    for (int dc2 = 0; dc2 < 4; ++dc2) {
      const unsigned va = vs_base + (unsigned)(dc2 * 2048);
      u16x4 v00 = tr16<0>(va);
      u16x4 v01 = tr16<512>(va);
      u16x4 v10 = tr16<1024>(va);
      u16x4 v11 = tr16<1536>(va);
      asm volatile("s_waitcnt lgkmcnt(0)" ::: "memory");
      __builtin_amdgcn_sched_barrier(0);
      bf16x8 vf0 = pack8(v00, v01);
      bf16x8 vf1 = pack8(v10, v11);
      oacc[dc2] = __builtin_amdgcn_mfma_f32_16x16x32_bf16(pf0, vf0, oacc[dc2], 0, 0, 0);
      oacc[dc2] = __builtin_amdgcn_mfma_f32_16x16x32_bf16(pf1, vf1, oacc[dc2], 0, 0, 0);
    }
    __builtin_amdgcn_s_setprio(0);
#pragma unroll
    for (int r = 0; r < 4; ++r) l[r] += sum_acc[r];
    __syncthreads();
  }

  // ---- epilogue: normalized write (cvt_pk conversions) ----
#pragma unroll
  for (int r = 0; r < 4; ++r) {
    int qrow = q0 + wid * 16 + rgrp * 4 + r;
    u16* op = O + ((size_t)b * 1024 + qrow) * 768 + h * 64;
    float inv = 1.f / l[r];
    unsigned w0 = cvt_pk_bf16(oacc[0][r] * inv, oacc[1][r] * inv);
    unsigned w1 = cvt_pk_bf16(oacc[2][r] * inv, oacc[3][r] * inv);
    op[colid] = (u16)w0;
    op[16 + colid] = (u16)(w0 >> 16);
    op[32 + colid] = (u16)w1;
    op[48 + colid] = (u16)(w1 >> 16);
  }
}

// =============================================================================================
extern "C" void kernel_launch(void* const* d_in, const int* in_sizes, int n_in,
                              void* d_out, int out_size, void* d_ws, size_t ws_size,
                              hipStream_t stream) {
  const float* x        = (const float*)d_in[0];
  const float* x_enc    = (const float*)d_in[1];
  const float* ln1_g    = (const float*)d_in[2];
  const float* ln1_b    = (const float*)d_in[3];
  const float* ln2_g    = (const float*)d_in[4];
  const float* ln2_b    = (const float*)d_in[5];
  const float* ln3_g    = (const float*)d_in[6];
  const float* ln3_b    = (const float*)d_in[7];
  const float* attn_w   = (const float*)d_in[8];
  const float* attn_bias= (const float*)d_in[9];
  const float* proj_w   = (const float*)d_in[10];
  const float* proj_b   = (const float*)d_in[11];
  const float* img_w    = (const float*)d_in[12];
  const float* img_b    = (const float*)d_in[13];
  const float* cap_w    = (const float*)d_in[14];
  const float* cap_b    = (const float*)d_in[15];
  const float* cross_w  = (const float*)d_in[16];
  const float* cross_b  = (const float*)d_in[17];
  const float* ad1_w    = (const float*)d_in[18];
  const float* ad1_b    = (const float*)d_in[19];
  const float* ad2_w    = (const float*)d_in[20];
  const float* ad2_b    = (const float*)d_in[21];
  const float* fc_w     = (const float*)d_in[22];
  const float* fc_b     = (const float*)d_in[23];
  const float* mproj_w  = (const float*)d_in[24];
  const float* mproj_b  = (const float*)d_in[25];

  const int Mx = 8192;            // B*T
  const int Me = 2056;            // B*N_ENC
  const int MeP = 2176;           // padded to 17*128

  float* out_x  = (float*)d_out;                    // [8192][768] fp32, residual master
  float* out_xe = out_x + (size_t)Mx * 768;         // [2056][768] fp32 pass-through

  char* ws = (char*)d_ws;
  size_t off = 0;
  auto alloc = [&](size_t elems) {
    u16* p = (u16*)(ws + off);
    off = (off + elems * 2 + 255) & ~(size_t)255;
    return p;
  };
  u16* wt_attn  = alloc((size_t)2304 * 768);
  u16* wt_proj  = alloc((size_t)768 * 768);
  u16* wt_img   = alloc((size_t)1536 * 768);
  u16* wt_cap   = alloc((size_t)768 * 768);
  u16* wt_cross = alloc((size_t)768 * 768);
  u16* wt_ad1   = alloc((size_t)192 * 768);         // unpadded N=192
  u16* wt_ad2   = alloc((size_t)768 * 192);         // unpadded K=192
  u16* wt_fc    = alloc((size_t)3072 * 768);
  u16* wt_mproj = alloc((size_t)768 * 3072);
  u16* hbuf     = alloc((size_t)Mx * 768);          // LN outputs (h / hq / hm)
  u16* big      = alloc((size_t)Mx * 3072);         // qkv | q2+kv | mlp hidden
  u16* p0       = alloc((size_t)Mx * 768);
  u16* p1       = alloc((size_t)Mx * 768);
  u16* hid      = alloc((size_t)Mx * 192);          // adapter hidden (native 192)
  u16* q2  = big;                                   // [8192][768]
  u16* kvb = big + (size_t)Mx * 768;                // [2176][1536]

  // x_enc pass-through
  hipMemcpyAsync(out_xe, x_enc, (size_t)Me * 768 * 4, hipMemcpyDeviceToDevice, stream);

  // ---- batched weight convert+transpose (one launch for all 9) ----
  TrBatch tb;
  int nt = 0;
  tb.tstart[0] = 0;
  auto addT = [&](const float* W, u16* Bt, int K, int N, int Kp, int Np) {
    tb.W[nt] = W; tb.Bt[nt] = Bt; tb.K[nt] = K; tb.N[nt] = N;
    tb.Kpad[nt] = Kp; tb.Npad[nt] = Np;
    tb.tstart[nt + 1] = tb.tstart[nt] + (Np / 64) * (Kp / 64);
    ++nt;
  };
  addT(attn_w, wt_attn, 768, 2304, 768, 2304);
  addT(proj_w, wt_proj, 768, 768, 768, 768);
  addT(img_w, wt_img, 768, 1536, 768, 1536);
  addT(cap_w, wt_cap, 768, 768, 768, 768);
  addT(cross_w, wt_cross, 768, 768, 768, 768);
  addT(ad1_w, wt_ad1, 768, 192, 768, 192);
  addT(ad2_w, wt_ad2, 192, 768, 192, 768);
  addT(fc_w, wt_fc, 768, 3072, 768, 3072);
  addT(mproj_w, wt_mproj, 3072, 768, 3072, 768);
  transpose_all<<<tb.tstart[9], 256, 0, stream>>>(tb);

  // gemm_bt (128x128) for high-occupancy grids (qkv/fc/dual); gemm_bt_m64 (64x128 M-split)
  // for latency-bound low-grid GEMMs; gemm_bt_6464 for ad1; gemm_bt_m64_res for ad2+residual.
  auto GEMM = [&](const u16* A, const u16* Bt, void* C, const float* bias,
                  int M, int N, int K, int ldc, int nbias, int mode) {
    dim3 g(M / 128, N / 128);
    if (mode == 0)      gemm_bt<0><<<g, 256, 0, stream>>>(A, Bt, C, bias, K, ldc, nbias);
    else if (mode == 1) gemm_bt<1><<<g, 256, 0, stream>>>(A, Bt, C, bias, K, ldc, nbias);
    else                gemm_bt<2><<<g, 256, 0, stream>>>(A, Bt, C, bias, K, ldc, nbias);
  };
  auto GEMM_M64 = [&](const u16* A, const u16* Bt, void* C, const float* bias,
                      int M, int N, int K, int ldc, int nbias, int mode) {
    dim3 g(M / 64, N / 128);    // M fastest: consecutive blocks share the B(weight)-panel
    if (mode == 0) gemm_bt_m64<0><<<g, 256, 0, stream>>>(A, Bt, C, bias, K, ldc, nbias);
    else           gemm_bt_m64<1><<<g, 256, 0, stream>>>(A, Bt, C, bias, K, ldc, nbias);
  };
  // ADAPTER_RES: ad1 -> hid; ad2 computes OX = SRC + adapter + bias (fp32).
  // First branch passes SRC = x (removes the init out_x = x copy); later branches SRC = out_x.
  auto ADAPTER_RES = [&](const u16* in, const float* srcResid) {
    dim3 g1(Mx / 64, 192 / 64);                    // 128 x 3 = 384 blocks
    gemm_bt_6464<1><<<g1, 256, 0, stream>>>(in, wt_ad1, hid, ad1_b, 768, 192, 192);
    dim3 g2(Mx / 64, 768 / 128);                   // 128 x 6 = 768 blocks
    gemm_bt_m64_res<<<g2, 256, 0, stream>>>(hid, wt_ad2, srcResid, out_x, ad2_b, 192, 768);
  };

  // ---- init: hbuf = ln1(x) (no out_x copy — first ad2_res reads x directly) ----
  ln_kernel<<<Mx, 64, 0, stream>>>(x, ln1_g, ln1_b, hbuf, Mx);

  // ---- causal self-attention branch (single-pass, normalized -> p0) ----
  GEMM(hbuf, wt_attn, big, attn_bias, Mx, 2304, 768, 2304, 2304, 0);   // qkv (1152 blocks)
  attn_mfma<true><<<dim3(96, 8), 512, 0, stream>>>(
      big, big, big, p0, 1024, 2304, 2304,
      (long long)1024 * 2304, (long long)1024 * 2304, 0, 768, 1536);
  GEMM_M64(p0, wt_proj, p1, proj_b, Mx, 768, 768, 768, 768, 0);        // sa (768 blocks)
  ADAPTER_RES(p1, x);                                                  // out_x = x + adapter(sa)
  // hq-LN (out_x) + he-LN (x_enc) merged into one dispatch (p0 is free after proj)
  ln_dual<<<Mx + MeP, 64, 0, stream>>>(out_x, ln1_g, ln1_b, hbuf, Mx,
                                       x_enc, ln3_g, ln3_b, p0, Me);

  // ---- cross-attention branch (kv + q2 GEMMs fused into one dispatch) ----
  {
    GemmJob jkv = { p0,   wt_img, kvb, img_b, 768, 1536, 1536, MeP / 128 };  // 17x12 = 204
    GemmJob jq2 = { hbuf, wt_cap, q2,  cap_b, 768, 768,  768,  Mx / 128 };   // 64x6  = 384
    const int split = (MeP / 128) * (1536 / 128);
    const int total = split + (Mx / 128) * (768 / 128);
    gemm_bt_dual<<<total, 256, 0, stream>>>(jkv, jq2, split);
  }
  attn_mfma<false><<<dim3(96, 8), 512, 0, stream>>>(
      q2, kvb, kvb, p1, 257, 768, 1536,
      (long long)1024 * 768, (long long)257 * 1536, 0, 0, 768);
  GEMM_M64(p1, wt_cross, p0, cross_b, Mx, 768, 768, 768, 768, 0);      // ca (768 blocks)
  ADAPTER_RES(p0, out_x);                                              // out_x += adapter(ca)
  ln_kernel<<<Mx, 64, 0, stream>>>(out_x, ln2_g, ln2_b, hbuf, Mx);     // hm

  // ---- MLP branch ----
  GEMM(hbuf, wt_fc, big, fc_b, Mx, 3072, 768, 3072, 3072, 2);          // fc (1536 blocks)
  GEMM_M64(big, wt_mproj, p0, mproj_b, Mx, 768, 3072, 768, 768, 0);    // mproj (768 blocks)
  ADAPTER_RES(p0, out_x);                                              // out_x += adapter(m)

  (void)in_sizes; (void)n_in; (void)out_size; (void)ws_size;
}